// Round 3
// baseline (10126.317 us; speedup 1.0000x reference)
//
#include <hip/hip_runtime.h>
#include <hip/hip_bf16.h>
#include <math.h>

typedef __hip_bfloat16 bf16;

#define B_ 2
#define N_ 48
#define A_ 16
#define E_ 5
#define HID 384
#define NHD 8
#define HD 48
#define LYR 4
#define MLPD 1536
#define L_ 2352      // N_ + N_*N_
#define M_ 4704      // B_*L_

static __device__ __forceinline__ float b2f(bf16 v) { return __bfloat162float(v); }
static __device__ __forceinline__ float ldv(const float* p, size_t i) { return p[i]; }
static __device__ __forceinline__ float ldv(const bf16*  p, size_t i) { return b2f(p[i]); }
static __device__ __forceinline__ void  stv(float* p, size_t i, float v) { p[i] = v; }
static __device__ __forceinline__ void  stv(bf16*  p, size_t i, float v) { p[i] = __float2bfloat16(v); }

// ------------------------------------------------ dtype detect (flag: 1=fp32, 0=bf16)
__global__ void k_detect(const void* w, int* flag) {
    if (threadIdx.x == 0 && blockIdx.x == 0) {
        const bf16* p = (const bf16*)w;   // node_w: 6144 elems of 0.02*normal
        int isf = 0;
        for (int i = 0; i < 256; ++i) {
            float v = fabsf(b2f(p[i]));
            if (!(v <= 1000.0f)) { isf = 1; break; }   // catches huge and NaN
        }
        *flag = isf;
    }
}

// ---------------------------------------------------------------- embed (-> f32 h)
template <typename T>
static __device__ void embed_body(
    const T* x, const T* adj, const T* node_w, const T* node_b,
    const T* edge_w, const T* edge_b, const T* pos, float* h)
{
    const int bl = blockIdx.x;
    const int b = bl / L_, l = bl % L_;
    const int c = threadIdx.x;          // 0..383
    float acc;
    if (l < N_) {
        acc = ldv(node_b, c);
        const size_t xr = (size_t)(b*N_ + l)*A_;
        #pragma unroll
        for (int a = 0; a < A_; ++a) acc += ldv(x, xr + a) * ldv(node_w, (size_t)a*HID + c);
    } else {
        const int e = l - N_;
        acc = ldv(edge_b, c);
        const size_t ar = ((size_t)b*N_*N_ + e)*E_;
        #pragma unroll
        for (int j = 0; j < E_; ++j) acc += ldv(adj, ar + j) * ldv(edge_w, (size_t)j*HID + c);
    }
    h[(size_t)bl*HID + c] = acc + ldv(pos, (size_t)l*HID + c);
}

__global__ __launch_bounds__(384) void k_embed(
    const void* x, const void* adj, const void* node_w, const void* node_b,
    const void* edge_w, const void* edge_b, const void* pos,
    const int* __restrict__ fl, float* __restrict__ h)
{
    if (*fl) embed_body<float>((const float*)x, (const float*)adj, (const float*)node_w,
                               (const float*)node_b, (const float*)edge_w, (const float*)edge_b,
                               (const float*)pos, h);
    else     embed_body<bf16>((const bf16*)x, (const bf16*)adj, (const bf16*)node_w,
                              (const bf16*)node_b, (const bf16*)edge_w, (const bf16*)edge_b,
                              (const bf16*)pos, h);
}

// ------------------------------------------- timestep cond + ada projections (f32)
template <typename T>
static __device__ void cond_body(
    const T* t, const T* t_w1, const T* t_b1, const T* t_w2, const T* t_b2,
    const T* ada1_w, const T* ada1_b, const T* ada2_w, const T* ada2_b,
    float* ada_out)
{
    __shared__ float temb[HID];
    __shared__ float hidden[4*HID];
    __shared__ float cond[HID];
    const int b = blockIdx.x, tid = threadIdx.x;
    const float tv = ldv(t, b);
    for (int c = tid; c < HID; c += 256) {
        int i = (c < 192) ? c : c - 192;
        float f = expf(-9.2103403719761836f * (float)i / 192.0f);
        float ang = tv * f;
        temb[c] = (c < 192) ? sinf(ang) : cosf(ang);
    }
    __syncthreads();
    for (int j = tid; j < 4*HID; j += 256) {
        float acc = ldv(t_b1, j);
        for (int i = 0; i < HID; ++i) acc += temb[i] * ldv(t_w1, (size_t)i*4*HID + j);
        hidden[j] = acc / (1.0f + expf(-acc));   // SiLU
    }
    __syncthreads();
    for (int c = tid; c < HID; c += 256) {
        float acc = ldv(t_b2, c);
        for (int j = 0; j < 4*HID; ++j) acc += hidden[j] * ldv(t_w2, (size_t)j*HID + c);
        cond[c] = acc;
    }
    __syncthreads();
    for (int idx = tid; idx < LYR*2*768; idx += 256) {
        const int layer = idx / 1536;
        const int rem   = idx % 1536;
        const int which = rem / 768;
        const int o     = rem % 768;
        const T* W  = (which ? ada2_w : ada1_w) + (size_t)layer*HID*768;
        const T* Bi = (which ? ada2_b : ada1_b) + layer*768;
        float acc = ldv(Bi, o);
        for (int c = 0; c < HID; ++c) acc += cond[c] * ldv(W, (size_t)c*768 + o);
        ada_out[((size_t)(layer*2 + which)*B_ + b)*768 + o] = acc;
    }
}

__global__ __launch_bounds__(256) void k_cond(
    const void* t, const void* t_w1, const void* t_b1, const void* t_w2, const void* t_b2,
    const void* ada1_w, const void* ada1_b, const void* ada2_w, const void* ada2_b,
    const int* __restrict__ fl, float* __restrict__ ada_out)
{
    if (*fl) cond_body<float>((const float*)t, (const float*)t_w1, (const float*)t_b1,
                              (const float*)t_w2, (const float*)t_b2, (const float*)ada1_w,
                              (const float*)ada1_b, (const float*)ada2_w, (const float*)ada2_b,
                              ada_out);
    else     cond_body<bf16>((const bf16*)t, (const bf16*)t_w1, (const bf16*)t_b1,
                             (const bf16*)t_w2, (const bf16*)t_b2, (const bf16*)ada1_w,
                             (const bf16*)ada1_b, (const bf16*)ada2_w, (const bf16*)ada2_b,
                             ada_out);
}

// ---------------------------------------------------------------- adaLN (f32 h -> bf16 n)
__global__ __launch_bounds__(256) void k_adaln(
    const float* __restrict__ h, const float* __restrict__ ada,
    bf16* __restrict__ n, int slot)
{
    const int row  = blockIdx.x * 4 + (threadIdx.x >> 6);
    const int lane = threadIdx.x & 63;
    const int b = row / L_;
    const float* hr = h + (size_t)row*HID;
    float v[6]; float s = 0.f, ss = 0.f;
    #pragma unroll
    for (int j = 0; j < 6; ++j) { float t = hr[lane + j*64]; v[j] = t; s += t; ss += t*t; }
    #pragma unroll
    for (int off = 32; off; off >>= 1) { s += __shfl_xor(s, off); ss += __shfl_xor(ss, off); }
    const float mu = s * (1.0f/HID);
    const float rs = rsqrtf(fmaxf(ss * (1.0f/HID) - mu*mu, 0.0f) + 1e-5f);
    const float* ap = ada + ((size_t)slot*B_ + b)*768;
    bf16* nr = n + (size_t)row*HID;
    #pragma unroll
    for (int j = 0; j < 6; ++j) {
        int c = lane + j*64;
        nr[c] = __float2bfloat16((v[j] - mu)*rs*(1.0f + ap[c]) + ap[384 + c]);
    }
}

// ------------------------------------------------- GEMM  C = act(A@W + bias)
// A: [M,K] bf16 (internal). W/bias: input dtype, with ELEMENT offsets woff/boff applied
// inside the typed body (dtype byte-size is unknown on the host).
template <typename T>
static __device__ void gemm_body(
    const bf16* A, const T* W, long long woff, const T* bias, long long boff,
    bf16* Cb, float* Cf, int M, int N, int K, int act, int res)
{
    __shared__ float As[16][65];   // [k][m]
    __shared__ float Bs[16][65];   // [k][n]
    const int tid = threadIdx.x;
    const int tx = tid & 15, ty = tid >> 4;
    const int bm = blockIdx.x * 64, bn = blockIdx.y * 64;
    const int ar = tid & 63, ak = (tid >> 6) * 4;
    const int bk = tid >> 4, bnn = (tid & 15) * 4;
    float acc[4][4] = {{0.f,0.f,0.f,0.f},{0.f,0.f,0.f,0.f},{0.f,0.f,0.f,0.f},{0.f,0.f,0.f,0.f}};
    for (int k0 = 0; k0 < K; k0 += 16) {
        float a0=0.f, a1=0.f, a2=0.f, a3=0.f;
        if (bm + ar < M) {
            const size_t ap = (size_t)(bm + ar)*K + k0 + ak;
            a0 = b2f(A[ap]); a1 = b2f(A[ap+1]); a2 = b2f(A[ap+2]); a3 = b2f(A[ap+3]);
        }
        const size_t wp = (size_t)woff + (size_t)(k0 + bk)*N + bn + bnn;
        const float w0 = ldv(W, wp), w1 = ldv(W, wp+1), w2 = ldv(W, wp+2), w3 = ldv(W, wp+3);
        __syncthreads();
        As[ak+0][ar] = a0; As[ak+1][ar] = a1; As[ak+2][ar] = a2; As[ak+3][ar] = a3;
        Bs[bk][bnn+0] = w0; Bs[bk][bnn+1] = w1; Bs[bk][bnn+2] = w2; Bs[bk][bnn+3] = w3;
        __syncthreads();
        #pragma unroll
        for (int k = 0; k < 16; ++k) {
            float av[4], bv[4];
            #pragma unroll
            for (int i = 0; i < 4; ++i) av[i] = As[k][ty*4 + i];
            #pragma unroll
            for (int j = 0; j < 4; ++j) bv[j] = Bs[k][tx*4 + j];
            #pragma unroll
            for (int i = 0; i < 4; ++i)
                #pragma unroll
                for (int j = 0; j < 4; ++j) acc[i][j] += av[i]*bv[j];
        }
    }
    float bcol[4];
    #pragma unroll
    for (int j = 0; j < 4; ++j) bcol[j] = ldv(bias, (size_t)boff + bn + tx*4 + j);
    #pragma unroll
    for (int i = 0; i < 4; ++i) {
        const int row = bm + ty*4 + i;
        if (row < M) {
            #pragma unroll
            for (int j = 0; j < 4; ++j) {
                float r = acc[i][j] + bcol[j];
                if (act) r = 0.5f * r * (1.0f + erff(r * 0.70710678118654752f));
                const size_t ci = (size_t)row*N + bn + tx*4 + j;
                if (res) Cf[ci] += r; else Cb[ci] = __float2bfloat16(r);
            }
        }
    }
}

__global__ __launch_bounds__(256) void k_gemm(
    const bf16* __restrict__ A, const void* W, long long woff, const void* bias, long long boff,
    bf16* Cb, float* Cf, int M, int N, int K, int act, int res,
    const int* __restrict__ fl)
{
    if (*fl) gemm_body<float>(A, (const float*)W, woff, (const float*)bias, boff,
                              Cb, Cf, M, N, K, act, res);
    else     gemm_body<bf16>(A, (const bf16*)W, woff, (const bf16*)bias, boff,
                             Cb, Cf, M, N, K, act, res);
}

// ---------------------------------------------------------------- attention (bf16 io)
__global__ __launch_bounds__(64) void k_attn(
    const bf16* __restrict__ q, const bf16* __restrict__ k,
    const bf16* __restrict__ v, bf16* __restrict__ ao)
{
    __shared__ float sc[L_];
    const int ql = blockIdx.x;
    const int bh = blockIdx.y;
    const int b = bh >> 3, hh = bh & 7;
    const int lane = threadIdx.x;
    const size_t rowbase = (size_t)(b*L_ + ql)*HID + hh*HD;
    float qq[48];
    {
        const bf16* qr = q + rowbase;
        #pragma unroll
        for (int d = 0; d < 48; ++d) qq[d] = b2f(qr[d]);
    }
    const bf16* kb = k + (size_t)b*L_*HID + hh*HD;
    float lmax = -3.0e38f;
    for (int key = lane; key < L_; key += 64) {
        const bf16* kr = kb + (size_t)key*HID;
        float s = 0.f;
        #pragma unroll
        for (int d = 0; d < 48; ++d) s += qq[d] * b2f(kr[d]);
        s *= 0.14433756729740643f;
        sc[key] = s;
        lmax = fmaxf(lmax, s);
    }
    #pragma unroll
    for (int off = 32; off; off >>= 1) lmax = fmaxf(lmax, __shfl_xor(lmax, off));
    const bf16* vb = v + (size_t)b*L_*HID + hh*HD;
    float po[48];
    #pragma unroll
    for (int d = 0; d < 48; ++d) po[d] = 0.f;
    float lsum = 0.f;
    for (int key = lane; key < L_; key += 64) {
        const float p = expf(sc[key] - lmax);
        lsum += p;
        const bf16* vr = vb + (size_t)key*HID;
        #pragma unroll
        for (int d = 0; d < 48; ++d) po[d] += p * b2f(vr[d]);
    }
    #pragma unroll
    for (int off = 32; off; off >>= 1) {
        lsum += __shfl_xor(lsum, off);
        #pragma unroll
        for (int d = 0; d < 48; ++d) po[d] += __shfl_xor(po[d], off);
    }
    const float inv = 1.0f / lsum;
    float outv = 0.f;
    #pragma unroll
    for (int d = 0; d < 48; ++d) if (lane == d) outv = po[d];
    if (lane < 48) ao[rowbase + lane] = __float2bfloat16(outv * inv);
}

// ------------------------------------------------------- final LN + heads
template <typename T, typename TO>
static __device__ void final_body(
    const float* h, const T* fn_g, const T* fn_b,
    const T* on_w, const T* on_b, const T* oe_w, const T* oe_b, TO* out)
{
    __shared__ float hf[HID];
    const int row = blockIdx.x;
    const int b = row / L_, l = row % L_;
    const int lane = threadIdx.x;
    const float* hr = h + (size_t)row*HID;
    float v[6]; float s = 0.f, ss = 0.f;
    #pragma unroll
    for (int j = 0; j < 6; ++j) { float t = hr[lane + j*64]; v[j] = t; s += t; ss += t*t; }
    #pragma unroll
    for (int off = 32; off; off >>= 1) { s += __shfl_xor(s, off); ss += __shfl_xor(ss, off); }
    const float mu = s * (1.0f/HID);
    const float rs = rsqrtf(fmaxf(ss * (1.0f/HID) - mu*mu, 0.0f) + 1e-5f);
    #pragma unroll
    for (int j = 0; j < 6; ++j) {
        int c = lane + j*64;
        hf[c] = (v[j] - mu) * rs * ldv(fn_g, c) + ldv(fn_b, c);
    }
    __syncthreads();
    if (l < N_) {
        if (lane < A_) {
            float acc = ldv(on_b, lane);
            for (int c = 0; c < HID; ++c) acc += hf[c] * ldv(on_w, (size_t)c*A_ + lane);
            stv(out, (size_t)(b*N_ + l)*A_ + lane, acc);
        }
    } else {
        const int e = l - N_;
        if (lane < E_) {
            float acc = ldv(oe_b, lane);
            for (int c = 0; c < HID; ++c) acc += hf[c] * ldv(oe_w, (size_t)c*E_ + lane);
            stv(out, (size_t)B_*N_*A_ + ((size_t)b*N_*N_ + e)*E_ + lane, acc);
        }
    }
}

__global__ __launch_bounds__(64) void k_final(
    const float* __restrict__ h, const void* fn_g, const void* fn_b,
    const void* on_w, const void* on_b, const void* oe_w, const void* oe_b,
    const int* __restrict__ fl, void* out)
{
    if (*fl) final_body<float, float>(h, (const float*)fn_g, (const float*)fn_b,
                                      (const float*)on_w, (const float*)on_b,
                                      (const float*)oe_w, (const float*)oe_b, (float*)out);
    else     final_body<bf16, bf16>(h, (const bf16*)fn_g, (const bf16*)fn_b,
                                    (const bf16*)on_w, (const bf16*)on_b,
                                    (const bf16*)oe_w, (const bf16*)oe_b, (bf16*)out);
}

// ---------------------------------------------------------------- launch
extern "C" void kernel_launch(void* const* d_in, const int* in_sizes, int n_in,
                              void* d_out, int out_size, void* d_ws, size_t ws_size,
                              hipStream_t stream) {
    const void* x      = d_in[0];
    const void* adj    = d_in[1];
    const void* t      = d_in[2];
    const void* node_w = d_in[3];
    const void* node_b = d_in[4];
    const void* edge_w = d_in[5];
    const void* edge_b = d_in[6];
    const void* pos    = d_in[7];
    const void* t_w1   = d_in[8];
    const void* t_b1   = d_in[9];
    const void* t_w2   = d_in[10];
    const void* t_b2   = d_in[11];
    const void* ada1_w = d_in[12];
    const void* ada1_b = d_in[13];
    const void* ada2_w = d_in[14];
    const void* ada2_b = d_in[15];
    const void* q_w    = d_in[16];
    const void* q_b    = d_in[17];
    const void* k_w    = d_in[18];
    const void* k_b    = d_in[19];
    const void* v_w    = d_in[20];
    const void* v_b    = d_in[21];
    const void* o_w    = d_in[22];
    const void* o_b    = d_in[23];
    const void* m1_w   = d_in[24];
    const void* m1_b   = d_in[25];
    const void* m2_w   = d_in[26];
    const void* m2_b   = d_in[27];
    const void* fn_g   = d_in[28];
    const void* fn_b   = d_in[29];
    const void* on_w   = d_in[30];
    const void* on_b   = d_in[31];
    const void* oe_w   = d_in[32];
    const void* oe_b   = d_in[33];

    const size_t SZ = (size_t)M_ * HID;   // 1,806,336 elements
    const size_t NEED = 256 + sizeof(float)*(SZ + 12288) + sizeof(bf16)*4*SZ;  // ~21.7 MB
    if (ws_size < NEED) {
        hipMemsetAsync(d_out, 0, (size_t)out_size*sizeof(bf16), stream);  // 1.14 signature
        return;
    }
    int*   fl  = (int*)d_ws;
    float* h   = (float*)((char*)d_ws + 256);
    float* ada = h + SZ;
    bf16* nb  = (bf16*)(ada + 12288);
    bf16* qb  = nb + SZ;
    bf16* kb  = qb + SZ;
    bf16* vb  = kb + SZ;
    bf16* m1b = kb;   // [2352,1536] bf16 == kb+vb exactly (dead after attention)

    k_detect<<<1, 64, 0, stream>>>(node_w, fl);
    k_embed<<<M_, HID, 0, stream>>>(x, adj, node_w, node_b, edge_w, edge_b, pos, fl, h);
    k_cond<<<B_, 256, 0, stream>>>(t, t_w1, t_b1, t_w2, t_b2,
                                   ada1_w, ada1_b, ada2_w, ada2_b, fl, ada);
    for (int i = 0; i < LYR; ++i) {
        const long long woff   = (long long)i * HID * HID;
        const long long boff   = (long long)i * HID;
        const long long m1woff = (long long)i * HID * MLPD;
        const long long m1boff = (long long)i * MLPD;
        const long long m2woff = (long long)i * MLPD * HID;

        k_adaln<<<M_/4, 256, 0, stream>>>(h, ada, nb, 2*i);
        k_gemm<<<dim3(74, 6), 256, 0, stream>>>(nb, q_w, woff, q_b, boff,
                                                qb, nullptr, M_, HID, HID, 0, 0, fl);
        k_gemm<<<dim3(74, 6), 256, 0, stream>>>(nb, k_w, woff, k_b, boff,
                                                kb, nullptr, M_, HID, HID, 0, 0, fl);
        k_gemm<<<dim3(74, 6), 256, 0, stream>>>(nb, v_w, woff, v_b, boff,
                                                vb, nullptr, M_, HID, HID, 0, 0, fl);
        k_attn<<<dim3(L_, B_*NHD), 64, 0, stream>>>(qb, kb, vb, nb);       // ao -> nb
        k_gemm<<<dim3(74, 6), 256, 0, stream>>>(nb, o_w, woff, o_b, boff,
                                                nullptr, h, M_, HID, HID, 0, 1, fl);
        k_adaln<<<M_/4, 256, 0, stream>>>(h, ada, nb, 2*i + 1);            // n2 -> nb
        for (int c = 0; c < 2; ++c) {
            k_gemm<<<dim3(37, 24), 256, 0, stream>>>(nb + (size_t)c*2352*HID,
                                                     m1_w, m1woff, m1_b, m1boff,
                                                     m1b, nullptr, 2352, MLPD, HID, 1, 0, fl);
            k_gemm<<<dim3(37, 6), 256, 0, stream>>>(m1b, m2_w, m2woff, m2_b, boff,
                                                    nullptr, h + (size_t)c*2352*HID,
                                                    2352, HID, MLPD, 0, 1, fl);
        }
    }
    k_final<<<M_, 64, 0, stream>>>(h, fn_g, fn_b, on_w, on_b, oe_w, oe_b, fl, (void*)d_out);
}

// Round 4
// 8497.123 us; speedup vs baseline: 1.1917x; 1.1917x over previous
//
#include <hip/hip_runtime.h>
#include <hip/hip_bf16.h>
#include <math.h>

typedef __hip_bfloat16 bf16;

#define B_ 2
#define N_ 48
#define A_ 16
#define E_ 5
#define HID 384
#define NHD 8
#define HD 48
#define LYR 4
#define MLPD 1536
#define L_ 2352      // N_ + N_*N_
#define M_ 4704      // B_*L_

static __device__ __forceinline__ float b2f(bf16 v) { return __bfloat162float(v); }
static __device__ __forceinline__ float us2f(unsigned short u) {
    return __uint_as_float(((unsigned)u) << 16);
}
static __device__ __forceinline__ unsigned short f2us(float f) {
    bf16 h = __float2bfloat16(f);
    return *reinterpret_cast<unsigned short*>(&h);
}
static __device__ __forceinline__ float ldv(const float* p, size_t i) { return p[i]; }
static __device__ __forceinline__ float ldv(const bf16*  p, size_t i) { return b2f(p[i]); }
static __device__ __forceinline__ void  stv(float* p, size_t i, float v) { p[i] = v; }
static __device__ __forceinline__ void  stv(bf16*  p, size_t i, float v) { p[i] = __float2bfloat16(v); }
// 4-wide typed loads (alignment guaranteed by callers: element offset % 4 == 0)
static __device__ __forceinline__ float4 ld4(const float* p, size_t i) {
    return *reinterpret_cast<const float4*>(p + i);
}
static __device__ __forceinline__ float4 ld4(const bf16* p, size_t i) {
    ushort4 u = *reinterpret_cast<const ushort4*>(p + i);
    return make_float4(us2f(u.x), us2f(u.y), us2f(u.z), us2f(u.w));
}

// ------------------------------------------------ dtype detect (flag: 1=fp32, 0=bf16)
__global__ void k_detect(const void* w, int* flag) {
    if (threadIdx.x == 0 && blockIdx.x == 0) {
        const bf16* p = (const bf16*)w;   // node_w: 6144 elems of 0.02*normal
        int isf = 0;
        for (int i = 0; i < 256; ++i) {
            float v = fabsf(b2f(p[i]));
            if (!(v <= 1000.0f)) { isf = 1; break; }
        }
        *flag = isf;
    }
}

// ---------------------------------------------------------------- embed (-> f32 h)
template <typename T>
static __device__ void embed_body(
    const T* x, const T* adj, const T* node_w, const T* node_b,
    const T* edge_w, const T* edge_b, const T* pos, float* h)
{
    const int bl = blockIdx.x;
    const int b = bl / L_, l = bl % L_;
    const int c = threadIdx.x;          // 0..383
    float acc;
    if (l < N_) {
        acc = ldv(node_b, c);
        const size_t xr = (size_t)(b*N_ + l)*A_;
        #pragma unroll
        for (int a = 0; a < A_; ++a) acc += ldv(x, xr + a) * ldv(node_w, (size_t)a*HID + c);
    } else {
        const int e = l - N_;
        acc = ldv(edge_b, c);
        const size_t ar = ((size_t)b*N_*N_ + e)*E_;
        #pragma unroll
        for (int j = 0; j < E_; ++j) acc += ldv(adj, ar + j) * ldv(edge_w, (size_t)j*HID + c);
    }
    h[(size_t)bl*HID + c] = acc + ldv(pos, (size_t)l*HID + c);
}

__global__ __launch_bounds__(384) void k_embed(
    const void* x, const void* adj, const void* node_w, const void* node_b,
    const void* edge_w, const void* edge_b, const void* pos,
    const int* __restrict__ fl, float* __restrict__ h)
{
    if (*fl) embed_body<float>((const float*)x, (const float*)adj, (const float*)node_w,
                               (const float*)node_b, (const float*)edge_w, (const float*)edge_b,
                               (const float*)pos, h);
    else     embed_body<bf16>((const bf16*)x, (const bf16*)adj, (const bf16*)node_w,
                              (const bf16*)node_b, (const bf16*)edge_w, (const bf16*)edge_b,
                              (const bf16*)pos, h);
}

// ------------------------------------------- timestep cond + ada projections (f32)
template <typename T>
static __device__ void cond_body(
    const T* t, const T* t_w1, const T* t_b1, const T* t_w2, const T* t_b2,
    const T* ada1_w, const T* ada1_b, const T* ada2_w, const T* ada2_b,
    float* ada_out)
{
    __shared__ float temb[HID];
    __shared__ float hidden[4*HID];
    __shared__ float cond[HID];
    const int b = blockIdx.x, tid = threadIdx.x;
    const float tv = ldv(t, b);
    for (int c = tid; c < HID; c += 256) {
        int i = (c < 192) ? c : c - 192;
        float f = expf(-9.2103403719761836f * (float)i / 192.0f);
        float ang = tv * f;
        temb[c] = (c < 192) ? sinf(ang) : cosf(ang);
    }
    __syncthreads();
    for (int j = tid; j < 4*HID; j += 256) {
        float acc = ldv(t_b1, j);
        for (int i = 0; i < HID; ++i) acc += temb[i] * ldv(t_w1, (size_t)i*4*HID + j);
        hidden[j] = acc / (1.0f + expf(-acc));   // SiLU
    }
    __syncthreads();
    for (int c = tid; c < HID; c += 256) {
        float acc = ldv(t_b2, c);
        for (int j = 0; j < 4*HID; ++j) acc += hidden[j] * ldv(t_w2, (size_t)j*HID + c);
        cond[c] = acc;
    }
    __syncthreads();
    for (int idx = tid; idx < LYR*2*768; idx += 256) {
        const int layer = idx / 1536;
        const int rem   = idx % 1536;
        const int which = rem / 768;
        const int o     = rem % 768;
        const T* W  = (which ? ada2_w : ada1_w) + (size_t)layer*HID*768;
        const T* Bi = (which ? ada2_b : ada1_b) + layer*768;
        float acc = ldv(Bi, o);
        for (int c = 0; c < HID; ++c) acc += cond[c] * ldv(W, (size_t)c*768 + o);
        ada_out[((size_t)(layer*2 + which)*B_ + b)*768 + o] = acc;
    }
}

__global__ __launch_bounds__(256) void k_cond(
    const void* t, const void* t_w1, const void* t_b1, const void* t_w2, const void* t_b2,
    const void* ada1_w, const void* ada1_b, const void* ada2_w, const void* ada2_b,
    const int* __restrict__ fl, float* __restrict__ ada_out)
{
    if (*fl) cond_body<float>((const float*)t, (const float*)t_w1, (const float*)t_b1,
                              (const float*)t_w2, (const float*)t_b2, (const float*)ada1_w,
                              (const float*)ada1_b, (const float*)ada2_w, (const float*)ada2_b,
                              ada_out);
    else     cond_body<bf16>((const bf16*)t, (const bf16*)t_w1, (const bf16*)t_b1,
                             (const bf16*)t_w2, (const bf16*)t_b2, (const bf16*)ada1_w,
                             (const bf16*)ada1_b, (const bf16*)ada2_w, (const bf16*)ada2_b,
                             ada_out);
}

// ---------------------------------------------------------------- adaLN (f32 h -> bf16 n)
__global__ __launch_bounds__(256) void k_adaln(
    const float* __restrict__ h, const float* __restrict__ ada,
    bf16* __restrict__ n, int slot)
{
    const int row  = blockIdx.x * 4 + (threadIdx.x >> 6);
    const int lane = threadIdx.x & 63;
    const int b = row / L_;
    const float* hr = h + (size_t)row*HID;
    float v[6]; float s = 0.f, ss = 0.f;
    #pragma unroll
    for (int j = 0; j < 6; ++j) { float t = hr[lane + j*64]; v[j] = t; s += t; ss += t*t; }
    #pragma unroll
    for (int off = 32; off; off >>= 1) { s += __shfl_xor(s, off); ss += __shfl_xor(ss, off); }
    const float mu = s * (1.0f/HID);
    const float rs = rsqrtf(fmaxf(ss * (1.0f/HID) - mu*mu, 0.0f) + 1e-5f);
    const float* ap = ada + ((size_t)slot*B_ + b)*768;
    bf16* nr = n + (size_t)row*HID;
    #pragma unroll
    for (int j = 0; j < 6; ++j) {
        int c = lane + j*64;
        nr[c] = __float2bfloat16((v[j] - mu)*rs*(1.0f + ap[c]) + ap[384 + c]);
    }
}

// ------------------------------------------------- GEMM  C = act(A@W + bias)
// A: [M,K] bf16 (internal). W/bias: input dtype with element offsets woff/boff.
// Tile 64x64, block 256 (16x16 threads of 4x4), vectorized loads, b128 LDS reads.
template <typename T>
static __device__ void gemm_body(
    const bf16* A, const T* W, long long woff, const T* bias, long long boff,
    bf16* Cb, float* Cf, int M, int N, int K, int act, int res)
{
    __shared__ float As[16][68];   // [k][m], 68-stride: 16B-aligned rows, 4-bank rotation
    __shared__ float Bs[16][68];   // [k][n]
    const int tid = threadIdx.x;
    const int tx = tid & 15, ty = tid >> 4;
    const int bm = blockIdx.x * 64, bn = blockIdx.y * 64;
    const int ar = tid & 63, ak = (tid >> 6) * 4;   // A loader: row ar, k ak..ak+3
    const int bk = tid >> 4, bnn = (tid & 15) * 4;  // W loader: k bk, n bnn..bnn+3
    const bool avalid = (bm + ar) < M;
    float acc[4][4] = {{0.f,0.f,0.f,0.f},{0.f,0.f,0.f,0.f},{0.f,0.f,0.f,0.f},{0.f,0.f,0.f,0.f}};
    for (int k0 = 0; k0 < K; k0 += 16) {
        float a0=0.f, a1=0.f, a2=0.f, a3=0.f;
        if (avalid) {
            ushort4 av = *reinterpret_cast<const ushort4*>(A + (size_t)(bm + ar)*K + k0 + ak);
            a0 = us2f(av.x); a1 = us2f(av.y); a2 = us2f(av.z); a3 = us2f(av.w);
        }
        const float4 wv = ld4(W, (size_t)woff + (size_t)(k0 + bk)*N + bn + bnn);
        __syncthreads();
        As[ak+0][ar] = a0; As[ak+1][ar] = a1; As[ak+2][ar] = a2; As[ak+3][ar] = a3;
        *reinterpret_cast<float4*>(&Bs[bk][bnn]) = wv;
        __syncthreads();
        #pragma unroll
        for (int kk = 0; kk < 16; ++kk) {
            const float4 a4 = *reinterpret_cast<const float4*>(&As[kk][ty*4]);
            const float4 b4 = *reinterpret_cast<const float4*>(&Bs[kk][tx*4]);
            acc[0][0] += a4.x*b4.x; acc[0][1] += a4.x*b4.y; acc[0][2] += a4.x*b4.z; acc[0][3] += a4.x*b4.w;
            acc[1][0] += a4.y*b4.x; acc[1][1] += a4.y*b4.y; acc[1][2] += a4.y*b4.z; acc[1][3] += a4.y*b4.w;
            acc[2][0] += a4.z*b4.x; acc[2][1] += a4.z*b4.y; acc[2][2] += a4.z*b4.z; acc[2][3] += a4.z*b4.w;
            acc[3][0] += a4.w*b4.x; acc[3][1] += a4.w*b4.y; acc[3][2] += a4.w*b4.z; acc[3][3] += a4.w*b4.w;
        }
    }
    float bcol[4];
    #pragma unroll
    for (int j = 0; j < 4; ++j) bcol[j] = ldv(bias, (size_t)boff + bn + tx*4 + j);
    #pragma unroll
    for (int i = 0; i < 4; ++i) {
        const int row = bm + ty*4 + i;
        if (row < M) {
            #pragma unroll
            for (int j = 0; j < 4; ++j) {
                float r = acc[i][j] + bcol[j];
                if (act) r = 0.5f * r * (1.0f + erff(r * 0.70710678118654752f));  // exact GELU
                const size_t ci = (size_t)row*N + bn + tx*4 + j;
                if (res) Cf[ci] += r; else Cb[ci] = __float2bfloat16(r);
            }
        }
    }
}

__global__ __launch_bounds__(256) void k_gemm(
    const bf16* __restrict__ A, const void* W, long long woff, const void* bias, long long boff,
    bf16* Cb, float* Cf, int M, int N, int K, int act, int res,
    const int* __restrict__ fl)
{
    if (*fl) gemm_body<float>(A, (const float*)W, woff, (const float*)bias, boff,
                              Cb, Cf, M, N, K, act, res);
    else     gemm_body<bf16>(A, (const bf16*)W, woff, (const bf16*)bias, boff,
                             Cb, Cf, M, N, K, act, res);
}

// ---------------------------------------------------------------- flash attention
// block = 128 threads = 128 queries (thread-per-query, Q and O in registers);
// K/V tiled 64 keys into LDS (padded rows, broadcast reads); online softmax per 16 keys.
#define TQ 128
#define TK 64
__global__ __launch_bounds__(128) void k_attn(
    const bf16* __restrict__ q, const bf16* __restrict__ k,
    const bf16* __restrict__ v, bf16* __restrict__ ao)
{
    __shared__ float Ks[TK][52];   // 52-stride: 16B-aligned rows, bank rotation for staging
    __shared__ float Vs[TK][52];
    const int tid = threadIdx.x;           // 0..127
    const int bh = blockIdx.y;             // 0..15
    const int b = bh >> 3, hh = bh & 7;
    const int qrow = blockIdx.x * TQ + tid;
    const int qr = (qrow < L_) ? qrow : (L_ - 1);
    const size_t base = (size_t)b*L_*HID + hh*HD;
    float qq[48];
    {
        const uint4* qp = reinterpret_cast<const uint4*>(q + base + (size_t)qr*HID);
        #pragma unroll
        for (int i = 0; i < 6; ++i) {
            uint4 u = qp[i];
            const unsigned short* us = reinterpret_cast<const unsigned short*>(&u);
            #pragma unroll
            for (int j = 0; j < 8; ++j) qq[i*8 + j] = us2f(us[j]);
        }
    }
    float oo[48];
    #pragma unroll
    for (int d = 0; d < 48; ++d) oo[d] = 0.f;
    float m = -3.0e38f, l = 0.f;

    for (int kt = 0; kt < L_; kt += TK) {
        const int kmax = min(TK, L_ - kt);   // 64 or 48 (both multiples of 16)
        __syncthreads();
        {   // stage: threads 0..63 -> K rows, 64..127 -> V rows (b128 LDS writes)
            const int r = tid & 63;
            if (r < kmax) {
                const bf16* src = ((tid < 64) ? k : v) + base + (size_t)(kt + r)*HID;
                float* dst = (tid < 64) ? Ks[r] : Vs[r];
                const uint4* sp = reinterpret_cast<const uint4*>(src);
                #pragma unroll
                for (int i = 0; i < 6; ++i) {
                    uint4 u = sp[i];
                    const unsigned short* us = reinterpret_cast<const unsigned short*>(&u);
                    float4 f0 = make_float4(us2f(us[0]), us2f(us[1]), us2f(us[2]), us2f(us[3]));
                    float4 f1 = make_float4(us2f(us[4]), us2f(us[5]), us2f(us[6]), us2f(us[7]));
                    *reinterpret_cast<float4*>(dst + i*8)     = f0;
                    *reinterpret_cast<float4*>(dst + i*8 + 4) = f1;
                }
            }
        }
        __syncthreads();
        for (int s0 = 0; s0 < kmax; s0 += 16) {
            float sv[16];
            #pragma unroll
            for (int j = 0; j < 16; ++j) {
                const float4* kr = reinterpret_cast<const float4*>(Ks[s0 + j]);
                float s = 0.f;
                #pragma unroll
                for (int d4 = 0; d4 < 12; ++d4) {
                    float4 kv = kr[d4];
                    s += qq[4*d4+0]*kv.x + qq[4*d4+1]*kv.y + qq[4*d4+2]*kv.z + qq[4*d4+3]*kv.w;
                }
                sv[j] = s * 0.14433756729740643f;   // 1/sqrt(48)
            }
            float tmax = sv[0];
            #pragma unroll
            for (int j = 1; j < 16; ++j) tmax = fmaxf(tmax, sv[j]);
            const float mn = fmaxf(m, tmax);
            const float alpha = __expf(m - mn);     // exp(-huge)=0 on first tile
            m = mn;
            l *= alpha;
            #pragma unroll
            for (int d = 0; d < 48; ++d) oo[d] *= alpha;
            #pragma unroll
            for (int j = 0; j < 16; ++j) {
                const float p = __expf(sv[j] - m);
                l += p;
                const float4* vr = reinterpret_cast<const float4*>(Vs[s0 + j]);
                #pragma unroll
                for (int d4 = 0; d4 < 12; ++d4) {
                    float4 vv = vr[d4];
                    oo[4*d4+0] += p*vv.x; oo[4*d4+1] += p*vv.y;
                    oo[4*d4+2] += p*vv.z; oo[4*d4+3] += p*vv.w;
                }
            }
        }
    }
    if (qrow < L_) {
        const float inv = 1.0f / l;
        bf16* orow = ao + base + (size_t)qrow*HID;
        #pragma unroll
        for (int i = 0; i < 6; ++i) {
            uint4 u;
            unsigned short* us = reinterpret_cast<unsigned short*>(&u);
            #pragma unroll
            for (int j = 0; j < 8; ++j) us[j] = f2us(oo[i*8 + j] * inv);
            *reinterpret_cast<uint4*>(orow + i*8) = u;
        }
    }
}

// ------------------------------------------------------- final LN + heads
template <typename T, typename TO>
static __device__ void final_body(
    const float* h, const T* fn_g, const T* fn_b,
    const T* on_w, const T* on_b, const T* oe_w, const T* oe_b, TO* out)
{
    __shared__ float hf[HID];
    const int row = blockIdx.x;
    const int b = row / L_, l = row % L_;
    const int lane = threadIdx.x;
    const float* hr = h + (size_t)row*HID;
    float v[6]; float s = 0.f, ss = 0.f;
    #pragma unroll
    for (int j = 0; j < 6; ++j) { float t = hr[lane + j*64]; v[j] = t; s += t; ss += t*t; }
    #pragma unroll
    for (int off = 32; off; off >>= 1) { s += __shfl_xor(s, off); ss += __shfl_xor(ss, off); }
    const float mu = s * (1.0f/HID);
    const float rs = rsqrtf(fmaxf(ss * (1.0f/HID) - mu*mu, 0.0f) + 1e-5f);
    #pragma unroll
    for (int j = 0; j < 6; ++j) {
        int c = lane + j*64;
        hf[c] = (v[j] - mu) * rs * ldv(fn_g, c) + ldv(fn_b, c);
    }
    __syncthreads();
    if (l < N_) {
        if (lane < A_) {
            float acc = ldv(on_b, lane);
            for (int c = 0; c < HID; ++c) acc += hf[c] * ldv(on_w, (size_t)c*A_ + lane);
            stv(out, (size_t)(b*N_ + l)*A_ + lane, acc);
        }
    } else {
        const int e = l - N_;
        if (lane < E_) {
            float acc = ldv(oe_b, lane);
            for (int c = 0; c < HID; ++c) acc += hf[c] * ldv(oe_w, (size_t)c*E_ + lane);
            stv(out, (size_t)B_*N_*A_ + ((size_t)b*N_*N_ + e)*E_ + lane, acc);
        }
    }
}

__global__ __launch_bounds__(64) void k_final(
    const float* __restrict__ h, const void* fn_g, const void* fn_b,
    const void* on_w, const void* on_b, const void* oe_w, const void* oe_b,
    const int* __restrict__ fl, void* out)
{
    if (*fl) final_body<float, float>(h, (const float*)fn_g, (const float*)fn_b,
                                      (const float*)on_w, (const float*)on_b,
                                      (const float*)oe_w, (const float*)oe_b, (float*)out);
    else     final_body<bf16, bf16>(h, (const bf16*)fn_g, (const bf16*)fn_b,
                                    (const bf16*)on_w, (const bf16*)on_b,
                                    (const bf16*)oe_w, (const bf16*)oe_b, (bf16*)out);
}

// ---------------------------------------------------------------- launch
extern "C" void kernel_launch(void* const* d_in, const int* in_sizes, int n_in,
                              void* d_out, int out_size, void* d_ws, size_t ws_size,
                              hipStream_t stream) {
    const void* x      = d_in[0];
    const void* adj    = d_in[1];
    const void* t      = d_in[2];
    const void* node_w = d_in[3];
    const void* node_b = d_in[4];
    const void* edge_w = d_in[5];
    const void* edge_b = d_in[6];
    const void* pos    = d_in[7];
    const void* t_w1   = d_in[8];
    const void* t_b1   = d_in[9];
    const void* t_w2   = d_in[10];
    const void* t_b2   = d_in[11];
    const void* ada1_w = d_in[12];
    const void* ada1_b = d_in[13];
    const void* ada2_w = d_in[14];
    const void* ada2_b = d_in[15];
    const void* q_w    = d_in[16];
    const void* q_b    = d_in[17];
    const void* k_w    = d_in[18];
    const void* k_b    = d_in[19];
    const void* v_w    = d_in[20];
    const void* v_b    = d_in[21];
    const void* o_w    = d_in[22];
    const void* o_b    = d_in[23];
    const void* m1_w   = d_in[24];
    const void* m1_b   = d_in[25];
    const void* m2_w   = d_in[26];
    const void* m2_b   = d_in[27];
    const void* fn_g   = d_in[28];
    const void* fn_b   = d_in[29];
    const void* on_w   = d_in[30];
    const void* on_b   = d_in[31];
    const void* oe_w   = d_in[32];
    const void* oe_b   = d_in[33];

    const size_t SZ = (size_t)M_ * HID;   // 1,806,336 elements
    const size_t NEED = 256 + sizeof(float)*(SZ + 12288) + sizeof(bf16)*4*SZ;  // ~21.7 MB
    if (ws_size < NEED) {
        hipMemsetAsync(d_out, 0, (size_t)out_size*sizeof(bf16), stream);  // 1.14 signature
        return;
    }
    int*   fl  = (int*)d_ws;
    float* h   = (float*)((char*)d_ws + 256);
    float* ada = h + SZ;
    bf16* nb  = (bf16*)(ada + 12288);
    bf16* qb  = nb + SZ;
    bf16* kb  = qb + SZ;
    bf16* vb  = kb + SZ;
    bf16* m1b = kb;   // [2352,1536] bf16 == kb+vb exactly (dead after attention)

    k_detect<<<1, 64, 0, stream>>>(node_w, fl);
    k_embed<<<M_, HID, 0, stream>>>(x, adj, node_w, node_b, edge_w, edge_b, pos, fl, h);
    k_cond<<<B_, 256, 0, stream>>>(t, t_w1, t_b1, t_w2, t_b2,
                                   ada1_w, ada1_b, ada2_w, ada2_b, fl, ada);
    for (int i = 0; i < LYR; ++i) {
        const long long woff   = (long long)i * HID * HID;
        const long long boff   = (long long)i * HID;
        const long long m1woff = (long long)i * HID * MLPD;
        const long long m1boff = (long long)i * MLPD;
        const long long m2woff = (long long)i * MLPD * HID;

        k_adaln<<<M_/4, 256, 0, stream>>>(h, ada, nb, 2*i);
        k_gemm<<<dim3(74, 6), 256, 0, stream>>>(nb, q_w, woff, q_b, boff,
                                                qb, nullptr, M_, HID, HID, 0, 0, fl);
        k_gemm<<<dim3(74, 6), 256, 0, stream>>>(nb, k_w, woff, k_b, boff,
                                                kb, nullptr, M_, HID, HID, 0, 0, fl);
        k_gemm<<<dim3(74, 6), 256, 0, stream>>>(nb, v_w, woff, v_b, boff,
                                                vb, nullptr, M_, HID, HID, 0, 0, fl);
        k_attn<<<dim3((L_ + TQ - 1)/TQ, B_*NHD), TQ, 0, stream>>>(qb, kb, vb, nb);  // ao -> nb
        k_gemm<<<dim3(74, 6), 256, 0, stream>>>(nb, o_w, woff, o_b, boff,
                                                nullptr, h, M_, HID, HID, 0, 1, fl);
        k_adaln<<<M_/4, 256, 0, stream>>>(h, ada, nb, 2*i + 1);            // n2 -> nb
        for (int c = 0; c < 2; ++c) {
            k_gemm<<<dim3(37, 24), 256, 0, stream>>>(nb + (size_t)c*2352*HID,
                                                     m1_w, m1woff, m1_b, m1boff,
                                                     m1b, nullptr, 2352, MLPD, HID, 1, 0, fl);
            k_gemm<<<dim3(37, 6), 256, 0, stream>>>(m1b, m2_w, m2woff, m2_b, boff,
                                                    nullptr, h + (size_t)c*2352*HID,
                                                    2352, HID, MLPD, 0, 1, fl);
        }
    }
    k_final<<<M_, 64, 0, stream>>>(h, fn_g, fn_b, on_w, on_b, oe_w, oe_b, fl, (void*)d_out);
}

// Round 5
// 3167.886 us; speedup vs baseline: 3.1966x; 2.6823x over previous
//
#include <hip/hip_runtime.h>
#include <hip/hip_bf16.h>
#include <math.h>

typedef __hip_bfloat16 bf16;
typedef __attribute__((ext_vector_type(8))) short short8;   // 8 bf16 in 4 VGPRs
typedef __attribute__((ext_vector_type(4))) float f32x4;

#define B_ 2
#define N_ 48
#define A_ 16
#define E_ 5
#define HID 384
#define NHD 8
#define HD 48
#define LYR 4
#define MLPD 1536
#define L_ 2352      // N_ + N_*N_
#define M_ 4704      // B_*L_

static __device__ __forceinline__ float b2f(bf16 v) { return __bfloat162float(v); }
static __device__ __forceinline__ float us2f(unsigned short u) {
    return __uint_as_float(((unsigned)u) << 16);
}
static __device__ __forceinline__ unsigned short f2us(float f) {
    bf16 h = __float2bfloat16(f);
    return *reinterpret_cast<unsigned short*>(&h);
}
static __device__ __forceinline__ float ldv(const float* p, size_t i) { return p[i]; }
static __device__ __forceinline__ float ldv(const bf16*  p, size_t i) { return b2f(p[i]); }
static __device__ __forceinline__ void  stv(float* p, size_t i, float v) { p[i] = v; }
static __device__ __forceinline__ void  stv(bf16*  p, size_t i, float v) { p[i] = __float2bfloat16(v); }
static __device__ __forceinline__ float4 ld4(const float* p, size_t i) {
    return *reinterpret_cast<const float4*>(p + i);
}
static __device__ __forceinline__ float4 ld4(const bf16* p, size_t i) {
    ushort4 u = *reinterpret_cast<const ushort4*>(p + i);
    return make_float4(us2f(u.x), us2f(u.y), us2f(u.z), us2f(u.w));
}

// ------------------------------------------------ dtype detect (flag: 1=fp32, 0=bf16)
__global__ void k_detect(const void* w, int* flag) {
    if (threadIdx.x == 0 && blockIdx.x == 0) {
        const bf16* p = (const bf16*)w;   // node_w: 6144 elems of 0.02*normal
        int isf = 0;
        for (int i = 0; i < 256; ++i) {
            float v = fabsf(b2f(p[i]));
            if (!(v <= 1000.0f)) { isf = 1; break; }
        }
        *flag = isf;
    }
}

// ---------------------------------------------------------------- embed (-> f32 h)
template <typename T>
static __device__ void embed_body(
    const T* x, const T* adj, const T* node_w, const T* node_b,
    const T* edge_w, const T* edge_b, const T* pos, float* h)
{
    const int bl = blockIdx.x;
    const int b = bl / L_, l = bl % L_;
    const int c = threadIdx.x;          // 0..383
    float acc;
    if (l < N_) {
        acc = ldv(node_b, c);
        const size_t xr = (size_t)(b*N_ + l)*A_;
        #pragma unroll
        for (int a = 0; a < A_; ++a) acc += ldv(x, xr + a) * ldv(node_w, (size_t)a*HID + c);
    } else {
        const int e = l - N_;
        acc = ldv(edge_b, c);
        const size_t ar = ((size_t)b*N_*N_ + e)*E_;
        #pragma unroll
        for (int j = 0; j < E_; ++j) acc += ldv(adj, ar + j) * ldv(edge_w, (size_t)j*HID + c);
    }
    h[(size_t)bl*HID + c] = acc + ldv(pos, (size_t)l*HID + c);
}

__global__ __launch_bounds__(384) void k_embed(
    const void* x, const void* adj, const void* node_w, const void* node_b,
    const void* edge_w, const void* edge_b, const void* pos,
    const int* __restrict__ fl, float* __restrict__ h)
{
    if (*fl) embed_body<float>((const float*)x, (const float*)adj, (const float*)node_w,
                               (const float*)node_b, (const float*)edge_w, (const float*)edge_b,
                               (const float*)pos, h);
    else     embed_body<bf16>((const bf16*)x, (const bf16*)adj, (const bf16*)node_w,
                              (const bf16*)node_b, (const bf16*)edge_w, (const bf16*)edge_b,
                              (const bf16*)pos, h);
}

// ------------------------------------------- timestep cond + ada projections (f32)
template <typename T>
static __device__ void cond_body(
    const T* t, const T* t_w1, const T* t_b1, const T* t_w2, const T* t_b2,
    const T* ada1_w, const T* ada1_b, const T* ada2_w, const T* ada2_b,
    float* ada_out)
{
    __shared__ float temb[HID];
    __shared__ float hidden[4*HID];
    __shared__ float cond[HID];
    const int b = blockIdx.x, tid = threadIdx.x;
    const float tv = ldv(t, b);
    for (int c = tid; c < HID; c += 256) {
        int i = (c < 192) ? c : c - 192;
        float f = expf(-9.2103403719761836f * (float)i / 192.0f);
        float ang = tv * f;
        temb[c] = (c < 192) ? sinf(ang) : cosf(ang);
    }
    __syncthreads();
    for (int j = tid; j < 4*HID; j += 256) {
        float acc = ldv(t_b1, j);
        for (int i = 0; i < HID; ++i) acc += temb[i] * ldv(t_w1, (size_t)i*4*HID + j);
        hidden[j] = acc / (1.0f + expf(-acc));   // SiLU
    }
    __syncthreads();
    for (int c = tid; c < HID; c += 256) {
        float acc = ldv(t_b2, c);
        for (int j = 0; j < 4*HID; ++j) acc += hidden[j] * ldv(t_w2, (size_t)j*HID + c);
        cond[c] = acc;
    }
    __syncthreads();
    for (int idx = tid; idx < LYR*2*768; idx += 256) {
        const int layer = idx / 1536;
        const int rem   = idx % 1536;
        const int which = rem / 768;
        const int o     = rem % 768;
        const T* W  = (which ? ada2_w : ada1_w) + (size_t)layer*HID*768;
        const T* Bi = (which ? ada2_b : ada1_b) + layer*768;
        float acc = ldv(Bi, o);
        for (int c = 0; c < HID; ++c) acc += cond[c] * ldv(W, (size_t)c*768 + o);
        ada_out[((size_t)(layer*2 + which)*B_ + b)*768 + o] = acc;
    }
}

__global__ __launch_bounds__(256) void k_cond(
    const void* t, const void* t_w1, const void* t_b1, const void* t_w2, const void* t_b2,
    const void* ada1_w, const void* ada1_b, const void* ada2_w, const void* ada2_b,
    const int* __restrict__ fl, float* __restrict__ ada_out)
{
    if (*fl) cond_body<float>((const float*)t, (const float*)t_w1, (const float*)t_b1,
                              (const float*)t_w2, (const float*)t_b2, (const float*)ada1_w,
                              (const float*)ada1_b, (const float*)ada2_w, (const float*)ada2_b,
                              ada_out);
    else     cond_body<bf16>((const bf16*)t, (const bf16*)t_w1, (const bf16*)t_b1,
                             (const bf16*)t_w2, (const bf16*)t_b2, (const bf16*)ada1_w,
                             (const bf16*)ada1_b, (const bf16*)ada2_w, (const bf16*)ada2_b,
                             ada_out);
}

// ---------------------------------------------------------------- adaLN (f32 h -> bf16 n)
__global__ __launch_bounds__(256) void k_adaln(
    const float* __restrict__ h, const float* __restrict__ ada,
    bf16* __restrict__ n, int slot)
{
    const int row  = blockIdx.x * 4 + (threadIdx.x >> 6);
    const int lane = threadIdx.x & 63;
    const int b = row / L_;
    const float* hr = h + (size_t)row*HID;
    float v[6]; float s = 0.f, ss = 0.f;
    #pragma unroll
    for (int j = 0; j < 6; ++j) { float t = hr[lane + j*64]; v[j] = t; s += t; ss += t*t; }
    #pragma unroll
    for (int off = 32; off; off >>= 1) { s += __shfl_xor(s, off); ss += __shfl_xor(ss, off); }
    const float mu = s * (1.0f/HID);
    const float rs = rsqrtf(fmaxf(ss * (1.0f/HID) - mu*mu, 0.0f) + 1e-5f);
    const float* ap = ada + ((size_t)slot*B_ + b)*768;
    bf16* nr = n + (size_t)row*HID;
    #pragma unroll
    for (int j = 0; j < 6; ++j) {
        int c = lane + j*64;
        nr[c] = __float2bfloat16((v[j] - mu)*rs*(1.0f + ap[c]) + ap[384 + c]);
    }
}

// ------------------------------------------------- GEMM  C = act(A@W + bias)
template <typename T>
static __device__ void gemm_body(
    const bf16* A, const T* W, long long woff, const T* bias, long long boff,
    bf16* Cb, float* Cf, int M, int N, int K, int act, int res)
{
    __shared__ float As[16][68];
    __shared__ float Bs[16][68];
    const int tid = threadIdx.x;
    const int tx = tid & 15, ty = tid >> 4;
    const int bm = blockIdx.x * 64, bn = blockIdx.y * 64;
    const int ar = tid & 63, ak = (tid >> 6) * 4;
    const int bk = tid >> 4, bnn = (tid & 15) * 4;
    const bool avalid = (bm + ar) < M;
    float acc[4][4] = {{0.f,0.f,0.f,0.f},{0.f,0.f,0.f,0.f},{0.f,0.f,0.f,0.f},{0.f,0.f,0.f,0.f}};
    for (int k0 = 0; k0 < K; k0 += 16) {
        float a0=0.f, a1=0.f, a2=0.f, a3=0.f;
        if (avalid) {
            ushort4 av = *reinterpret_cast<const ushort4*>(A + (size_t)(bm + ar)*K + k0 + ak);
            a0 = us2f(av.x); a1 = us2f(av.y); a2 = us2f(av.z); a3 = us2f(av.w);
        }
        const float4 wv = ld4(W, (size_t)woff + (size_t)(k0 + bk)*N + bn + bnn);
        __syncthreads();
        As[ak+0][ar] = a0; As[ak+1][ar] = a1; As[ak+2][ar] = a2; As[ak+3][ar] = a3;
        *reinterpret_cast<float4*>(&Bs[bk][bnn]) = wv;
        __syncthreads();
        #pragma unroll
        for (int kk = 0; kk < 16; ++kk) {
            const float4 a4 = *reinterpret_cast<const float4*>(&As[kk][ty*4]);
            const float4 b4 = *reinterpret_cast<const float4*>(&Bs[kk][tx*4]);
            acc[0][0] += a4.x*b4.x; acc[0][1] += a4.x*b4.y; acc[0][2] += a4.x*b4.z; acc[0][3] += a4.x*b4.w;
            acc[1][0] += a4.y*b4.x; acc[1][1] += a4.y*b4.y; acc[1][2] += a4.y*b4.z; acc[1][3] += a4.y*b4.w;
            acc[2][0] += a4.z*b4.x; acc[2][1] += a4.z*b4.y; acc[2][2] += a4.z*b4.z; acc[2][3] += a4.z*b4.w;
            acc[3][0] += a4.w*b4.x; acc[3][1] += a4.w*b4.y; acc[3][2] += a4.w*b4.z; acc[3][3] += a4.w*b4.w;
        }
    }
    float bcol[4];
    #pragma unroll
    for (int j = 0; j < 4; ++j) bcol[j] = ldv(bias, (size_t)boff + bn + tx*4 + j);
    #pragma unroll
    for (int i = 0; i < 4; ++i) {
        const int row = bm + ty*4 + i;
        if (row < M) {
            #pragma unroll
            for (int j = 0; j < 4; ++j) {
                float r = acc[i][j] + bcol[j];
                if (act) r = 0.5f * r * (1.0f + erff(r * 0.70710678118654752f));
                const size_t ci = (size_t)row*N + bn + tx*4 + j;
                if (res) Cf[ci] += r; else Cb[ci] = __float2bfloat16(r);
            }
        }
    }
}

__global__ __launch_bounds__(256) void k_gemm(
    const bf16* __restrict__ A, const void* W, long long woff, const void* bias, long long boff,
    bf16* Cb, float* Cf, int M, int N, int K, int act, int res,
    const int* __restrict__ fl)
{
    if (*fl) gemm_body<float>(A, (const float*)W, woff, (const float*)bias, boff,
                              Cb, Cf, M, N, K, act, res);
    else     gemm_body<bf16>(A, (const bf16*)W, woff, (const bf16*)bias, boff,
                             Cb, Cf, M, N, K, act, res);
}

// ---------------------------------------------------------------- MFMA flash attention
// Transposed formulation: S^T = K·Q^T, O^T = V^T·P^T  (mfma_f32_16x16x32_bf16).
// Softmax state is per-query = per-lane-column (lane&15): one alpha per lane,
// row-max reduce = shfl_xor(16)+shfl_xor(32) across the 4 quads.
// Block = 256 threads = 4 waves; each wave owns 16 queries; K/V staged per block.
// Fragment maps (m89/m120-verified): A[m=lane&15][k=quad*8+j], B[k=quad*8+j][n=lane&15],
// C/D: row=quad*4+reg, col=lane&15.
__global__ __launch_bounds__(256) void k_attn(
    const bf16* __restrict__ q, const bf16* __restrict__ k,
    const bf16* __restrict__ v, bf16* __restrict__ ao)
{
    __shared__ __align__(16) unsigned short Ks[32][72];      // [key][d0..63 padded]
    __shared__ __align__(16) unsigned short Vt[48][56];      // [d][key0..31 padded]
    __shared__ __align__(16) unsigned short Pq[4][16][56];   // per wave: [query][key]
    const int tid  = threadIdx.x;
    const int wv   = tid >> 6;
    const int lane = tid & 63;
    const int quad = lane >> 4, c = lane & 15;
    const int bh = blockIdx.y;
    const int b = bh >> 3, hh = bh & 7;
    const size_t base = (size_t)b*L_*HID + hh*HD;
    const int q0 = blockIdx.x*64 + wv*16;
    const bool qvalid = q0 < L_;                 // wave-uniform
    const int qrow = qvalid ? (q0 + c) : c;

    // Q^T B-fragments in registers: qf[h] -> B[k=d=h*32+quad*8+j][n=query c]
    short8 qf0, qf1;
    {
        const unsigned short* qp = (const unsigned short*)(q + base + (size_t)qrow*HID);
        qf0 = *reinterpret_cast<const short8*>(qp + quad*8);               // d 0..31
        if (quad < 2) qf1 = *reinterpret_cast<const short8*>(qp + 32 + quad*8);  // d 32..47
        else          qf1 = short8{0,0,0,0,0,0,0,0};                       // d 48..63 pad
    }
    f32x4 o0 = {0.f,0.f,0.f,0.f}, o1 = {0.f,0.f,0.f,0.f}, o2 = {0.f,0.f,0.f,0.f};
    float m = -3.0e38f, lp = 0.f;

    for (int kt = 0; kt < L_; kt += 32) {
        __syncthreads();
        // ---- stage K-tile [32 keys][d 0..47 data, 48..63 zeros]
        if (tid < 192) {
            const int row = tid / 6, ch = tid % 6;
            const int key = kt + row;
            short8 val = short8{0,0,0,0,0,0,0,0};
            if (key < L_)
                val = *reinterpret_cast<const short8*>(
                        (const unsigned short*)(k + base + (size_t)key*HID) + ch*8);
            *reinterpret_cast<short8*>(&Ks[row][ch*8]) = val;
        } else {
            const int t2 = tid - 192;
            const int row = t2 >> 1, ch = 6 + (t2 & 1);
            *reinterpret_cast<short8*>(&Ks[row][ch*8]) = short8{0,0,0,0,0,0,0,0};
        }
        // ---- stage V transposed: Vt[d][key]
        for (int idx = tid; idx < 1536; idx += 256) {
            const int key = idx / 48, d = idx % 48;
            const int gk = kt + key;
            unsigned short val = 0;
            if (gk < L_) val = ((const unsigned short*)(v + base))[(size_t)gk*HID + d];
            Vt[d][key] = val;
        }
        __syncthreads();

        // ---- S^T tiles (t: keys kt+t*16 .. +15)
        f32x4 s[2];
        #pragma unroll
        for (int t = 0; t < 2; ++t) {
            f32x4 acc = {0.f,0.f,0.f,0.f};
            short8 a0 = *reinterpret_cast<const short8*>(&Ks[t*16 + c][quad*8]);       // d 0..31
            short8 a1 = *reinterpret_cast<const short8*>(&Ks[t*16 + c][32 + quad*8]);  // d 32..63
            acc = __builtin_amdgcn_mfma_f32_16x16x32_bf16(a0, qf0, acc, 0, 0, 0);
            acc = __builtin_amdgcn_mfma_f32_16x16x32_bf16(a1, qf1, acc, 0, 0, 0);
            s[t] = acc;
        }
        // ---- scale + mask + online softmax (query = col c; keys = kt+t*16+quad*4+r)
        float sv[8];
        float tmax = -3.0e38f;
        #pragma unroll
        for (int t = 0; t < 2; ++t)
            #pragma unroll
            for (int r = 0; r < 4; ++r) {
                const int key = kt + t*16 + quad*4 + r;
                const float val = (key < L_) ? s[t][r] * 0.14433756729740643f : -3.0e38f;
                sv[t*4 + r] = val;
                tmax = fmaxf(tmax, val);
            }
        tmax = fmaxf(tmax, __shfl_xor(tmax, 16));
        tmax = fmaxf(tmax, __shfl_xor(tmax, 32));
        const float mn = fmaxf(m, tmax);
        const float alpha = __expf(m - mn);
        m = mn;
        float psum = 0.f;
        unsigned short pv[8];
        #pragma unroll
        for (int i = 0; i < 8; ++i) {
            const float p = __expf(sv[i] - m);
            psum += p;
            pv[i] = f2us(p);
        }
        lp = lp * alpha + psum;
        o0 *= alpha; o1 *= alpha; o2 *= alpha;
        // ---- P -> LDS (per-wave buffer; same-wave rw, no barrier needed)
        #pragma unroll
        for (int t = 0; t < 2; ++t) {
            ushort4 w4 = make_ushort4(pv[t*4+0], pv[t*4+1], pv[t*4+2], pv[t*4+3]);
            *reinterpret_cast<ushort4*>(&Pq[wv][c][t*16 + quad*4]) = w4;
        }
        // ---- O^T += V^T · P^T
        short8 pf  = *reinterpret_cast<const short8*>(&Pq[wv][c][quad*8]);
        short8 vf0 = *reinterpret_cast<const short8*>(&Vt[c][quad*8]);
        short8 vf1 = *reinterpret_cast<const short8*>(&Vt[16 + c][quad*8]);
        short8 vf2 = *reinterpret_cast<const short8*>(&Vt[32 + c][quad*8]);
        o0 = __builtin_amdgcn_mfma_f32_16x16x32_bf16(vf0, pf, o0, 0, 0, 0);
        o1 = __builtin_amdgcn_mfma_f32_16x16x32_bf16(vf1, pf, o1, 0, 0, 0);
        o2 = __builtin_amdgcn_mfma_f32_16x16x32_bf16(vf2, pf, o2, 0, 0, 0);
    }
    // ---- finalize: l = sum over quads; write O^T (lane: query c, d = dt*16+quad*4+r)
    float l = lp;
    l += __shfl_xor(l, 16);
    l += __shfl_xor(l, 32);
    const float inv = 1.0f / l;
    if (qvalid) {
        unsigned short* orow = (unsigned short*)(ao + base + (size_t)(q0 + c)*HID);
        const f32x4 ot[3] = {o0, o1, o2};
        #pragma unroll
        for (int dt = 0; dt < 3; ++dt) {
            ushort4 w4;
            w4.x = f2us(ot[dt][0] * inv);
            w4.y = f2us(ot[dt][1] * inv);
            w4.z = f2us(ot[dt][2] * inv);
            w4.w = f2us(ot[dt][3] * inv);
            *reinterpret_cast<ushort4*>(orow + dt*16 + quad*4) = w4;
        }
    }
}

// ------------------------------------------------------- final LN + heads
template <typename T, typename TO>
static __device__ void final_body(
    const float* h, const T* fn_g, const T* fn_b,
    const T* on_w, const T* on_b, const T* oe_w, const T* oe_b, TO* out)
{
    __shared__ float hf[HID];
    const int row = blockIdx.x;
    const int b = row / L_, l = row % L_;
    const int lane = threadIdx.x;
    const float* hr = h + (size_t)row*HID;
    float v[6]; float s = 0.f, ss = 0.f;
    #pragma unroll
    for (int j = 0; j < 6; ++j) { float t = hr[lane + j*64]; v[j] = t; s += t; ss += t*t; }
    #pragma unroll
    for (int off = 32; off; off >>= 1) { s += __shfl_xor(s, off); ss += __shfl_xor(ss, off); }
    const float mu = s * (1.0f/HID);
    const float rs = rsqrtf(fmaxf(ss * (1.0f/HID) - mu*mu, 0.0f) + 1e-5f);
    #pragma unroll
    for (int j = 0; j < 6; ++j) {
        int c = lane + j*64;
        hf[c] = (v[j] - mu) * rs * ldv(fn_g, c) + ldv(fn_b, c);
    }
    __syncthreads();
    if (l < N_) {
        if (lane < A_) {
            float acc = ldv(on_b, lane);
            for (int c = 0; c < HID; ++c) acc += hf[c] * ldv(on_w, (size_t)c*A_ + lane);
            stv(out, (size_t)(b*N_ + l)*A_ + lane, acc);
        }
    } else {
        const int e = l - N_;
        if (lane < E_) {
            float acc = ldv(oe_b, lane);
            for (int c = 0; c < HID; ++c) acc += hf[c] * ldv(oe_w, (size_t)c*E_ + lane);
            stv(out, (size_t)B_*N_*A_ + ((size_t)b*N_*N_ + e)*E_ + lane, acc);
        }
    }
}

__global__ __launch_bounds__(64) void k_final(
    const float* __restrict__ h, const void* fn_g, const void* fn_b,
    const void* on_w, const void* on_b, const void* oe_w, const void* oe_b,
    const int* __restrict__ fl, void* out)
{
    if (*fl) final_body<float, float>(h, (const float*)fn_g, (const float*)fn_b,
                                      (const float*)on_w, (const float*)on_b,
                                      (const float*)oe_w, (const float*)oe_b, (float*)out);
    else     final_body<bf16, bf16>(h, (const bf16*)fn_g, (const bf16*)fn_b,
                                    (const bf16*)on_w, (const bf16*)on_b,
                                    (const bf16*)oe_w, (const bf16*)oe_b, (bf16*)out);
}

// ---------------------------------------------------------------- launch
extern "C" void kernel_launch(void* const* d_in, const int* in_sizes, int n_in,
                              void* d_out, int out_size, void* d_ws, size_t ws_size,
                              hipStream_t stream) {
    const void* x      = d_in[0];
    const void* adj    = d_in[1];
    const void* t      = d_in[2];
    const void* node_w = d_in[3];
    const void* node_b = d_in[4];
    const void* edge_w = d_in[5];
    const void* edge_b = d_in[6];
    const void* pos    = d_in[7];
    const void* t_w1   = d_in[8];
    const void* t_b1   = d_in[9];
    const void* t_w2   = d_in[10];
    const void* t_b2   = d_in[11];
    const void* ada1_w = d_in[12];
    const void* ada1_b = d_in[13];
    const void* ada2_w = d_in[14];
    const void* ada2_b = d_in[15];
    const void* q_w    = d_in[16];
    const void* q_b    = d_in[17];
    const void* k_w    = d_in[18];
    const void* k_b    = d_in[19];
    const void* v_w    = d_in[20];
    const void* v_b    = d_in[21];
    const void* o_w    = d_in[22];
    const void* o_b    = d_in[23];
    const void* m1_w   = d_in[24];
    const void* m1_b   = d_in[25];
    const void* m2_w   = d_in[26];
    const void* m2_b   = d_in[27];
    const void* fn_g   = d_in[28];
    const void* fn_b   = d_in[29];
    const void* on_w   = d_in[30];
    const void* on_b   = d_in[31];
    const void* oe_w   = d_in[32];
    const void* oe_b   = d_in[33];

    const size_t SZ = (size_t)M_ * HID;   // 1,806,336 elements
    const size_t NEED = 256 + sizeof(float)*(SZ + 12288) + sizeof(bf16)*4*SZ;  // ~21.7 MB
    if (ws_size < NEED) {
        hipMemsetAsync(d_out, 0, (size_t)out_size*sizeof(bf16), stream);  // 1.14 signature
        return;
    }
    int*   fl  = (int*)d_ws;
    float* h   = (float*)((char*)d_ws + 256);
    float* ada = h + SZ;
    bf16* nb  = (bf16*)(ada + 12288);
    bf16* qb  = nb + SZ;
    bf16* kb  = qb + SZ;
    bf16* vb  = kb + SZ;
    bf16* m1b = kb;   // [2352,1536] bf16 == kb+vb exactly (dead after attention)

    k_detect<<<1, 64, 0, stream>>>(node_w, fl);
    k_embed<<<M_, HID, 0, stream>>>(x, adj, node_w, node_b, edge_w, edge_b, pos, fl, h);
    k_cond<<<B_, 256, 0, stream>>>(t, t_w1, t_b1, t_w2, t_b2,
                                   ada1_w, ada1_b, ada2_w, ada2_b, fl, ada);
    for (int i = 0; i < LYR; ++i) {
        const long long woff   = (long long)i * HID * HID;
        const long long boff   = (long long)i * HID;
        const long long m1woff = (long long)i * HID * MLPD;
        const long long m1boff = (long long)i * MLPD;
        const long long m2woff = (long long)i * MLPD * HID;

        k_adaln<<<M_/4, 256, 0, stream>>>(h, ada, nb, 2*i);
        k_gemm<<<dim3(74, 6), 256, 0, stream>>>(nb, q_w, woff, q_b, boff,
                                                qb, nullptr, M_, HID, HID, 0, 0, fl);
        k_gemm<<<dim3(74, 6), 256, 0, stream>>>(nb, k_w, woff, k_b, boff,
                                                kb, nullptr, M_, HID, HID, 0, 0, fl);
        k_gemm<<<dim3(74, 6), 256, 0, stream>>>(nb, v_w, woff, v_b, boff,
                                                vb, nullptr, M_, HID, HID, 0, 0, fl);
        k_attn<<<dim3(37, B_*NHD), 256, 0, stream>>>(qb, kb, vb, nb);      // ao -> nb
        k_gemm<<<dim3(74, 6), 256, 0, stream>>>(nb, o_w, woff, o_b, boff,
                                                nullptr, h, M_, HID, HID, 0, 1, fl);
        k_adaln<<<M_/4, 256, 0, stream>>>(h, ada, nb, 2*i + 1);            // n2 -> nb
        for (int c = 0; c < 2; ++c) {
            k_gemm<<<dim3(37, 24), 256, 0, stream>>>(nb + (size_t)c*2352*HID,
                                                     m1_w, m1woff, m1_b, m1boff,
                                                     m1b, nullptr, 2352, MLPD, HID, 1, 0, fl);
            k_gemm<<<dim3(37, 6), 256, 0, stream>>>(m1b, m2_w, m2woff, m2_b, boff,
                                                    nullptr, h + (size_t)c*2352*HID,
                                                    2352, HID, MLPD, 0, 1, fl);
        }
    }
    k_final<<<M_, 64, 0, stream>>>(h, fn_g, fn_b, on_w, on_b, oe_w, oe_b, fl, (void*)d_out);
}

// Round 6
// 1838.670 us; speedup vs baseline: 5.5074x; 1.7229x over previous
//
#include <hip/hip_runtime.h>
#include <hip/hip_bf16.h>
#include <math.h>

typedef __hip_bfloat16 bf16;
typedef __attribute__((ext_vector_type(8))) short short8;   // 8 bf16 in 4 VGPRs
typedef __attribute__((ext_vector_type(4))) float f32x4;

#define B_ 2
#define N_ 48
#define A_ 16
#define E_ 5
#define HID 384
#define NHD 8
#define HD 48
#define LYR 4
#define MLPD 1536
#define L_ 2352      // N_ + N_*N_
#define M_ 4704      // B_*L_

static __device__ __forceinline__ float b2f(bf16 v) { return __bfloat162float(v); }
static __device__ __forceinline__ float us2f(unsigned short u) {
    return __uint_as_float(((unsigned)u) << 16);
}
static __device__ __forceinline__ unsigned short f2us(float f) {
    bf16 h = __float2bfloat16(f);
    return *reinterpret_cast<unsigned short*>(&h);
}
static __device__ __forceinline__ float ldv(const float* p, size_t i) { return p[i]; }
static __device__ __forceinline__ float ldv(const bf16*  p, size_t i) { return b2f(p[i]); }
static __device__ __forceinline__ void  stv(float* p, size_t i, float v) { p[i] = v; }
static __device__ __forceinline__ void  stv(bf16*  p, size_t i, float v) { p[i] = __float2bfloat16(v); }
static __device__ __forceinline__ float4 ld4(const float* p, size_t i) {
    return *reinterpret_cast<const float4*>(p + i);
}
static __device__ __forceinline__ float4 ld4(const bf16* p, size_t i) {
    ushort4 u = *reinterpret_cast<const ushort4*>(p + i);
    return make_float4(us2f(u.x), us2f(u.y), us2f(u.z), us2f(u.w));
}

// ------------------------------------------------ dtype detect (flag: 1=fp32, 0=bf16)
__global__ void k_detect(const void* w, int* flag) {
    if (threadIdx.x == 0 && blockIdx.x == 0) {
        const bf16* p = (const bf16*)w;   // node_w: 6144 elems of 0.02*normal
        int isf = 0;
        for (int i = 0; i < 256; ++i) {
            float v = fabsf(b2f(p[i]));
            if (!(v <= 1000.0f)) { isf = 1; break; }
        }
        *flag = isf;
    }
}

// ---------------------------------------------------------------- embed (-> f32 h)
template <typename T>
static __device__ void embed_body(
    const T* x, const T* adj, const T* node_w, const T* node_b,
    const T* edge_w, const T* edge_b, const T* pos, float* h)
{
    const int bl = blockIdx.x;
    const int b = bl / L_, l = bl % L_;
    const int c = threadIdx.x;          // 0..383
    float acc;
    if (l < N_) {
        acc = ldv(node_b, c);
        const size_t xr = (size_t)(b*N_ + l)*A_;
        #pragma unroll
        for (int a = 0; a < A_; ++a) acc += ldv(x, xr + a) * ldv(node_w, (size_t)a*HID + c);
    } else {
        const int e = l - N_;
        acc = ldv(edge_b, c);
        const size_t ar = ((size_t)b*N_*N_ + e)*E_;
        #pragma unroll
        for (int j = 0; j < E_; ++j) acc += ldv(adj, ar + j) * ldv(edge_w, (size_t)j*HID + c);
    }
    h[(size_t)bl*HID + c] = acc + ldv(pos, (size_t)l*HID + c);
}

__global__ __launch_bounds__(384) void k_embed(
    const void* x, const void* adj, const void* node_w, const void* node_b,
    const void* edge_w, const void* edge_b, const void* pos,
    const int* __restrict__ fl, float* __restrict__ h)
{
    if (*fl) embed_body<float>((const float*)x, (const float*)adj, (const float*)node_w,
                               (const float*)node_b, (const float*)edge_w, (const float*)edge_b,
                               (const float*)pos, h);
    else     embed_body<bf16>((const bf16*)x, (const bf16*)adj, (const bf16*)node_w,
                              (const bf16*)node_b, (const bf16*)edge_w, (const bf16*)edge_b,
                              (const bf16*)pos, h);
}

// ---------------------------------------- cond stage 1: temb -> hidden (SiLU)
// grid (B_, 6), block 256: each block computes 256 of the 1536 hidden outputs.
template <typename T>
static __device__ void cond1_body(const T* t, const T* t_w1, const T* t_b1, float* hid)
{
    __shared__ float temb[HID];
    const int b = blockIdx.x, tid = threadIdx.x;
    const float tv = ldv(t, b);
    for (int c = tid; c < HID; c += 256) {
        int i = (c < 192) ? c : c - 192;
        float f = expf(-9.2103403719761836f * (float)i / 192.0f);
        float ang = tv * f;
        temb[c] = (c < 192) ? sinf(ang) : cosf(ang);
    }
    __syncthreads();
    const int j = blockIdx.y * 256 + tid;
    float acc = ldv(t_b1, j);
    for (int i = 0; i < HID; ++i) acc += temb[i] * ldv(t_w1, (size_t)i*4*HID + j);
    hid[(size_t)b*4*HID + j] = acc / (1.0f + expf(-acc));   // SiLU
}

__global__ __launch_bounds__(256) void k_cond1(
    const void* t, const void* t_w1, const void* t_b1,
    const int* __restrict__ fl, float* __restrict__ hid)
{
    if (*fl) cond1_body<float>((const float*)t, (const float*)t_w1, (const float*)t_b1, hid);
    else     cond1_body<bf16>((const bf16*)t, (const bf16*)t_w1, (const bf16*)t_b1, hid);
}

// ---------------------------------------- cond stage 2: hidden -> cond[b][384]
// grid (B_), block 384.
template <typename T>
static __device__ void cond2_body(const T* t_w2, const T* t_b2, const float* hid, float* cnd)
{
    const int b = blockIdx.x, c = threadIdx.x;
    const float* hb = hid + (size_t)b*4*HID;
    float acc = ldv(t_b2, c);
    for (int j = 0; j < 4*HID; ++j) acc += hb[j] * ldv(t_w2, (size_t)j*HID + c);
    cnd[(size_t)b*HID + c] = acc;
}

__global__ __launch_bounds__(384) void k_cond2(
    const void* t_w2, const void* t_b2, const int* __restrict__ fl,
    const float* __restrict__ hid, float* __restrict__ cnd)
{
    if (*fl) cond2_body<float>((const float*)t_w2, (const float*)t_b2, hid, cnd);
    else     cond2_body<bf16>((const bf16*)t_w2, (const bf16*)t_b2, hid, cnd);
}

// ---------------------------------------- cond stage 3: ada projections
// grid (24, B_): blockIdx.x = slot*3 + chunk; 256 threads, each one output of 768.
template <typename T>
static __device__ void cond3_body(
    const T* ada1_w, const T* ada1_b, const T* ada2_w, const T* ada2_b,
    const float* cnd, float* ada_out)
{
    __shared__ float cs[HID];
    const int slot = blockIdx.x / 3, ob = blockIdx.x % 3, b = blockIdx.y;
    const int tid = threadIdx.x;
    for (int c = tid; c < HID; c += 256) cs[c] = cnd[(size_t)b*HID + c];
    __syncthreads();
    const int layer = slot >> 1, which = slot & 1;
    const int o = ob*256 + tid;
    const T* W  = which ? ada2_w : ada1_w;
    const T* Bi = which ? ada2_b : ada1_b;
    float acc = ldv(Bi, (size_t)layer*768 + o);
    const size_t wb = (size_t)layer*HID*768 + o;
    for (int c = 0; c < HID; ++c) acc += cs[c] * ldv(W, wb + (size_t)c*768);
    ada_out[((size_t)slot*B_ + b)*768 + o] = acc;
}

__global__ __launch_bounds__(256) void k_cond3(
    const void* ada1_w, const void* ada1_b, const void* ada2_w, const void* ada2_b,
    const int* __restrict__ fl, const float* __restrict__ cnd, float* __restrict__ ada_out)
{
    if (*fl) cond3_body<float>((const float*)ada1_w, (const float*)ada1_b,
                               (const float*)ada2_w, (const float*)ada2_b, cnd, ada_out);
    else     cond3_body<bf16>((const bf16*)ada1_w, (const bf16*)ada1_b,
                              (const bf16*)ada2_w, (const bf16*)ada2_b, cnd, ada_out);
}

// ---------------------------------------------------------------- adaLN (f32 h -> bf16 n)
__global__ __launch_bounds__(256) void k_adaln(
    const float* __restrict__ h, const float* __restrict__ ada,
    bf16* __restrict__ n, int slot)
{
    const int row  = blockIdx.x * 4 + (threadIdx.x >> 6);
    const int lane = threadIdx.x & 63;
    const int b = row / L_;
    const float* hr = h + (size_t)row*HID;
    float v[6]; float s = 0.f, ss = 0.f;
    #pragma unroll
    for (int j = 0; j < 6; ++j) { float t = hr[lane + j*64]; v[j] = t; s += t; ss += t*t; }
    #pragma unroll
    for (int off = 32; off; off >>= 1) { s += __shfl_xor(s, off); ss += __shfl_xor(ss, off); }
    const float mu = s * (1.0f/HID);
    const float rs = rsqrtf(fmaxf(ss * (1.0f/HID) - mu*mu, 0.0f) + 1e-5f);
    const float* ap = ada + ((size_t)slot*B_ + b)*768;
    bf16* nr = n + (size_t)row*HID;
    #pragma unroll
    for (int j = 0; j < 6; ++j) {
        int c = lane + j*64;
        nr[c] = __float2bfloat16((v[j] - mu)*rs*(1.0f + ap[c]) + ap[384 + c]);
    }
}

// ------------------------------------------------- MFMA GEMM  C = act(A@W + bias)
// A: [M,K] bf16 (internal). W/bias: input dtype (fp32 weights converted to bf16
// during LDS staging). Tile 64x64, BK=32, 4 waves in 2x2, each wave 2x2 mfma
// 16x16x32. Fragment maps (m89-verified, same as k_attn): A[m=lane&15][k=quad*8+j],
// B[k=quad*8+j][n=lane&15], C/D row=quad*4+reg, col=lane&15.
template <typename T>
static __device__ void gemm_body(
    const bf16* A, const T* W, long long woff, const T* bias, long long boff,
    bf16* Cb, float* Cf, int M, int N, int K, int act, int res)
{
    __shared__ __align__(16) unsigned short As[64][40];   // [m][k], 80B rows (16B-aligned)
    __shared__ __align__(16) unsigned short Bt[64][40];   // [n][k]
    const int tid  = threadIdx.x;
    const int wv   = tid >> 6, lane = tid & 63;
    const int quad = lane >> 4, c = lane & 15;
    const int wm = wv & 1, wn = wv >> 1;
    const int bm = blockIdx.x * 64, bn = blockIdx.y * 64;
    const int sar = tid >> 2, sac = (tid & 3) * 8;    // A staging: row, k-offset
    const int swk = tid & 31, swn = (tid >> 5) * 8;   // W staging: k, n-offset
    f32x4 acc[2][2] = {{{0.f,0.f,0.f,0.f},{0.f,0.f,0.f,0.f}},
                       {{0.f,0.f,0.f,0.f},{0.f,0.f,0.f,0.f}}};
    for (int k0 = 0; k0 < K; k0 += 32) {
        short8 av = short8{0,0,0,0,0,0,0,0};
        if (bm + sar < M)
            av = *reinterpret_cast<const short8*>(A + (size_t)(bm + sar)*K + k0 + sac);
        const size_t wrow = (size_t)woff + (size_t)(k0 + swk)*N + bn + swn;
        const float4 w0 = ld4(W, wrow);
        const float4 w1 = ld4(W, wrow + 4);
        __syncthreads();
        *reinterpret_cast<short8*>(&As[sar][sac]) = av;
        Bt[swn+0][swk] = f2us(w0.x); Bt[swn+1][swk] = f2us(w0.y);
        Bt[swn+2][swk] = f2us(w0.z); Bt[swn+3][swk] = f2us(w0.w);
        Bt[swn+4][swk] = f2us(w1.x); Bt[swn+5][swk] = f2us(w1.y);
        Bt[swn+6][swk] = f2us(w1.z); Bt[swn+7][swk] = f2us(w1.w);
        __syncthreads();
        short8 af[2], bfr[2];
        #pragma unroll
        for (int mi = 0; mi < 2; ++mi)
            af[mi] = *reinterpret_cast<const short8*>(&As[wm*32 + mi*16 + c][quad*8]);
        #pragma unroll
        for (int ni = 0; ni < 2; ++ni)
            bfr[ni] = *reinterpret_cast<const short8*>(&Bt[wn*32 + ni*16 + c][quad*8]);
        #pragma unroll
        for (int mi = 0; mi < 2; ++mi)
            #pragma unroll
            for (int ni = 0; ni < 2; ++ni)
                acc[mi][ni] = __builtin_amdgcn_mfma_f32_16x16x32_bf16(
                                  af[mi], bfr[ni], acc[mi][ni], 0, 0, 0);
    }
    float bcol[2];
    #pragma unroll
    for (int ni = 0; ni < 2; ++ni)
        bcol[ni] = ldv(bias, (size_t)boff + bn + wn*32 + ni*16 + c);
    #pragma unroll
    for (int mi = 0; mi < 2; ++mi)
        #pragma unroll
        for (int ni = 0; ni < 2; ++ni) {
            const int col = bn + wn*32 + ni*16 + c;
            #pragma unroll
            for (int r = 0; r < 4; ++r) {
                const int row = bm + wm*32 + mi*16 + quad*4 + r;
                if (row < M) {
                    float v = acc[mi][ni][r] + bcol[ni];
                    if (act) v = 0.5f * v * (1.0f + erff(v * 0.70710678118654752f));  // GELU
                    const size_t ci = (size_t)row*N + col;
                    if (res) Cf[ci] += v; else Cb[ci] = __float2bfloat16(v);
                }
            }
        }
}

__global__ __launch_bounds__(256) void k_gemm(
    const bf16* __restrict__ A, const void* W, long long woff, const void* bias, long long boff,
    bf16* Cb, float* Cf, int M, int N, int K, int act, int res,
    const int* __restrict__ fl)
{
    if (*fl) gemm_body<float>(A, (const float*)W, woff, (const float*)bias, boff,
                              Cb, Cf, M, N, K, act, res);
    else     gemm_body<bf16>(A, (const bf16*)W, woff, (const bf16*)bias, boff,
                             Cb, Cf, M, N, K, act, res);
}

// ---------------------------------------------------------------- MFMA flash attention
// (unchanged from round 5 — verified correct)
__global__ __launch_bounds__(256) void k_attn(
    const bf16* __restrict__ q, const bf16* __restrict__ k,
    const bf16* __restrict__ v, bf16* __restrict__ ao)
{
    __shared__ __align__(16) unsigned short Ks[32][72];      // [key][d0..63 padded]
    __shared__ __align__(16) unsigned short Vt[48][56];      // [d][key0..31 padded]
    __shared__ __align__(16) unsigned short Pq[4][16][56];   // per wave: [query][key]
    const int tid  = threadIdx.x;
    const int wv   = tid >> 6;
    const int lane = tid & 63;
    const int quad = lane >> 4, c = lane & 15;
    const int bh = blockIdx.y;
    const int b = bh >> 3, hh = bh & 7;
    const size_t base = (size_t)b*L_*HID + hh*HD;
    const int q0 = blockIdx.x*64 + wv*16;
    const bool qvalid = q0 < L_;                 // wave-uniform
    const int qrow = qvalid ? (q0 + c) : c;

    short8 qf0, qf1;
    {
        const unsigned short* qp = (const unsigned short*)(q + base + (size_t)qrow*HID);
        qf0 = *reinterpret_cast<const short8*>(qp + quad*8);               // d 0..31
        if (quad < 2) qf1 = *reinterpret_cast<const short8*>(qp + 32 + quad*8);  // d 32..47
        else          qf1 = short8{0,0,0,0,0,0,0,0};                       // d 48..63 pad
    }
    f32x4 o0 = {0.f,0.f,0.f,0.f}, o1 = {0.f,0.f,0.f,0.f}, o2 = {0.f,0.f,0.f,0.f};
    float m = -3.0e38f, lp = 0.f;

    for (int kt = 0; kt < L_; kt += 32) {
        __syncthreads();
        if (tid < 192) {
            const int row = tid / 6, ch = tid % 6;
            const int key = kt + row;
            short8 val = short8{0,0,0,0,0,0,0,0};
            if (key < L_)
                val = *reinterpret_cast<const short8*>(
                        (const unsigned short*)(k + base + (size_t)key*HID) + ch*8);
            *reinterpret_cast<short8*>(&Ks[row][ch*8]) = val;
        } else {
            const int t2 = tid - 192;
            const int row = t2 >> 1, ch = 6 + (t2 & 1);
            *reinterpret_cast<short8*>(&Ks[row][ch*8]) = short8{0,0,0,0,0,0,0,0};
        }
        for (int idx = tid; idx < 1536; idx += 256) {
            const int key = idx / 48, d = idx % 48;
            const int gk = kt + key;
            unsigned short val = 0;
            if (gk < L_) val = ((const unsigned short*)(v + base))[(size_t)gk*HID + d];
            Vt[d][key] = val;
        }
        __syncthreads();

        f32x4 s[2];
        #pragma unroll
        for (int t = 0; t < 2; ++t) {
            f32x4 acc = {0.f,0.f,0.f,0.f};
            short8 a0 = *reinterpret_cast<const short8*>(&Ks[t*16 + c][quad*8]);
            short8 a1 = *reinterpret_cast<const short8*>(&Ks[t*16 + c][32 + quad*8]);
            acc = __builtin_amdgcn_mfma_f32_16x16x32_bf16(a0, qf0, acc, 0, 0, 0);
            acc = __builtin_amdgcn_mfma_f32_16x16x32_bf16(a1, qf1, acc, 0, 0, 0);
            s[t] = acc;
        }
        float sv[8];
        float tmax = -3.0e38f;
        #pragma unroll
        for (int t = 0; t < 2; ++t)
            #pragma unroll
            for (int r = 0; r < 4; ++r) {
                const int key = kt + t*16 + quad*4 + r;
                const float val = (key < L_) ? s[t][r] * 0.14433756729740643f : -3.0e38f;
                sv[t*4 + r] = val;
                tmax = fmaxf(tmax, val);
            }
        tmax = fmaxf(tmax, __shfl_xor(tmax, 16));
        tmax = fmaxf(tmax, __shfl_xor(tmax, 32));
        const float mn = fmaxf(m, tmax);
        const float alpha = __expf(m - mn);
        m = mn;
        float psum = 0.f;
        unsigned short pv[8];
        #pragma unroll
        for (int i = 0; i < 8; ++i) {
            const float p = __expf(sv[i] - m);
            psum += p;
            pv[i] = f2us(p);
        }
        lp = lp * alpha + psum;
        o0 *= alpha; o1 *= alpha; o2 *= alpha;
        #pragma unroll
        for (int t = 0; t < 2; ++t) {
            ushort4 w4 = make_ushort4(pv[t*4+0], pv[t*4+1], pv[t*4+2], pv[t*4+3]);
            *reinterpret_cast<ushort4*>(&Pq[wv][c][t*16 + quad*4]) = w4;
        }
        short8 pf  = *reinterpret_cast<const short8*>(&Pq[wv][c][quad*8]);
        short8 vf0 = *reinterpret_cast<const short8*>(&Vt[c][quad*8]);
        short8 vf1 = *reinterpret_cast<const short8*>(&Vt[16 + c][quad*8]);
        short8 vf2 = *reinterpret_cast<const short8*>(&Vt[32 + c][quad*8]);
        o0 = __builtin_amdgcn_mfma_f32_16x16x32_bf16(vf0, pf, o0, 0, 0, 0);
        o1 = __builtin_amdgcn_mfma_f32_16x16x32_bf16(vf1, pf, o1, 0, 0, 0);
        o2 = __builtin_amdgcn_mfma_f32_16x16x32_bf16(vf2, pf, o2, 0, 0, 0);
    }
    float l = lp;
    l += __shfl_xor(l, 16);
    l += __shfl_xor(l, 32);
    const float inv = 1.0f / l;
    if (qvalid) {
        unsigned short* orow = (unsigned short*)(ao + base + (size_t)(q0 + c)*HID);
        const f32x4 ot[3] = {o0, o1, o2};
        #pragma unroll
        for (int dt = 0; dt < 3; ++dt) {
            ushort4 w4;
            w4.x = f2us(ot[dt][0] * inv);
            w4.y = f2us(ot[dt][1] * inv);
            w4.z = f2us(ot[dt][2] * inv);
            w4.w = f2us(ot[dt][3] * inv);
            *reinterpret_cast<ushort4*>(orow + dt*16 + quad*4) = w4;
        }
    }
}

// ------------------------------------------------------- final LN + heads
template <typename T, typename TO>
static __device__ void final_body(
    const float* h, const T* fn_g, const T* fn_b,
    const T* on_w, const T* on_b, const T* oe_w, const T* oe_b, TO* out)
{
    __shared__ float hf[HID];
    const int row = blockIdx.x;
    const int b = row / L_, l = row % L_;
    const int lane = threadIdx.x;
    const float* hr = h + (size_t)row*HID;
    float v[6]; float s = 0.f, ss = 0.f;
    #pragma unroll
    for (int j = 0; j < 6; ++j) { float t = hr[lane + j*64]; v[j] = t; s += t; ss += t*t; }
    #pragma unroll
    for (int off = 32; off; off >>= 1) { s += __shfl_xor(s, off); ss += __shfl_xor(ss, off); }
    const float mu = s * (1.0f/HID);
    const float rs = rsqrtf(fmaxf(ss * (1.0f/HID) - mu*mu, 0.0f) + 1e-5f);
    #pragma unroll
    for (int j = 0; j < 6; ++j) {
        int c = lane + j*64;
        hf[c] = (v[j] - mu) * rs * ldv(fn_g, c) + ldv(fn_b, c);
    }
    __syncthreads();
    if (l < N_) {
        if (lane < A_) {
            float acc = ldv(on_b, lane);
            for (int c = 0; c < HID; ++c) acc += hf[c] * ldv(on_w, (size_t)c*A_ + lane);
            stv(out, (size_t)(b*N_ + l)*A_ + lane, acc);
        }
    } else {
        const int e = l - N_;
        if (lane < E_) {
            float acc = ldv(oe_b, lane);
            for (int c = 0; c < HID; ++c) acc += hf[c] * ldv(oe_w, (size_t)c*E_ + lane);
            stv(out, (size_t)B_*N_*A_ + ((size_t)b*N_*N_ + e)*E_ + lane, acc);
        }
    }
}

__global__ __launch_bounds__(64) void k_final(
    const float* __restrict__ h, const void* fn_g, const void* fn_b,
    const void* on_w, const void* on_b, const void* oe_w, const void* oe_b,
    const int* __restrict__ fl, void* out)
{
    if (*fl) final_body<float, float>(h, (const float*)fn_g, (const float*)fn_b,
                                      (const float*)on_w, (const float*)on_b,
                                      (const float*)oe_w, (const float*)oe_b, (float*)out);
    else     final_body<bf16, bf16>(h, (const bf16*)fn_g, (const bf16*)fn_b,
                                    (const bf16*)on_w, (const bf16*)on_b,
                                    (const bf16*)oe_w, (const bf16*)oe_b, (bf16*)out);
}

// ---------------------------------------------------------------- launch
extern "C" void kernel_launch(void* const* d_in, const int* in_sizes, int n_in,
                              void* d_out, int out_size, void* d_ws, size_t ws_size,
                              hipStream_t stream) {
    const void* x      = d_in[0];
    const void* adj    = d_in[1];
    const void* t      = d_in[2];
    const void* node_w = d_in[3];
    const void* node_b = d_in[4];
    const void* edge_w = d_in[5];
    const void* edge_b = d_in[6];
    const void* pos    = d_in[7];
    const void* t_w1   = d_in[8];
    const void* t_b1   = d_in[9];
    const void* t_w2   = d_in[10];
    const void* t_b2   = d_in[11];
    const void* ada1_w = d_in[12];
    const void* ada1_b = d_in[13];
    const void* ada2_w = d_in[14];
    const void* ada2_b = d_in[15];
    const void* q_w    = d_in[16];
    const void* q_b    = d_in[17];
    const void* k_w    = d_in[18];
    const void* k_b    = d_in[19];
    const void* v_w    = d_in[20];
    const void* v_b    = d_in[21];
    const void* o_w    = d_in[22];
    const void* o_b    = d_in[23];
    const void* m1_w   = d_in[24];
    const void* m1_b   = d_in[25];
    const void* m2_w   = d_in[26];
    const void* m2_b   = d_in[27];
    const void* fn_g   = d_in[28];
    const void* fn_b   = d_in[29];
    const void* on_w   = d_in[30];
    const void* on_b   = d_in[31];
    const void* oe_w   = d_in[32];
    const void* oe_b   = d_in[33];

    const size_t SZ = (size_t)M_ * HID;   // 1,806,336 elements
    const size_t NEED = 256 + sizeof(float)*(SZ + 12288 + B_*4*HID + B_*HID)
                      + sizeof(bf16)*4*SZ;   // ~21.8 MB
    if (ws_size < NEED) {
        hipMemsetAsync(d_out, 0, (size_t)out_size*sizeof(bf16), stream);  // 1.14 signature
        return;
    }
    int*   fl  = (int*)d_ws;
    float* h   = (float*)((char*)d_ws + 256);
    float* ada = h + SZ;                 // [8][B_][768]
    float* hid = ada + 12288;            // [B_][1536]
    float* cnd = hid + B_*4*HID;         // [B_][384]
    bf16* nb  = (bf16*)(cnd + B_*HID);
    bf16* qb  = nb + SZ;
    bf16* kb  = qb + SZ;
    bf16* vb  = kb + SZ;
    bf16* m1b = kb;   // [2352,1536] bf16 == kb+vb exactly (dead after attention)

    k_detect<<<1, 64, 0, stream>>>(node_w, fl);
    k_embed<<<M_, HID, 0, stream>>>(x, adj, node_w, node_b, edge_w, edge_b, pos, fl, h);
    k_cond1<<<dim3(B_, 6), 256, 0, stream>>>(t, t_w1, t_b1, fl, hid);
    k_cond2<<<B_, 384, 0, stream>>>(t_w2, t_b2, fl, hid, cnd);
    k_cond3<<<dim3(24, B_), 256, 0, stream>>>(ada1_w, ada1_b, ada2_w, ada2_b, fl, cnd, ada);
    for (int i = 0; i < LYR; ++i) {
        const long long woff   = (long long)i * HID * HID;
        const long long boff   = (long long)i * HID;
        const long long m1woff = (long long)i * HID * MLPD;
        const long long m1boff = (long long)i * MLPD;
        const long long m2woff = (long long)i * MLPD * HID;

        k_adaln<<<M_/4, 256, 0, stream>>>(h, ada, nb, 2*i);
        k_gemm<<<dim3(74, 6), 256, 0, stream>>>(nb, q_w, woff, q_b, boff,
                                                qb, nullptr, M_, HID, HID, 0, 0, fl);
        k_gemm<<<dim3(74, 6), 256, 0, stream>>>(nb, k_w, woff, k_b, boff,
                                                kb, nullptr, M_, HID, HID, 0, 0, fl);
        k_gemm<<<dim3(74, 6), 256, 0, stream>>>(nb, v_w, woff, v_b, boff,
                                                vb, nullptr, M_, HID, HID, 0, 0, fl);
        k_attn<<<dim3(37, B_*NHD), 256, 0, stream>>>(qb, kb, vb, nb);      // ao -> nb
        k_gemm<<<dim3(74, 6), 256, 0, stream>>>(nb, o_w, woff, o_b, boff,
                                                nullptr, h, M_, HID, HID, 0, 1, fl);
        k_adaln<<<M_/4, 256, 0, stream>>>(h, ada, nb, 2*i + 1);            // n2 -> nb
        for (int c = 0; c < 2; ++c) {
            k_gemm<<<dim3(37, 24), 256, 0, stream>>>(nb + (size_t)c*2352*HID,
                                                     m1_w, m1woff, m1_b, m1boff,
                                                     m1b, nullptr, 2352, MLPD, HID, 1, 0, fl);
            k_gemm<<<dim3(37, 6), 256, 0, stream>>>(m1b, m2_w, m2woff, m2_b, boff,
                                                    nullptr, h + (size_t)c*2352*HID,
                                                    2352, HID, MLPD, 0, 1, fl);
        }
    }
    k_final<<<M_, 64, 0, stream>>>(h, fn_g, fn_b, on_w, on_b, oe_w, oe_b, fl, (void*)d_out);
}

// Round 8
// 1351.633 us; speedup vs baseline: 7.4919x; 1.3603x over previous
//
#include <hip/hip_runtime.h>
#include <hip/hip_bf16.h>
#include <math.h>

typedef __hip_bfloat16 bf16;
typedef __attribute__((ext_vector_type(8))) short short8;   // 8 bf16 in 4 VGPRs
typedef __attribute__((ext_vector_type(4))) float f32x4;

#define B_ 2
#define N_ 48
#define A_ 16
#define E_ 5
#define HID 384
#define NHD 8
#define HD 48
#define LYR 4
#define MLPD 1536
#define L_ 2352      // N_ + N_*N_
#define M_ 4704      // B_*L_
#define VLP 2432     // padded key stride of transposed-V buffer (19*64*2 splits)

static __device__ __forceinline__ float b2f(bf16 v) { return __bfloat162float(v); }
static __device__ __forceinline__ float us2f(unsigned short u) {
    return __uint_as_float(((unsigned)u) << 16);
}
static __device__ __forceinline__ unsigned short f2us(float f) {
    bf16 h = __float2bfloat16(f);
    return *reinterpret_cast<unsigned short*>(&h);
}
static __device__ __forceinline__ float ldv(const float* p, size_t i) { return p[i]; }
static __device__ __forceinline__ float ldv(const bf16*  p, size_t i) { return b2f(p[i]); }
static __device__ __forceinline__ void  stv(float* p, size_t i, float v) { p[i] = v; }
static __device__ __forceinline__ void  stv(bf16*  p, size_t i, float v) { p[i] = __float2bfloat16(v); }
static __device__ __forceinline__ float4 ld4(const float* p, size_t i) {
    return *reinterpret_cast<const float4*>(p + i);
}
static __device__ __forceinline__ float4 ld4(const bf16* p, size_t i) {
    ushort4 u = *reinterpret_cast<const ushort4*>(p + i);
    return make_float4(us2f(u.x), us2f(u.y), us2f(u.z), us2f(u.w));
}

// ------------------------------------------------ dtype detect (flag: 1=fp32, 0=bf16)
__global__ void k_detect(const void* w, int* flag) {
    if (threadIdx.x == 0 && blockIdx.x == 0) {
        const bf16* p = (const bf16*)w;   // node_w: 6144 elems of 0.02*normal
        int isf = 0;
        for (int i = 0; i < 256; ++i) {
            float v = fabsf(b2f(p[i]));
            if (!(v <= 1000.0f)) { isf = 1; break; }
        }
        *flag = isf;
    }
}

// ---------------------------------------------------------------- embed (-> f32 h)
template <typename T>
static __device__ void embed_body(
    const T* x, const T* adj, const T* node_w, const T* node_b,
    const T* edge_w, const T* edge_b, const T* pos, float* h)
{
    const int bl = blockIdx.x;
    const int b = bl / L_, l = bl % L_;
    const int c = threadIdx.x;          // 0..383
    float acc;
    if (l < N_) {
        acc = ldv(node_b, c);
        const size_t xr = (size_t)(b*N_ + l)*A_;
        #pragma unroll
        for (int a = 0; a < A_; ++a) acc += ldv(x, xr + a) * ldv(node_w, (size_t)a*HID + c);
    } else {
        const int e = l - N_;
        acc = ldv(edge_b, c);
        const size_t ar = ((size_t)b*N_*N_ + e)*E_;
        #pragma unroll
        for (int j = 0; j < E_; ++j) acc += ldv(adj, ar + j) * ldv(edge_w, (size_t)j*HID + c);
    }
    h[(size_t)bl*HID + c] = acc + ldv(pos, (size_t)l*HID + c);
}

__global__ __launch_bounds__(384) void k_embed(
    const void* x, const void* adj, const void* node_w, const void* node_b,
    const void* edge_w, const void* edge_b, const void* pos,
    const int* __restrict__ fl, float* __restrict__ h)
{
    if (*fl) embed_body<float>((const float*)x, (const float*)adj, (const float*)node_w,
                               (const float*)node_b, (const float*)edge_w, (const float*)edge_b,
                               (const float*)pos, h);
    else     embed_body<bf16>((const bf16*)x, (const bf16*)adj, (const bf16*)node_w,
                              (const bf16*)node_b, (const bf16*)edge_w, (const bf16*)edge_b,
                              (const bf16*)pos, h);
}

// ---------------------------------------- cond stage 1: temb -> hidden (SiLU)
template <typename T>
static __device__ void cond1_body(const T* t, const T* t_w1, const T* t_b1, float* hid)
{
    __shared__ float temb[HID];
    const int b = blockIdx.x, tid = threadIdx.x;
    const float tv = ldv(t, b);
    for (int c = tid; c < HID; c += 256) {
        int i = (c < 192) ? c : c - 192;
        float f = expf(-9.2103403719761836f * (float)i / 192.0f);
        float ang = tv * f;
        temb[c] = (c < 192) ? sinf(ang) : cosf(ang);
    }
    __syncthreads();
    const int j = blockIdx.y * 256 + tid;
    float acc = ldv(t_b1, j);
    for (int i = 0; i < HID; ++i) acc += temb[i] * ldv(t_w1, (size_t)i*4*HID + j);
    hid[(size_t)b*4*HID + j] = acc / (1.0f + expf(-acc));   // SiLU
}

__global__ __launch_bounds__(256) void k_cond1(
    const void* t, const void* t_w1, const void* t_b1,
    const int* __restrict__ fl, float* __restrict__ hid)
{
    if (*fl) cond1_body<float>((const float*)t, (const float*)t_w1, (const float*)t_b1, hid);
    else     cond1_body<bf16>((const bf16*)t, (const bf16*)t_w1, (const bf16*)t_b1, hid);
}

// ---------------------------------------- cond stage 2: hidden -> cond[b][384]
template <typename T>
static __device__ void cond2_body(const T* t_w2, const T* t_b2, const float* hid, float* cnd)
{
    const int b = blockIdx.x, c = threadIdx.x;
    const float* hb = hid + (size_t)b*4*HID;
    float acc = ldv(t_b2, c);
    for (int j = 0; j < 4*HID; ++j) acc += hb[j] * ldv(t_w2, (size_t)j*HID + c);
    cnd[(size_t)b*HID + c] = acc;
}

__global__ __launch_bounds__(384) void k_cond2(
    const void* t_w2, const void* t_b2, const int* __restrict__ fl,
    const float* __restrict__ hid, float* __restrict__ cnd)
{
    if (*fl) cond2_body<float>((const float*)t_w2, (const float*)t_b2, hid, cnd);
    else     cond2_body<bf16>((const bf16*)t_w2, (const bf16*)t_b2, hid, cnd);
}

// ---------------------------------------- cond stage 3: ada projections
template <typename T>
static __device__ void cond3_body(
    const T* ada1_w, const T* ada1_b, const T* ada2_w, const T* ada2_b,
    const float* cnd, float* ada_out)
{
    __shared__ float cs[HID];
    const int slot = blockIdx.x / 3, ob = blockIdx.x % 3, b = blockIdx.y;
    const int tid = threadIdx.x;
    for (int c = tid; c < HID; c += 256) cs[c] = cnd[(size_t)b*HID + c];
    __syncthreads();
    const int layer = slot >> 1, which = slot & 1;
    const int o = ob*256 + tid;
    const T* W  = which ? ada2_w : ada1_w;
    const T* Bi = which ? ada2_b : ada1_b;
    float acc = ldv(Bi, (size_t)layer*768 + o);
    const size_t wb = (size_t)layer*HID*768 + o;
    for (int c = 0; c < HID; ++c) acc += cs[c] * ldv(W, wb + (size_t)c*768);
    ada_out[((size_t)slot*B_ + b)*768 + o] = acc;
}

__global__ __launch_bounds__(256) void k_cond3(
    const void* ada1_w, const void* ada1_b, const void* ada2_w, const void* ada2_b,
    const int* __restrict__ fl, const float* __restrict__ cnd, float* __restrict__ ada_out)
{
    if (*fl) cond3_body<float>((const float*)ada1_w, (const float*)ada1_b,
                               (const float*)ada2_w, (const float*)ada2_b, cnd, ada_out);
    else     cond3_body<bf16>((const bf16*)ada1_w, (const bf16*)ada1_b,
                              (const bf16*)ada2_w, (const bf16*)ada2_b, cnd, ada_out);
}

// ---------------------------------------------------------------- adaLN (f32 h -> bf16 n)
__global__ __launch_bounds__(256) void k_adaln(
    const float* __restrict__ h, const float* __restrict__ ada,
    bf16* __restrict__ n, int slot)
{
    const int row  = blockIdx.x * 4 + (threadIdx.x >> 6);
    const int lane = threadIdx.x & 63;
    const int b = row / L_;
    const float* hr = h + (size_t)row*HID;
    float v[6]; float s = 0.f, ss = 0.f;
    #pragma unroll
    for (int j = 0; j < 6; ++j) { float t = hr[lane + j*64]; v[j] = t; s += t; ss += t*t; }
    #pragma unroll
    for (int off = 32; off; off >>= 1) { s += __shfl_xor(s, off); ss += __shfl_xor(ss, off); }
    const float mu = s * (1.0f/HID);
    const float rs = rsqrtf(fmaxf(ss * (1.0f/HID) - mu*mu, 0.0f) + 1e-5f);
    const float* ap = ada + ((size_t)slot*B_ + b)*768;
    bf16* nr = n + (size_t)row*HID;
    #pragma unroll
    for (int j = 0; j < 6; ++j) {
        int c = lane + j*64;
        nr[c] = __float2bfloat16((v[j] - mu)*rs*(1.0f + ap[c]) + ap[384 + c]);
    }
}

// ------------------------------------------------- MFMA GEMM  C = act(A@W + bias)
// mode 0: Cb[row*N+col] = bf16(r)   mode 1: Cf[row*N+col] += r
// mode 2: transposed-V store: Cb[(bh*48+d)*VLP + key] = bf16(r)  (N==HID assumed)
template <typename T>
static __device__ void gemm_body(
    const bf16* A, const T* W, long long woff, const T* bias, long long boff,
    bf16* Cb, float* Cf, int M, int N, int K, int act, int mode)
{
    __shared__ __align__(16) unsigned short As[64][40];   // [m][k], 80B rows (16B-aligned)
    __shared__ __align__(16) unsigned short Bt[64][40];   // [n][k]
    const int tid  = threadIdx.x;
    const int wv   = tid >> 6, lane = tid & 63;
    const int quad = lane >> 4, c = lane & 15;
    const int wm = wv & 1, wn = wv >> 1;
    const int bm = blockIdx.x * 64, bn = blockIdx.y * 64;
    const int sar = tid >> 2, sac = (tid & 3) * 8;    // A staging: row, k-offset
    const int swk = tid & 31, swn = (tid >> 5) * 8;   // W staging: k, n-offset
    f32x4 acc[2][2] = {{{0.f,0.f,0.f,0.f},{0.f,0.f,0.f,0.f}},
                       {{0.f,0.f,0.f,0.f},{0.f,0.f,0.f,0.f}}};
    for (int k0 = 0; k0 < K; k0 += 32) {
        short8 av = short8{0,0,0,0,0,0,0,0};
        if (bm + sar < M)
            av = *reinterpret_cast<const short8*>(A + (size_t)(bm + sar)*K + k0 + sac);
        const size_t wrow = (size_t)woff + (size_t)(k0 + swk)*N + bn + swn;
        const float4 w0 = ld4(W, wrow);
        const float4 w1 = ld4(W, wrow + 4);
        __syncthreads();
        *reinterpret_cast<short8*>(&As[sar][sac]) = av;
        Bt[swn+0][swk] = f2us(w0.x); Bt[swn+1][swk] = f2us(w0.y);
        Bt[swn+2][swk] = f2us(w0.z); Bt[swn+3][swk] = f2us(w0.w);
        Bt[swn+4][swk] = f2us(w1.x); Bt[swn+5][swk] = f2us(w1.y);
        Bt[swn+6][swk] = f2us(w1.z); Bt[swn+7][swk] = f2us(w1.w);
        __syncthreads();
        short8 af[2], bfr[2];
        #pragma unroll
        for (int mi = 0; mi < 2; ++mi)
            af[mi] = *reinterpret_cast<const short8*>(&As[wm*32 + mi*16 + c][quad*8]);
        #pragma unroll
        for (int ni = 0; ni < 2; ++ni)
            bfr[ni] = *reinterpret_cast<const short8*>(&Bt[wn*32 + ni*16 + c][quad*8]);
        #pragma unroll
        for (int mi = 0; mi < 2; ++mi)
            #pragma unroll
            for (int ni = 0; ni < 2; ++ni)
                acc[mi][ni] = __builtin_amdgcn_mfma_f32_16x16x32_bf16(
                                  af[mi], bfr[ni], acc[mi][ni], 0, 0, 0);
    }
    float bcol[2];
    #pragma unroll
    for (int ni = 0; ni < 2; ++ni)
        bcol[ni] = ldv(bias, (size_t)boff + bn + wn*32 + ni*16 + c);
    #pragma unroll
    for (int mi = 0; mi < 2; ++mi)
        #pragma unroll
        for (int ni = 0; ni < 2; ++ni) {
            const int col = bn + wn*32 + ni*16 + c;
            #pragma unroll
            for (int r = 0; r < 4; ++r) {
                const int row = bm + wm*32 + mi*16 + quad*4 + r;
                if (row < M) {
                    float v = acc[mi][ni][r] + bcol[ni];
                    if (act) v = 0.5f * v * (1.0f + erff(v * 0.70710678118654752f));  // GELU
                    if (mode == 1) Cf[(size_t)row*N + col] += v;
                    else if (mode == 0) Cb[(size_t)row*N + col] = __float2bfloat16(v);
                    else {
                        const int b   = row >= L_ ? 1 : 0;
                        const int key = row - b*L_;
                        const int hh  = col / 48, d = col - hh*48;
                        Cb[((size_t)(b*8 + hh)*48 + d)*VLP + key] = __float2bfloat16(v);
                    }
                }
            }
        }
}

__global__ __launch_bounds__(256) void k_gemm(
    const bf16* __restrict__ A, const void* W, long long woff, const void* bias, long long boff,
    bf16* Cb, float* Cf, int M, int N, int K, int act, int mode,
    const int* __restrict__ fl)
{
    if (*fl) gemm_body<float>(A, (const float*)W, woff, (const float*)bias, boff,
                              Cb, Cf, M, N, K, act, mode);
    else     gemm_body<bf16>(A, (const bf16*)W, woff, (const bf16*)bias, boff,
                             Cb, Cf, M, N, K, act, mode);
}

// QKV batched: blockIdx.z selects {q,k,v}; v writes transposed layout (mode 2)
__global__ __launch_bounds__(256) void k_gemm_qkv(
    const bf16* __restrict__ A,
    const void* qw, const void* kw, const void* vw,
    const void* qb, const void* kb, const void* vb,
    long long woff, long long boff,
    bf16* Cq, bf16* Ck, bf16* Cv, const int* __restrict__ fl)
{
    const int z = blockIdx.z;
    const void* W  = (z == 0) ? qw : (z == 1) ? kw : vw;
    const void* Bi = (z == 0) ? qb : (z == 1) ? kb : vb;
    bf16* C        = (z == 0) ? Cq : (z == 1) ? Ck : Cv;
    const int mode = (z == 2) ? 2 : 0;
    if (*fl) gemm_body<float>(A, (const float*)W, woff, (const float*)Bi, boff,
                              C, nullptr, M_, HID, HID, 0, mode);
    else     gemm_body<bf16>(A, (const bf16*)W, woff, (const bf16*)Bi, boff,
                             C, nullptr, M_, HID, HID, 0, mode);
}

// ---------------------------------------------------------------- MFMA flash attention
// Transposed formulation (round-5-verified fragment maps), now:
//  - 64-key tiles, 16B-aligned LDS strides (80 shorts)
//  - V read pre-transposed from vt[(bh*48+d)*VLP + key] (b128 staging, no VALU transpose)
//  - split-K x2 inside the block: 4 waves = 2 q-tiles x 2 key-halves (19 tiles each),
//    merged at the end through LDS (m/l/o merge).
__global__ __launch_bounds__(256) void k_attn(
    const bf16* __restrict__ q, const bf16* __restrict__ k,
    const bf16* __restrict__ vt, bf16* __restrict__ ao)
{
    __shared__ __align__(16) unsigned short Ks[2][64][80];   // [split][key][d 0..63 +pad]
    __shared__ __align__(16) unsigned short Vt[2][48][80];   // [split][d][key 0..63 +pad]
    __shared__ __align__(16) unsigned short Pq[4][16][80];   // [wave][query][key 0..63 +pad]
    const int tid  = threadIdx.x;
    const int w    = tid >> 6, lane = tid & 63;
    const int quad = lane >> 4, c = lane & 15;
    const int qt = w & 1, sp = w >> 1;
    const int bh = blockIdx.y;                       // b*8+hh
    const size_t base  = (size_t)(bh >> 3)*L_*HID + (size_t)(bh & 7)*HD;
    const size_t vbase = (size_t)bh*48*VLP;
    const int q0 = blockIdx.x*32 + qt*16;
    const bool qvalid = q0 < L_;                     // wave-uniform
    const int qrow = qvalid ? (q0 + c) : c;

    short8 qf0, qf1;
    {
        const unsigned short* qp = (const unsigned short*)(q + base + (size_t)qrow*HID);
        qf0 = *reinterpret_cast<const short8*>(qp + quad*8);                 // d 0..31
        if (quad < 2) qf1 = *reinterpret_cast<const short8*>(qp + 32 + quad*8);  // d 32..47
        else          qf1 = short8{0,0,0,0,0,0,0,0};                         // d 48..63 pad
    }
    f32x4 o0 = {0.f,0.f,0.f,0.f}, o1 = {0.f,0.f,0.f,0.f}, o2 = {0.f,0.f,0.f,0.f};
    float m = -3.0e38f, lsum = 0.f;
    const int t128 = tid & 127, grp = tid >> 7;      // staging group == its waves' split

    for (int tt = 0; tt < 19; ++tt) {
        const int kb0 = grp*1216 + tt*64;            // staging key base
        __syncthreads();
        // ---- K staging: 512 short8 slots (row 0..63, ch 0..7 => d 0..63; ch>=6 zero)
        #pragma unroll
        for (int ii = 0; ii < 4; ++ii) {
            const int idx = t128 + ii*128;
            const int row = idx >> 3, ch = idx & 7;
            short8 val = short8{0,0,0,0,0,0,0,0};
            if (ch < 6) {
                const int key = min(kb0 + row, L_ - 1);   // clamp; masked on S side
                val = *reinterpret_cast<const short8*>(
                        (const unsigned short*)(k + base + (size_t)key*HID) + ch*8);
            }
            *reinterpret_cast<short8*>(&Ks[grp][row][ch*8]) = val;
        }
        // ---- V staging (already transposed in global): 384 short8 slots
        #pragma unroll
        for (int ii = 0; ii < 3; ++ii) {
            const int idx = t128 + ii*128;
            const int d = idx >> 3, ch = idx & 7;
            short8 val = *reinterpret_cast<const short8*>(
                    (const unsigned short*)(vt + vbase + (size_t)d*VLP + kb0) + ch*8);
            *reinterpret_cast<short8*>(&Vt[grp][d][ch*8]) = val;
        }
        __syncthreads();

        const int kt = sp*1216 + tt*64;              // compute key base for this wave
        float sv[16];
        float tmax = -3.0e38f;
        #pragma unroll
        for (int t = 0; t < 4; ++t) {
            f32x4 acc = {0.f,0.f,0.f,0.f};
            short8 a0 = *reinterpret_cast<const short8*>(&Ks[sp][t*16 + c][quad*8]);
            short8 a1 = *reinterpret_cast<const short8*>(&Ks[sp][t*16 + c][32 + quad*8]);
            acc = __builtin_amdgcn_mfma_f32_16x16x32_bf16(a0, qf0, acc, 0, 0, 0);
            acc = __builtin_amdgcn_mfma_f32_16x16x32_bf16(a1, qf1, acc, 0, 0, 0);
            #pragma unroll
            for (int r = 0; r < 4; ++r) {
                const int key = kt + t*16 + quad*4 + r;
                const float val = (key < L_) ? acc[r] * 0.14433756729740643f : -3.0e38f;
                sv[t*4 + r] = val;
                tmax = fmaxf(tmax, val);
            }
        }
        tmax = fmaxf(tmax, __shfl_xor(tmax, 16));
        tmax = fmaxf(tmax, __shfl_xor(tmax, 32));
        const float mn = fmaxf(m, tmax);
        const float alpha = __expf(m - mn);
        m = mn;
        float psum = 0.f;
        unsigned short pv[16];
        #pragma unroll
        for (int i = 0; i < 16; ++i) {
            const float p = __expf(sv[i] - m);
            psum += p;
            pv[i] = f2us(p);
        }
        lsum = lsum * alpha + psum;
        o0 *= alpha; o1 *= alpha; o2 *= alpha;
        // P row (query c) -> LDS; same-wave rw, no barrier needed
        #pragma unroll
        for (int t = 0; t < 4; ++t)
            *reinterpret_cast<ushort4*>(&Pq[w][c][t*16 + quad*4]) =
                make_ushort4(pv[t*4+0], pv[t*4+1], pv[t*4+2], pv[t*4+3]);
        // PV in 2 steps of 32 keys
        #pragma unroll
        for (int s = 0; s < 2; ++s) {
            short8 pf  = *reinterpret_cast<const short8*>(&Pq[w][c][s*32 + quad*8]);
            short8 vf0 = *reinterpret_cast<const short8*>(&Vt[sp][c][s*32 + quad*8]);
            short8 vf1 = *reinterpret_cast<const short8*>(&Vt[sp][16 + c][s*32 + quad*8]);
            short8 vf2 = *reinterpret_cast<const short8*>(&Vt[sp][32 + c][s*32 + quad*8]);
            o0 = __builtin_amdgcn_mfma_f32_16x16x32_bf16(vf0, pf, o0, 0, 0, 0);
            o1 = __builtin_amdgcn_mfma_f32_16x16x32_bf16(vf1, pf, o1, 0, 0, 0);
            o2 = __builtin_amdgcn_mfma_f32_16x16x32_bf16(vf2, pf, o2, 0, 0, 0);
        }
    }
    // ---- reduce l across quads within wave
    float lw = lsum;
    lw += __shfl_xor(lw, 16);
    lw += __shfl_xor(lw, 32);
    // ---- split merge through LDS (reuse Pq area; 128*14 floats = 7168 B <= 10240 B)
    float* Mg = (float*)&Pq[0][0][0];
    __syncthreads();
    if (sp == 1) {
        float* dst = Mg + (size_t)(qt*64 + lane)*14;
        dst[0] = o0[0]; dst[1] = o0[1]; dst[2]  = o0[2]; dst[3]  = o0[3];
        dst[4] = o1[0]; dst[5] = o1[1]; dst[6]  = o1[2]; dst[7]  = o1[3];
        dst[8] = o2[0]; dst[9] = o2[1]; dst[10] = o2[2]; dst[11] = o2[3];
        dst[12] = m; dst[13] = lw;
    }
    __syncthreads();
    if (sp == 0 && qvalid) {
        const float* src = Mg + (size_t)(qt*64 + lane)*14;
        const float m2 = src[12], l2 = src[13];
        const float mm = fmaxf(m, m2);
        const float a1 = __expf(m - mm), a2 = __expf(m2 - mm);
        const float inv = 1.0f / (lw*a1 + l2*a2);
        unsigned short* orow = (unsigned short*)(ao + base + (size_t)(q0 + c)*HID);
        const f32x4 ot[3] = {o0, o1, o2};
        #pragma unroll
        for (int dt = 0; dt < 3; ++dt) {
            ushort4 w4;
            w4.x = f2us((ot[dt][0]*a1 + src[dt*4+0]*a2) * inv);
            w4.y = f2us((ot[dt][1]*a1 + src[dt*4+1]*a2) * inv);
            w4.z = f2us((ot[dt][2]*a1 + src[dt*4+2]*a2) * inv);
            w4.w = f2us((ot[dt][3]*a1 + src[dt*4+3]*a2) * inv);
            *reinterpret_cast<ushort4*>(orow + dt*16 + quad*4) = w4;
        }
    }
}

// ------------------------------------------------------- final LN + heads
template <typename T, typename TO>
static __device__ void final_body(
    const float* h, const T* fn_g, const T* fn_b,
    const T* on_w, const T* on_b, const T* oe_w, const T* oe_b, TO* out)
{
    __shared__ float hf[HID];
    const int row = blockIdx.x;
    const int b = row / L_, l = row % L_;
    const int lane = threadIdx.x;
    const float* hr = h + (size_t)row*HID;
    float v[6]; float s = 0.f, ss = 0.f;
    #pragma unroll
    for (int j = 0; j < 6; ++j) { float t = hr[lane + j*64]; v[j] = t; s += t; ss += t*t; }
    #pragma unroll
    for (int off = 32; off; off >>= 1) { s += __shfl_xor(s, off); ss += __shfl_xor(ss, off); }
    const float mu = s * (1.0f/HID);
    const float rs = rsqrtf(fmaxf(ss * (1.0f/HID) - mu*mu, 0.0f) + 1e-5f);
    #pragma unroll
    for (int j = 0; j < 6; ++j) {
        int c = lane + j*64;
        hf[c] = (v[j] - mu) * rs * ldv(fn_g, c) + ldv(fn_b, c);
    }
    __syncthreads();
    if (l < N_) {
        if (lane < A_) {
            float acc = ldv(on_b, lane);
            for (int c = 0; c < HID; ++c) acc += hf[c] * ldv(on_w, (size_t)c*A_ + lane);
            stv(out, (size_t)(b*N_ + l)*A_ + lane, acc);
        }
    } else {
        const int e = l - N_;
        if (lane < E_) {
            float acc = ldv(oe_b, lane);
            for (int c = 0; c < HID; ++c) acc += hf[c] * ldv(oe_w, (size_t)c*E_ + lane);
            stv(out, (size_t)B_*N_*A_ + ((size_t)b*N_*N_ + e)*E_ + lane, acc);
        }
    }
}

__global__ __launch_bounds__(64) void k_final(
    const float* __restrict__ h, const void* fn_g, const void* fn_b,
    const void* on_w, const void* on_b, const void* oe_w, const void* oe_b,
    const int* __restrict__ fl, void* out)
{
    if (*fl) final_body<float, float>(h, (const float*)fn_g, (const float*)fn_b,
                                      (const float*)on_w, (const float*)on_b,
                                      (const float*)oe_w, (const float*)oe_b, (float*)out);
    else     final_body<bf16, bf16>(h, (const bf16*)fn_g, (const bf16*)fn_b,
                                    (const bf16*)on_w, (const bf16*)on_b,
                                    (const bf16*)oe_w, (const bf16*)oe_b, (bf16*)out);
}

// ---------------------------------------------------------------- launch
extern "C" void kernel_launch(void* const* d_in, const int* in_sizes, int n_in,
                              void* d_out, int out_size, void* d_ws, size_t ws_size,
                              hipStream_t stream) {
    const void* x      = d_in[0];
    const void* adj    = d_in[1];
    const void* t      = d_in[2];
    const void* node_w = d_in[3];
    const void* node_b = d_in[4];
    const void* edge_w = d_in[5];
    const void* edge_b = d_in[6];
    const void* pos    = d_in[7];
    const void* t_w1   = d_in[8];
    const void* t_b1   = d_in[9];
    const void* t_w2   = d_in[10];
    const void* t_b2   = d_in[11];
    const void* ada1_w = d_in[12];
    const void* ada1_b = d_in[13];
    const void* ada2_w = d_in[14];
    const void* ada2_b = d_in[15];
    const void* q_w    = d_in[16];
    const void* q_b    = d_in[17];
    const void* k_w    = d_in[18];
    const void* k_b    = d_in[19];
    const void* v_w    = d_in[20];
    const void* v_b    = d_in[21];
    const void* o_w    = d_in[22];
    const void* o_b    = d_in[23];
    const void* m1_w   = d_in[24];
    const void* m1_b   = d_in[25];
    const void* m2_w   = d_in[26];
    const void* m2_b   = d_in[27];
    const void* fn_g   = d_in[28];
    const void* fn_b   = d_in[29];
    const void* on_w   = d_in[30];
    const void* on_b   = d_in[31];
    const void* oe_w   = d_in[32];
    const void* oe_b   = d_in[33];

    const size_t SZ  = (size_t)M_ * HID;          // 1,806,336 elements
    const size_t VTZ = (size_t)B_*NHD*HD*VLP;     // 1,867,776 elements (padded V^T)
    const size_t NEED = 256 + sizeof(float)*(SZ + 12288 + (size_t)B_*4*HID + (size_t)B_*HID)
                      + sizeof(bf16)*(3*SZ + VTZ);   // ~21.9 MB
    if (ws_size < NEED) {
        hipMemsetAsync(d_out, 0, (size_t)out_size*sizeof(bf16), stream);  // 1.14 signature
        return;
    }
    int*   fl  = (int*)d_ws;
    float* h   = (float*)((char*)d_ws + 256);
    float* ada = h + SZ;                 // [8][B_][768]
    float* hid = ada + 12288;            // [B_][1536]
    float* cnd = hid + (size_t)B_*4*HID; // [B_][384]
    bf16* nb  = (bf16*)(cnd + (size_t)B_*HID);
    bf16* qb  = nb + SZ;
    bf16* kb  = qb + SZ;
    bf16* vtb = kb + SZ;                 // transposed V, [bh*48+d][VLP]
    bf16* m1b = kb;                      // [2352,1536] bf16 spans kb+vtb (dead after attn)

    k_detect<<<1, 64, 0, stream>>>(node_w, fl);
    k_embed<<<M_, HID, 0, stream>>>(x, adj, node_w, node_b, edge_w, edge_b, pos, fl, h);
    k_cond1<<<dim3(B_, 6), 256, 0, stream>>>(t, t_w1, t_b1, fl, hid);
    k_cond2<<<B_, 384, 0, stream>>>(t_w2, t_b2, fl, hid, cnd);
    k_cond3<<<dim3(24, B_), 256, 0, stream>>>(ada1_w, ada1_b, ada2_w, ada2_b, fl, cnd, ada);
    for (int i = 0; i < LYR; ++i) {
        const long long woff   = (long long)i * HID * HID;
        const long long boff   = (long long)i * HID;
        const long long m1woff = (long long)i * HID * MLPD;
        const long long m1boff = (long long)i * MLPD;
        const long long m2woff = (long long)i * MLPD * HID;

        k_adaln<<<M_/4, 256, 0, stream>>>(h, ada, nb, 2*i);
        k_gemm_qkv<<<dim3(74, 6, 3), 256, 0, stream>>>(nb, q_w, k_w, v_w, q_b, k_b, v_b,
                                                       woff, boff, qb, kb, vtb, fl);
        k_attn<<<dim3(74, B_*NHD), 256, 0, stream>>>(qb, kb, vtb, nb);     // ao -> nb
        k_gemm<<<dim3(74, 6), 256, 0, stream>>>(nb, o_w, woff, o_b, boff,
                                                nullptr, h, M_, HID, HID, 0, 1, fl);
        k_adaln<<<M_/4, 256, 0, stream>>>(h, ada, nb, 2*i + 1);            // n2 -> nb
        for (int c = 0; c < 2; ++c) {
            k_gemm<<<dim3(37, 24), 256, 0, stream>>>(nb + (size_t)c*2352*HID,
                                                     m1_w, m1woff, m1_b, m1boff,
                                                     m1b, nullptr, 2352, MLPD, HID, 1, 0, fl);
            k_gemm<<<dim3(37, 6), 256, 0, stream>>>(m1b, m2_w, m2woff, m2_b, boff,
                                                    nullptr, h + (size_t)c*2352*HID,
                                                    2352, HID, MLPD, 0, 1, fl);
        }
    }
    k_final<<<M_, 64, 0, stream>>>(h, fn_g, fn_b, on_w, on_b, oe_w, oe_b, fl, (void*)d_out);
}

// Round 10
// 1278.199 us; speedup vs baseline: 7.9223x; 1.0575x over previous
//
#include <hip/hip_runtime.h>
#include <hip/hip_bf16.h>
#include <math.h>

typedef __hip_bfloat16 bf16;
typedef __attribute__((ext_vector_type(8))) short short8;   // 8 bf16 in 4 VGPRs
typedef __attribute__((ext_vector_type(4))) float f32x4;

#define B_ 2
#define N_ 48
#define A_ 16
#define E_ 5
#define HID 384
#define NHD 8
#define HD 48
#define LYR 4
#define MLPD 1536
#define L_ 2352      // N_ + N_*N_
#define M_ 4704      // B_*L_
#define VLP 2432     // padded key stride of transposed-V buffer (19*64*2 splits)

static __device__ __forceinline__ float b2f(bf16 v) { return __bfloat162float(v); }
static __device__ __forceinline__ float us2f(unsigned short u) {
    return __uint_as_float(((unsigned)u) << 16);
}
static __device__ __forceinline__ unsigned short f2us(float f) {
    bf16 h = __float2bfloat16(f);
    return *reinterpret_cast<unsigned short*>(&h);
}
static __device__ __forceinline__ float ldv(const float* p, size_t i) { return p[i]; }
static __device__ __forceinline__ float ldv(const bf16*  p, size_t i) { return b2f(p[i]); }
static __device__ __forceinline__ void  stv(float* p, size_t i, float v) { p[i] = v; }
static __device__ __forceinline__ void  stv(bf16*  p, size_t i, float v) { p[i] = __float2bfloat16(v); }
static __device__ __forceinline__ float4 ld4(const float* p, size_t i) {
    return *reinterpret_cast<const float4*>(p + i);
}
static __device__ __forceinline__ float4 ld4(const bf16* p, size_t i) {
    ushort4 u = *reinterpret_cast<const ushort4*>(p + i);
    return make_float4(us2f(u.x), us2f(u.y), us2f(u.z), us2f(u.w));
}

// ------------------------------------------------ dtype detect (flag: 1=fp32, 0=bf16)
__global__ void k_detect(const void* w, int* flag) {
    if (threadIdx.x == 0 && blockIdx.x == 0) {
        const bf16* p = (const bf16*)w;   // node_w: 6144 elems of 0.02*normal
        int isf = 0;
        for (int i = 0; i < 256; ++i) {
            float v = fabsf(b2f(p[i]));
            if (!(v <= 1000.0f)) { isf = 1; break; }
        }
        *flag = isf;
    }
}

// ---------------------------------------------------------------- embed (-> f32 h)
template <typename T>
static __device__ void embed_body(
    const T* x, const T* adj, const T* node_w, const T* node_b,
    const T* edge_w, const T* edge_b, const T* pos, float* h)
{
    const int bl = blockIdx.x;
    const int b = bl / L_, l = bl % L_;
    const int c = threadIdx.x;          // 0..383
    float acc;
    if (l < N_) {
        acc = ldv(node_b, c);
        const size_t xr = (size_t)(b*N_ + l)*A_;
        #pragma unroll
        for (int a = 0; a < A_; ++a) acc += ldv(x, xr + a) * ldv(node_w, (size_t)a*HID + c);
    } else {
        const int e = l - N_;
        acc = ldv(edge_b, c);
        const size_t ar = ((size_t)b*N_*N_ + e)*E_;
        #pragma unroll
        for (int j = 0; j < E_; ++j) acc += ldv(adj, ar + j) * ldv(edge_w, (size_t)j*HID + c);
    }
    h[(size_t)bl*HID + c] = acc + ldv(pos, (size_t)l*HID + c);
}

__global__ __launch_bounds__(384) void k_embed(
    const void* x, const void* adj, const void* node_w, const void* node_b,
    const void* edge_w, const void* edge_b, const void* pos,
    const int* __restrict__ fl, float* __restrict__ h)
{
    if (*fl) embed_body<float>((const float*)x, (const float*)adj, (const float*)node_w,
                               (const float*)node_b, (const float*)edge_w, (const float*)edge_b,
                               (const float*)pos, h);
    else     embed_body<bf16>((const bf16*)x, (const bf16*)adj, (const bf16*)node_w,
                              (const bf16*)node_b, (const bf16*)edge_w, (const bf16*)edge_b,
                              (const bf16*)pos, h);
}

// ---------------------------------------- cond stage 1: temb -> hidden (SiLU)
// grid (B_, 24), block 256 = 4 K-quarters x 64 outputs; LDS reduce.
template <typename T>
static __device__ void cond1_body(const T* t, const T* t_w1, const T* t_b1, float* hid)
{
    __shared__ float temb[HID];
    __shared__ float red[4][64];
    const int b = blockIdx.x, jb = blockIdx.y, tid = threadIdx.x;
    const float tv = ldv(t, b);
    for (int c = tid; c < HID; c += 256) {
        int i = (c < 192) ? c : c - 192;
        float f = expf(-9.2103403719761836f * (float)i / 192.0f);
        float ang = tv * f;
        temb[c] = (c < 192) ? sinf(ang) : cosf(ang);
    }
    __syncthreads();
    const int ko = tid >> 6, jo = tid & 63;
    const int j = jb*64 + jo;
    float acc = 0.f;
    for (int i = ko*96; i < (ko + 1)*96; ++i)
        acc += temb[i] * ldv(t_w1, (size_t)i*4*HID + j);
    red[ko][jo] = acc;
    __syncthreads();
    if (ko == 0) {
        float a = red[0][jo] + red[1][jo] + red[2][jo] + red[3][jo] + ldv(t_b1, j);
        hid[(size_t)b*4*HID + j] = a / (1.0f + expf(-a));   // SiLU
    }
}

__global__ __launch_bounds__(256) void k_cond1(
    const void* t, const void* t_w1, const void* t_b1,
    const int* __restrict__ fl, float* __restrict__ hid)
{
    if (*fl) cond1_body<float>((const float*)t, (const float*)t_w1, (const float*)t_b1, hid);
    else     cond1_body<bf16>((const bf16*)t, (const bf16*)t_w1, (const bf16*)t_b1, hid);
}

// ---------------------------------------- cond stage 2: hidden -> partial cond sums
// grid (B_, 12), block 384: each block covers 128 of the 1536 hidden dims,
// writes part[b][chunk][384]; bias folded into chunk 0. Final sum happens in cond3.
template <typename T>
static __device__ void cond2_body(const T* t_w2, const T* t_b2, const float* hid, float* part)
{
    __shared__ float hs[128];
    const int b = blockIdx.x, ch = blockIdx.y, c = threadIdx.x;
    const int j0 = ch*128;
    if (c < 128) hs[c] = hid[(size_t)b*4*HID + j0 + c];
    __syncthreads();
    float acc = (ch == 0) ? ldv(t_b2, c) : 0.f;
    for (int jj = 0; jj < 128; ++jj)
        acc += hs[jj] * ldv(t_w2, (size_t)(j0 + jj)*HID + c);
    part[((size_t)b*12 + ch)*HID + c] = acc;
}

__global__ __launch_bounds__(384) void k_cond2(
    const void* t_w2, const void* t_b2, const int* __restrict__ fl,
    const float* __restrict__ hid, float* __restrict__ part)
{
    if (*fl) cond2_body<float>((const float*)t_w2, (const float*)t_b2, hid, part);
    else     cond2_body<bf16>((const bf16*)t_w2, (const bf16*)t_b2, hid, part);
}

// ---------------------------------------- cond stage 3: ada projections
// grid (24, B_): blockIdx.x = slot*3 + chunk; sums the 12 cond partials on load.
template <typename T>
static __device__ void cond3_body(
    const T* ada1_w, const T* ada1_b, const T* ada2_w, const T* ada2_b,
    const float* part, float* ada_out)
{
    __shared__ float cs[HID];
    const int slot = blockIdx.x / 3, ob = blockIdx.x % 3, b = blockIdx.y;
    const int tid = threadIdx.x;
    for (int c = tid; c < HID; c += 256) {
        float s = 0.f;
        #pragma unroll
        for (int ch = 0; ch < 12; ++ch) s += part[((size_t)b*12 + ch)*HID + c];
        cs[c] = s;
    }
    __syncthreads();
    const int layer = slot >> 1, which = slot & 1;
    const int o = ob*256 + tid;
    const T* W  = which ? ada2_w : ada1_w;
    const T* Bi = which ? ada2_b : ada1_b;
    float acc = ldv(Bi, (size_t)layer*768 + o);
    const size_t wb = (size_t)layer*HID*768 + o;
    for (int c = 0; c < HID; ++c) acc += cs[c] * ldv(W, wb + (size_t)c*768);
    ada_out[((size_t)slot*B_ + b)*768 + o] = acc;
}

__global__ __launch_bounds__(256) void k_cond3(
    const void* ada1_w, const void* ada1_b, const void* ada2_w, const void* ada2_b,
    const int* __restrict__ fl, const float* __restrict__ part, float* __restrict__ ada_out)
{
    if (*fl) cond3_body<float>((const float*)ada1_w, (const float*)ada1_b,
                               (const float*)ada2_w, (const float*)ada2_b, part, ada_out);
    else     cond3_body<bf16>((const bf16*)ada1_w, (const bf16*)ada1_b,
                              (const bf16*)ada2_w, (const bf16*)ada2_b, part, ada_out);
}

// ---------------------------------------------------------------- adaLN (f32 h -> bf16 n)
__global__ __launch_bounds__(256) void k_adaln(
    const float* __restrict__ h, const float* __restrict__ ada,
    bf16* __restrict__ n, int slot)
{
    const int row  = blockIdx.x * 4 + (threadIdx.x >> 6);
    const int lane = threadIdx.x & 63;
    const int b = row / L_;
    const float* hr = h + (size_t)row*HID;
    float v[6]; float s = 0.f, ss = 0.f;
    #pragma unroll
    for (int j = 0; j < 6; ++j) { float t = hr[lane + j*64]; v[j] = t; s += t; ss += t*t; }
    #pragma unroll
    for (int off = 32; off; off >>= 1) { s += __shfl_xor(s, off); ss += __shfl_xor(ss, off); }
    const float mu = s * (1.0f/HID);
    const float rs = rsqrtf(fmaxf(ss * (1.0f/HID) - mu*mu, 0.0f) + 1e-5f);
    const float* ap = ada + ((size_t)slot*B_ + b)*768;
    bf16* nr = n + (size_t)row*HID;
    #pragma unroll
    for (int j = 0; j < 6; ++j) {
        int c = lane + j*64;
        nr[c] = __float2bfloat16((v[j] - mu)*rs*(1.0f + ap[c]) + ap[384 + c]);
    }
}

// ------------------------------------------------- MFMA GEMM  C = act(A@W + bias)
// BK=64 (half the barriers of BK=32). Tile 64x64, 4 waves 2x2, each wave 2x2 mfma.
// mode 0: Cb[row*N+col] = bf16(r)   mode 1: Cf[row*N+col] += r
// mode 2: transposed-V store: Cb[(bh*48+d)*VLP + key] = bf16(r)  (N==HID assumed)
template <typename T>
static __device__ void gemm_body(
    const bf16* A, const T* W, long long woff, const T* bias, long long boff,
    bf16* Cb, float* Cf, int M, int N, int K, int act, int mode)
{
    __shared__ __align__(16) unsigned short As[64][72];   // [m][k0..63], 144B rows
    __shared__ __align__(16) unsigned short Bt[64][72];   // [n][k]
    const int tid  = threadIdx.x;
    const int wv   = tid >> 6, lane = tid & 63;
    const int quad = lane >> 4, c = lane & 15;
    const int wm = wv & 1, wn = wv >> 1;
    const int bm = blockIdx.x * 64, bn = blockIdx.y * 64;
    const int arow = tid >> 3, ach = tid & 7;   // A/W slot decomposition (+32 rows per i)
    f32x4 acc[2][2] = {{{0.f,0.f,0.f,0.f},{0.f,0.f,0.f,0.f}},
                       {{0.f,0.f,0.f,0.f},{0.f,0.f,0.f,0.f}}};
    for (int k0 = 0; k0 < K; k0 += 64) {
        short8 av[2]; float4 w0[2], w1[2];
        #pragma unroll
        for (int i = 0; i < 2; ++i) {
            const int row = i*32 + arow;
            av[i] = short8{0,0,0,0,0,0,0,0};
            if (bm + row < M)
                av[i] = *reinterpret_cast<const short8*>(
                            A + (size_t)(bm + row)*K + k0 + ach*8);
            const size_t wrow = (size_t)woff + (size_t)(k0 + i*32 + arow)*N + bn + ach*8;
            w0[i] = ld4(W, wrow);
            w1[i] = ld4(W, wrow + 4);
        }
        __syncthreads();
        #pragma unroll
        for (int i = 0; i < 2; ++i) {
            *reinterpret_cast<short8*>(&As[i*32 + arow][ach*8]) = av[i];
            const int kk = i*32 + arow, nb0 = ach*8;
            Bt[nb0+0][kk] = f2us(w0[i].x); Bt[nb0+1][kk] = f2us(w0[i].y);
            Bt[nb0+2][kk] = f2us(w0[i].z); Bt[nb0+3][kk] = f2us(w0[i].w);
            Bt[nb0+4][kk] = f2us(w1[i].x); Bt[nb0+5][kk] = f2us(w1[i].y);
            Bt[nb0+6][kk] = f2us(w1[i].z); Bt[nb0+7][kk] = f2us(w1[i].w);
        }
        __syncthreads();
        #pragma unroll
        for (int ks = 0; ks < 2; ++ks) {
            short8 af[2], bfr[2];
            #pragma unroll
            for (int mi = 0; mi < 2; ++mi)
                af[mi] = *reinterpret_cast<const short8*>(
                             &As[wm*32 + mi*16 + c][ks*32 + quad*8]);
            #pragma unroll
            for (int ni = 0; ni < 2; ++ni)
                bfr[ni] = *reinterpret_cast<const short8*>(
                              &Bt[wn*32 + ni*16 + c][ks*32 + quad*8]);
            #pragma unroll
            for (int mi = 0; mi < 2; ++mi)
                #pragma unroll
                for (int ni = 0; ni < 2; ++ni)
                    acc[mi][ni] = __builtin_amdgcn_mfma_f32_16x16x32_bf16(
                                      af[mi], bfr[ni], acc[mi][ni], 0, 0, 0);
        }
    }
    float bcol[2];
    #pragma unroll
    for (int ni = 0; ni < 2; ++ni)
        bcol[ni] = ldv(bias, (size_t)boff + bn + wn*32 + ni*16 + c);
    #pragma unroll
    for (int mi = 0; mi < 2; ++mi)
        #pragma unroll
        for (int ni = 0; ni < 2; ++ni) {
            const int col = bn + wn*32 + ni*16 + c;
            #pragma unroll
            for (int r = 0; r < 4; ++r) {
                const int row = bm + wm*32 + mi*16 + quad*4 + r;
                if (row < M) {
                    float v = acc[mi][ni][r] + bcol[ni];
                    if (act) v = 0.5f * v * (1.0f + erff(v * 0.70710678118654752f));  // GELU
                    if (mode == 1) Cf[(size_t)row*N + col] += v;
                    else if (mode == 0) Cb[(size_t)row*N + col] = __float2bfloat16(v);
                    else {
                        const int b   = row >= L_ ? 1 : 0;
                        const int key = row - b*L_;
                        const int hh  = col / 48, d = col - hh*48;
                        Cb[((size_t)(b*8 + hh)*48 + d)*VLP + key] = __float2bfloat16(v);
                    }
                }
            }
        }
}

__global__ __launch_bounds__(256) void k_gemm(
    const bf16* __restrict__ A, const void* W, long long woff, const void* bias, long long boff,
    bf16* Cb, float* Cf, int M, int N, int K, int act, int mode,
    const int* __restrict__ fl)
{
    if (*fl) gemm_body<float>(A, (const float*)W, woff, (const float*)bias, boff,
                              Cb, Cf, M, N, K, act, mode);
    else     gemm_body<bf16>(A, (const bf16*)W, woff, (const bf16*)bias, boff,
                             Cb, Cf, M, N, K, act, mode);
}

// QKV batched: blockIdx.z selects {q,k,v}; v writes transposed layout (mode 2)
__global__ __launch_bounds__(256) void k_gemm_qkv(
    const bf16* __restrict__ A,
    const void* qw, const void* kw, const void* vw,
    const void* qb, const void* kb, const void* vb,
    long long woff, long long boff,
    bf16* Cq, bf16* Ck, bf16* Cv, const int* __restrict__ fl)
{
    const int z = blockIdx.z;
    const void* W  = (z == 0) ? qw : (z == 1) ? kw : vw;
    const void* Bi = (z == 0) ? qb : (z == 1) ? kb : vb;
    bf16* C        = (z == 0) ? Cq : (z == 1) ? Ck : Cv;
    const int mode = (z == 2) ? 2 : 0;
    if (*fl) gemm_body<float>(A, (const float*)W, woff, (const float*)Bi, boff,
                              C, nullptr, M_, HID, HID, 0, mode);
    else     gemm_body<bf16>(A, (const bf16*)W, woff, (const bf16*)Bi, boff,
                             C, nullptr, M_, HID, HID, 0, mode);
}

// ---------------------------------------------------------------- MFMA flash attention
// (round-7 structure, verified: 64-key tiles, pre-transposed V, in-block split-K x2)
__global__ __launch_bounds__(256) void k_attn(
    const bf16* __restrict__ q, const bf16* __restrict__ k,
    const bf16* __restrict__ vt, bf16* __restrict__ ao)
{
    __shared__ __align__(16) unsigned short Ks[2][64][80];   // [split][key][d 0..63 +pad]
    __shared__ __align__(16) unsigned short Vt[2][48][80];   // [split][d][key 0..63 +pad]
    __shared__ __align__(16) unsigned short Pq[4][16][80];   // [wave][query][key 0..63 +pad]
    const int tid  = threadIdx.x;
    const int w    = tid >> 6, lane = tid & 63;
    const int quad = lane >> 4, c = lane & 15;
    const int qt = w & 1, sp = w >> 1;
    const int bh = blockIdx.y;                       // b*8+hh
    const size_t base  = (size_t)(bh >> 3)*L_*HID + (size_t)(bh & 7)*HD;
    const size_t vbase = (size_t)bh*48*VLP;
    const int q0 = blockIdx.x*32 + qt*16;
    const bool qvalid = q0 < L_;                     // wave-uniform
    const int qrow = qvalid ? (q0 + c) : c;

    short8 qf0, qf1;
    {
        const unsigned short* qp = (const unsigned short*)(q + base + (size_t)qrow*HID);
        qf0 = *reinterpret_cast<const short8*>(qp + quad*8);                 // d 0..31
        if (quad < 2) qf1 = *reinterpret_cast<const short8*>(qp + 32 + quad*8);  // d 32..47
        else          qf1 = short8{0,0,0,0,0,0,0,0};                         // d 48..63 pad
    }
    f32x4 o0 = {0.f,0.f,0.f,0.f}, o1 = {0.f,0.f,0.f,0.f}, o2 = {0.f,0.f,0.f,0.f};
    float m = -3.0e38f, lsum = 0.f;
    const int t128 = tid & 127, grp = tid >> 7;      // staging group == its waves' split

    for (int tt = 0; tt < 19; ++tt) {
        const int kb0 = grp*1216 + tt*64;            // staging key base
        __syncthreads();
        // ---- K staging: 512 short8 slots (row 0..63, ch 0..7 => d 0..63; ch>=6 zero)
        #pragma unroll
        for (int ii = 0; ii < 4; ++ii) {
            const int idx = t128 + ii*128;
            const int row = idx >> 3, ch = idx & 7;
            short8 val = short8{0,0,0,0,0,0,0,0};
            if (ch < 6) {
                const int key = min(kb0 + row, L_ - 1);   // clamp; masked on S side
                val = *reinterpret_cast<const short8*>(
                        (const unsigned short*)(k + base + (size_t)key*HID) + ch*8);
            }
            *reinterpret_cast<short8*>(&Ks[grp][row][ch*8]) = val;
        }
        // ---- V staging (already transposed in global): 384 short8 slots
        #pragma unroll
        for (int ii = 0; ii < 3; ++ii) {
            const int idx = t128 + ii*128;
            const int d = idx >> 3, ch = idx & 7;
            short8 val = *reinterpret_cast<const short8*>(
                    (const unsigned short*)(vt + vbase + (size_t)d*VLP + kb0) + ch*8);
            *reinterpret_cast<short8*>(&Vt[grp][d][ch*8]) = val;
        }
        __syncthreads();

        const int kt = sp*1216 + tt*64;              // compute key base for this wave
        float sv[16];
        float tmax = -3.0e38f;
        #pragma unroll
        for (int t = 0; t < 4; ++t) {
            f32x4 acc = {0.f,0.f,0.f,0.f};
            short8 a0 = *reinterpret_cast<const short8*>(&Ks[sp][t*16 + c][quad*8]);
            short8 a1 = *reinterpret_cast<const short8*>(&Ks[sp][t*16 + c][32 + quad*8]);
            acc = __builtin_amdgcn_mfma_f32_16x16x32_bf16(a0, qf0, acc, 0, 0, 0);
            acc = __builtin_amdgcn_mfma_f32_16x16x32_bf16(a1, qf1, acc, 0, 0, 0);
            #pragma unroll
            for (int r = 0; r < 4; ++r) {
                const int key = kt + t*16 + quad*4 + r;
                const float val = (key < L_) ? acc[r] * 0.14433756729740643f : -3.0e38f;
                sv[t*4 + r] = val;
                tmax = fmaxf(tmax, val);
            }
        }
        tmax = fmaxf(tmax, __shfl_xor(tmax, 16));
        tmax = fmaxf(tmax, __shfl_xor(tmax, 32));
        const float mn = fmaxf(m, tmax);
        const float alpha = __expf(m - mn);
        m = mn;
        float psum = 0.f;
        unsigned short pv[16];
        #pragma unroll
        for (int i = 0; i < 16; ++i) {
            const float p = __expf(sv[i] - m);
            psum += p;
            pv[i] = f2us(p);
        }
        lsum = lsum * alpha + psum;
        o0 *= alpha; o1 *= alpha; o2 *= alpha;
        // P row (query c) -> LDS; same-wave rw, no barrier needed
        #pragma unroll
        for (int t = 0; t < 4; ++t)
            *reinterpret_cast<ushort4*>(&Pq[w][c][t*16 + quad*4]) =
                make_ushort4(pv[t*4+0], pv[t*4+1], pv[t*4+2], pv[t*4+3]);
        // PV in 2 steps of 32 keys
        #pragma unroll
        for (int s = 0; s < 2; ++s) {
            short8 pf  = *reinterpret_cast<const short8*>(&Pq[w][c][s*32 + quad*8]);
            short8 vf0 = *reinterpret_cast<const short8*>(&Vt[sp][c][s*32 + quad*8]);
            short8 vf1 = *reinterpret_cast<const short8*>(&Vt[sp][16 + c][s*32 + quad*8]);
            short8 vf2 = *reinterpret_cast<const short8*>(&Vt[sp][32 + c][s*32 + quad*8]);
            o0 = __builtin_amdgcn_mfma_f32_16x16x32_bf16(vf0, pf, o0, 0, 0, 0);
            o1 = __builtin_amdgcn_mfma_f32_16x16x32_bf16(vf1, pf, o1, 0, 0, 0);
            o2 = __builtin_amdgcn_mfma_f32_16x16x32_bf16(vf2, pf, o2, 0, 0, 0);
        }
    }
    // ---- reduce l across quads within wave
    float lw = lsum;
    lw += __shfl_xor(lw, 16);
    lw += __shfl_xor(lw, 32);
    // ---- split merge through LDS (reuse Pq area; 128*14 floats = 7168 B <= 10240 B)
    float* Mg = (float*)&Pq[0][0][0];
    __syncthreads();
    if (sp == 1) {
        float* dst = Mg + (size_t)(qt*64 + lane)*14;
        dst[0] = o0[0]; dst[1] = o0[1]; dst[2]  = o0[2]; dst[3]  = o0[3];
        dst[4] = o1[0]; dst[5] = o1[1]; dst[6]  = o1[2]; dst[7]  = o1[3];
        dst[8] = o2[0]; dst[9] = o2[1]; dst[10] = o2[2]; dst[11] = o2[3];
        dst[12] = m; dst[13] = lw;
    }
    __syncthreads();
    if (sp == 0 && qvalid) {
        const float* src = Mg + (size_t)(qt*64 + lane)*14;
        const float m2 = src[12], l2 = src[13];
        const float mm = fmaxf(m, m2);
        const float a1 = __expf(m - mm), a2 = __expf(m2 - mm);
        const float inv = 1.0f / (lw*a1 + l2*a2);
        unsigned short* orow = (unsigned short*)(ao + base + (size_t)(q0 + c)*HID);
        const f32x4 ot[3] = {o0, o1, o2};
        #pragma unroll
        for (int dt = 0; dt < 3; ++dt) {
            ushort4 w4;
            w4.x = f2us((ot[dt][0]*a1 + src[dt*4+0]*a2) * inv);
            w4.y = f2us((ot[dt][1]*a1 + src[dt*4+1]*a2) * inv);
            w4.z = f2us((ot[dt][2]*a1 + src[dt*4+2]*a2) * inv);
            w4.w = f2us((ot[dt][3]*a1 + src[dt*4+3]*a2) * inv);
            *reinterpret_cast<ushort4*>(orow + dt*16 + quad*4) = w4;
        }
    }
}

// ------------------------------------------------------- final LN + heads
template <typename T, typename TO>
static __device__ void final_body(
    const float* h, const T* fn_g, const T* fn_b,
    const T* on_w, const T* on_b, const T* oe_w, const T* oe_b, TO* out)
{
    __shared__ float hf[HID];
    const int row = blockIdx.x;
    const int b = row / L_, l = row % L_;
    const int lane = threadIdx.x;
    const float* hr = h + (size_t)row*HID;
    float v[6]; float s = 0.f, ss = 0.f;
    #pragma unroll
    for (int j = 0; j < 6; ++j) { float t = hr[lane + j*64]; v[j] = t; s += t; ss += t*t; }
    #pragma unroll
    for (int off = 32; off; off >>= 1) { s += __shfl_xor(s, off); ss += __shfl_xor(ss, off); }
    const float mu = s * (1.0f/HID);
    const float rs = rsqrtf(fmaxf(ss * (1.0f/HID) - mu*mu, 0.0f) + 1e-5f);
    #pragma unroll
    for (int j = 0; j < 6; ++j) {
        int c = lane + j*64;
        hf[c] = (v[j] - mu) * rs * ldv(fn_g, c) + ldv(fn_b, c);
    }
    __syncthreads();
    if (l < N_) {
        if (lane < A_) {
            float acc = ldv(on_b, lane);
            for (int c = 0; c < HID; ++c) acc += hf[c] * ldv(on_w, (size_t)c*A_ + lane);
            stv(out, (size_t)(b*N_ + l)*A_ + lane, acc);
        }
    } else {
        const int e = l - N_;
        if (lane < E_) {
            float acc = ldv(oe_b, lane);
            for (int c = 0; c < HID; ++c) acc += hf[c] * ldv(oe_w, (size_t)c*E_ + lane);
            stv(out, (size_t)B_*N_*A_ + ((size_t)b*N_*N_ + e)*E_ + lane, acc);
        }
    }
}

__global__ __launch_bounds__(64) void k_final(
    const float* __restrict__ h, const void* fn_g, const void* fn_b,
    const void* on_w, const void* on_b, const void* oe_w, const void* oe_b,
    const int* __restrict__ fl, void* out)
{
    if (*fl) final_body<float, float>(h, (const float*)fn_g, (const float*)fn_b,
                                      (const float*)on_w, (const float*)on_b,
                                      (const float*)oe_w, (const float*)oe_b, (float*)out);
    else     final_body<bf16, bf16>(h, (const bf16*)fn_g, (const bf16*)fn_b,
                                    (const bf16*)on_w, (const bf16*)on_b,
                                    (const bf16*)oe_w, (const bf16*)oe_b, (bf16*)out);
}

// ---------------------------------------------------------------- launch
extern "C" void kernel_launch(void* const* d_in, const int* in_sizes, int n_in,
                              void* d_out, int out_size, void* d_ws, size_t ws_size,
                              hipStream_t stream) {
    const void* x      = d_in[0];
    const void* adj    = d_in[1];
    const void* t      = d_in[2];
    const void* node_w = d_in[3];
    const void* node_b = d_in[4];
    const void* edge_w = d_in[5];
    const void* edge_b = d_in[6];
    const void* pos    = d_in[7];
    const void* t_w1   = d_in[8];
    const void* t_b1   = d_in[9];
    const void* t_w2   = d_in[10];
    const void* t_b2   = d_in[11];
    const void* ada1_w = d_in[12];
    const void* ada1_b = d_in[13];
    const void* ada2_w = d_in[14];
    const void* ada2_b = d_in[15];
    const void* q_w    = d_in[16];
    const void* q_b    = d_in[17];
    const void* k_w    = d_in[18];
    const void* k_b    = d_in[19];
    const void* v_w    = d_in[20];
    const void* v_b    = d_in[21];
    const void* o_w    = d_in[22];
    const void* o_b    = d_in[23];
    const void* m1_w   = d_in[24];
    const void* m1_b   = d_in[25];
    const void* m2_w   = d_in[26];
    const void* m2_b   = d_in[27];
    const void* fn_g   = d_in[28];
    const void* fn_b   = d_in[29];
    const void* on_w   = d_in[30];
    const void* on_b   = d_in[31];
    const void* oe_w   = d_in[32];
    const void* oe_b   = d_in[33];

    const size_t SZ  = (size_t)M_ * HID;          // 1,806,336 elements
    const size_t VTZ = (size_t)B_*NHD*HD*VLP;     // 1,867,776 elements (padded V^T)
    const size_t NEED = 256
        + sizeof(float)*(SZ + 12288 + (size_t)B_*4*HID + (size_t)B_*12*HID)
        + sizeof(bf16)*(3*SZ + VTZ);              // ~21.9 MB
    if (ws_size < NEED) {
        hipMemsetAsync(d_out, 0, (size_t)out_size*sizeof(bf16), stream);  // 1.14 signature
        return;
    }
    int*   fl   = (int*)d_ws;
    float* h    = (float*)((char*)d_ws + 256);
    float* ada  = h + SZ;                  // [8][B_][768]
    float* hid  = ada + 12288;             // [B_][1536]
    float* part = hid + (size_t)B_*4*HID;  // [B_][12][384] cond partials
    bf16* nb  = (bf16*)(part + (size_t)B_*12*HID);
    bf16* qb  = nb + SZ;
    bf16* kb  = qb + SZ;
    bf16* vtb = kb + SZ;                   // transposed V, [bh*48+d][VLP]
    bf16* m1b = kb;                        // [2352,1536] bf16 spans kb+vtb (dead after attn)

    k_detect<<<1, 64, 0, stream>>>(node_w, fl);
    k_embed<<<M_, HID, 0, stream>>>(x, adj, node_w, node_b, edge_w, edge_b, pos, fl, h);
    k_cond1<<<dim3(B_, 24), 256, 0, stream>>>(t, t_w1, t_b1, fl, hid);
    k_cond2<<<dim3(B_, 12), 384, 0, stream>>>(t_w2, t_b2, fl, hid, part);
    k_cond3<<<dim3(24, B_), 256, 0, stream>>>(ada1_w, ada1_b, ada2_w, ada2_b, fl, part, ada);
    for (int i = 0; i < LYR; ++i) {
        const long long woff   = (long long)i * HID * HID;
        const long long boff   = (long long)i * HID;
        const long long m1woff = (long long)i * HID * MLPD;
        const long long m1boff = (long long)i * MLPD;
        const long long m2woff = (long long)i * MLPD * HID;

        k_adaln<<<M_/4, 256, 0, stream>>>(h, ada, nb, 2*i);
        k_gemm_qkv<<<dim3(74, 6, 3), 256, 0, stream>>>(nb, q_w, k_w, v_w, q_b, k_b, v_b,
                                                       woff, boff, qb, kb, vtb, fl);
        k_attn<<<dim3(74, B_*NHD), 256, 0, stream>>>(qb, kb, vtb, nb);     // ao -> nb
        k_gemm<<<dim3(74, 6), 256, 0, stream>>>(nb, o_w, woff, o_b, boff,
                                                nullptr, h, M_, HID, HID, 0, 1, fl);
        k_adaln<<<M_/4, 256, 0, stream>>>(h, ada, nb, 2*i + 1);            // n2 -> nb
        for (int c = 0; c < 2; ++c) {
            k_gemm<<<dim3(37, 24), 256, 0, stream>>>(nb + (size_t)c*2352*HID,
                                                     m1_w, m1woff, m1_b, m1boff,
                                                     m1b, nullptr, 2352, MLPD, HID, 1, 0, fl);
            k_gemm<<<dim3(37, 6), 256, 0, stream>>>(m1b, m2_w, m2woff, m2_b, boff,
                                                    nullptr, h + (size_t)c*2352*HID,
                                                    2352, HID, MLPD, 0, 1, fl);
        }
    }
    k_final<<<M_, 64, 0, stream>>>(h, fn_g, fn_b, on_w, on_b, oe_w, oe_b, fl, (void*)d_out);
}

// Round 11
// 1108.488 us; speedup vs baseline: 9.1353x; 1.1531x over previous
//
#include <hip/hip_runtime.h>
#include <hip/hip_bf16.h>
#include <math.h>

typedef __hip_bfloat16 bf16;
typedef __attribute__((ext_vector_type(8))) short short8;   // 8 bf16 in 4 VGPRs
typedef __attribute__((ext_vector_type(4))) short short4b;  // 4 bf16 in 2 VGPRs
typedef __attribute__((ext_vector_type(4))) float f32x4;

#if defined(__has_builtin)
#if __has_builtin(__builtin_amdgcn_mfma_f32_16x16x16bf16_1k)
#define HAVE_MFMA16K 1
#endif
#endif

#define B_ 2
#define N_ 48
#define A_ 16
#define E_ 5
#define HID 384
#define NHD 8
#define HD 48
#define LYR 4
#define MLPD 1536
#define L_ 2352      // N_ + N_*N_
#define M_ 4704      // B_*L_
#define VLP 2432     // padded key stride of transposed-V buffer (19*64*2 splits)
// 1/sqrt(48) * log2(e): Q pre-scale so softmax runs in log2 domain (exp2f)
#define QSCALE 0.20823513f

static __device__ __forceinline__ float b2f(bf16 v) { return __bfloat162float(v); }
static __device__ __forceinline__ float us2f(unsigned short u) {
    return __uint_as_float(((unsigned)u) << 16);
}
static __device__ __forceinline__ unsigned short f2us(float f) {
    bf16 h = __float2bfloat16(f);
    return *reinterpret_cast<unsigned short*>(&h);
}
static __device__ __forceinline__ float ldv(const float* p, size_t i) { return p[i]; }
static __device__ __forceinline__ float ldv(const bf16*  p, size_t i) { return b2f(p[i]); }
static __device__ __forceinline__ void  stv(float* p, size_t i, float v) { p[i] = v; }
static __device__ __forceinline__ void  stv(bf16*  p, size_t i, float v) { p[i] = __float2bfloat16(v); }
static __device__ __forceinline__ float4 ld4(const float* p, size_t i) {
    return *reinterpret_cast<const float4*>(p + i);
}
static __device__ __forceinline__ float4 ld4(const bf16* p, size_t i) {
    ushort4 u = *reinterpret_cast<const ushort4*>(p + i);
    return make_float4(us2f(u.x), us2f(u.y), us2f(u.z), us2f(u.w));
}

// ------------------------------------------------ dtype detect (flag: 1=fp32, 0=bf16)
__global__ void k_detect(const void* w, int* flag) {
    if (threadIdx.x == 0 && blockIdx.x == 0) {
        const bf16* p = (const bf16*)w;   // node_w: 6144 elems of 0.02*normal
        int isf = 0;
        for (int i = 0; i < 256; ++i) {
            float v = fabsf(b2f(p[i]));
            if (!(v <= 1000.0f)) { isf = 1; break; }
        }
        *flag = isf;
    }
}

// ---------------------------------------------------------------- embed (-> f32 h)
template <typename T>
static __device__ void embed_body(
    const T* x, const T* adj, const T* node_w, const T* node_b,
    const T* edge_w, const T* edge_b, const T* pos, float* h)
{
    const int bl = blockIdx.x;
    const int b = bl / L_, l = bl % L_;
    const int c = threadIdx.x;          // 0..383
    float acc;
    if (l < N_) {
        acc = ldv(node_b, c);
        const size_t xr = (size_t)(b*N_ + l)*A_;
        #pragma unroll
        for (int a = 0; a < A_; ++a) acc += ldv(x, xr + a) * ldv(node_w, (size_t)a*HID + c);
    } else {
        const int e = l - N_;
        acc = ldv(edge_b, c);
        const size_t ar = ((size_t)b*N_*N_ + e)*E_;
        #pragma unroll
        for (int j = 0; j < E_; ++j) acc += ldv(adj, ar + j) * ldv(edge_w, (size_t)j*HID + c);
    }
    h[(size_t)bl*HID + c] = acc + ldv(pos, (size_t)l*HID + c);
}

__global__ __launch_bounds__(384) void k_embed(
    const void* x, const void* adj, const void* node_w, const void* node_b,
    const void* edge_w, const void* edge_b, const void* pos,
    const int* __restrict__ fl, float* __restrict__ h)
{
    if (*fl) embed_body<float>((const float*)x, (const float*)adj, (const float*)node_w,
                               (const float*)node_b, (const float*)edge_w, (const float*)edge_b,
                               (const float*)pos, h);
    else     embed_body<bf16>((const bf16*)x, (const bf16*)adj, (const bf16*)node_w,
                              (const bf16*)node_b, (const bf16*)edge_w, (const bf16*)edge_b,
                              (const bf16*)pos, h);
}

// ---------------------------------------- cond stage 1: temb -> hidden (SiLU)
// grid (B_, 24), block 256 = 4 K-quarters x 64 outputs; LDS reduce.
template <typename T>
static __device__ void cond1_body(const T* t, const T* t_w1, const T* t_b1, float* hid)
{
    __shared__ float temb[HID];
    __shared__ float red[4][64];
    const int b = blockIdx.x, jb = blockIdx.y, tid = threadIdx.x;
    const float tv = ldv(t, b);
    for (int c = tid; c < HID; c += 256) {
        int i = (c < 192) ? c : c - 192;
        float f = expf(-9.2103403719761836f * (float)i / 192.0f);
        float ang = tv * f;
        temb[c] = (c < 192) ? sinf(ang) : cosf(ang);
    }
    __syncthreads();
    const int ko = tid >> 6, jo = tid & 63;
    const int j = jb*64 + jo;
    float acc = 0.f;
    for (int i = ko*96; i < (ko + 1)*96; ++i)
        acc += temb[i] * ldv(t_w1, (size_t)i*4*HID + j);
    red[ko][jo] = acc;
    __syncthreads();
    if (ko == 0) {
        float a = red[0][jo] + red[1][jo] + red[2][jo] + red[3][jo] + ldv(t_b1, j);
        hid[(size_t)b*4*HID + j] = a / (1.0f + expf(-a));   // SiLU
    }
}

__global__ __launch_bounds__(256) void k_cond1(
    const void* t, const void* t_w1, const void* t_b1,
    const int* __restrict__ fl, float* __restrict__ hid)
{
    if (*fl) cond1_body<float>((const float*)t, (const float*)t_w1, (const float*)t_b1, hid);
    else     cond1_body<bf16>((const bf16*)t, (const bf16*)t_w1, (const bf16*)t_b1, hid);
}

// ---------------------------------------- cond stage 2: hidden -> partial cond sums
template <typename T>
static __device__ void cond2_body(const T* t_w2, const T* t_b2, const float* hid, float* part)
{
    __shared__ float hs[128];
    const int b = blockIdx.x, ch = blockIdx.y, c = threadIdx.x;
    const int j0 = ch*128;
    if (c < 128) hs[c] = hid[(size_t)b*4*HID + j0 + c];
    __syncthreads();
    float acc = (ch == 0) ? ldv(t_b2, c) : 0.f;
    for (int jj = 0; jj < 128; ++jj)
        acc += hs[jj] * ldv(t_w2, (size_t)(j0 + jj)*HID + c);
    part[((size_t)b*12 + ch)*HID + c] = acc;
}

__global__ __launch_bounds__(384) void k_cond2(
    const void* t_w2, const void* t_b2, const int* __restrict__ fl,
    const float* __restrict__ hid, float* __restrict__ part)
{
    if (*fl) cond2_body<float>((const float*)t_w2, (const float*)t_b2, hid, part);
    else     cond2_body<bf16>((const bf16*)t_w2, (const bf16*)t_b2, hid, part);
}

// ---------------------------------------- cond stage 3: ada projections
template <typename T>
static __device__ void cond3_body(
    const T* ada1_w, const T* ada1_b, const T* ada2_w, const T* ada2_b,
    const float* part, float* ada_out)
{
    __shared__ float cs[HID];
    const int slot = blockIdx.x / 3, ob = blockIdx.x % 3, b = blockIdx.y;
    const int tid = threadIdx.x;
    for (int c = tid; c < HID; c += 256) {
        float s = 0.f;
        #pragma unroll
        for (int ch = 0; ch < 12; ++ch) s += part[((size_t)b*12 + ch)*HID + c];
        cs[c] = s;
    }
    __syncthreads();
    const int layer = slot >> 1, which = slot & 1;
    const int o = ob*256 + tid;
    const T* W  = which ? ada2_w : ada1_w;
    const T* Bi = which ? ada2_b : ada1_b;
    float acc = ldv(Bi, (size_t)layer*768 + o);
    const size_t wb = (size_t)layer*HID*768 + o;
    for (int c = 0; c < HID; ++c) acc += cs[c] * ldv(W, wb + (size_t)c*768);
    ada_out[((size_t)slot*B_ + b)*768 + o] = acc;
}

__global__ __launch_bounds__(256) void k_cond3(
    const void* ada1_w, const void* ada1_b, const void* ada2_w, const void* ada2_b,
    const int* __restrict__ fl, const float* __restrict__ part, float* __restrict__ ada_out)
{
    if (*fl) cond3_body<float>((const float*)ada1_w, (const float*)ada1_b,
                               (const float*)ada2_w, (const float*)ada2_b, part, ada_out);
    else     cond3_body<bf16>((const bf16*)ada1_w, (const bf16*)ada1_b,
                              (const bf16*)ada2_w, (const bf16*)ada2_b, part, ada_out);
}

// ---------------------------------------------------------------- adaLN (f32 h -> bf16 n)
__global__ __launch_bounds__(256) void k_adaln(
    const float* __restrict__ h, const float* __restrict__ ada,
    bf16* __restrict__ n, int slot)
{
    const int row  = blockIdx.x * 4 + (threadIdx.x >> 6);
    const int lane = threadIdx.x & 63;
    const int b = row / L_;
    const float* hr = h + (size_t)row*HID;
    float v[6]; float s = 0.f, ss = 0.f;
    #pragma unroll
    for (int j = 0; j < 6; ++j) { float t = hr[lane + j*64]; v[j] = t; s += t; ss += t*t; }
    #pragma unroll
    for (int off = 32; off; off >>= 1) { s += __shfl_xor(s, off); ss += __shfl_xor(ss, off); }
    const float mu = s * (1.0f/HID);
    const float rs = rsqrtf(fmaxf(ss * (1.0f/HID) - mu*mu, 0.0f) + 1e-5f);
    const float* ap = ada + ((size_t)slot*B_ + b)*768;
    bf16* nr = n + (size_t)row*HID;
    #pragma unroll
    for (int j = 0; j < 6; ++j) {
        int c = lane + j*64;
        nr[c] = __float2bfloat16((v[j] - mu)*rs*(1.0f + ap[c]) + ap[384 + c]);
    }
}

// ------------------------------------------------- MFMA GEMM  C = act(A@W + bias)
// BK=64. Tile 64x64, 4 waves 2x2, each wave 2x2 mfma 16x16x32.
// mode 0: Cb = bf16(r)   mode 1: Cf += r   mode 2: V^T store   mode 3: bf16(r*QSCALE)
template <typename T>
static __device__ void gemm_body(
    const bf16* A, const T* W, long long woff, const T* bias, long long boff,
    bf16* Cb, float* Cf, int M, int N, int K, int act, int mode)
{
    __shared__ __align__(16) unsigned short As[64][72];   // [m][k0..63], 144B rows
    __shared__ __align__(16) unsigned short Bt[64][72];   // [n][k]
    const int tid  = threadIdx.x;
    const int wv   = tid >> 6, lane = tid & 63;
    const int quad = lane >> 4, c = lane & 15;
    const int wm = wv & 1, wn = wv >> 1;
    const int bm = blockIdx.x * 64, bn = blockIdx.y * 64;
    const int arow = tid >> 3, ach = tid & 7;   // A/W slot decomposition (+32 rows per i)
    f32x4 acc[2][2] = {{{0.f,0.f,0.f,0.f},{0.f,0.f,0.f,0.f}},
                       {{0.f,0.f,0.f,0.f},{0.f,0.f,0.f,0.f}}};
    for (int k0 = 0; k0 < K; k0 += 64) {
        short8 av[2]; float4 w0[2], w1[2];
        #pragma unroll
        for (int i = 0; i < 2; ++i) {
            const int row = i*32 + arow;
            av[i] = short8{0,0,0,0,0,0,0,0};
            if (bm + row < M)
                av[i] = *reinterpret_cast<const short8*>(
                            A + (size_t)(bm + row)*K + k0 + ach*8);
            const size_t wrow = (size_t)woff + (size_t)(k0 + i*32 + arow)*N + bn + ach*8;
            w0[i] = ld4(W, wrow);
            w1[i] = ld4(W, wrow + 4);
        }
        __syncthreads();
        #pragma unroll
        for (int i = 0; i < 2; ++i) {
            *reinterpret_cast<short8*>(&As[i*32 + arow][ach*8]) = av[i];
            const int kk = i*32 + arow, nb0 = ach*8;
            Bt[nb0+0][kk] = f2us(w0[i].x); Bt[nb0+1][kk] = f2us(w0[i].y);
            Bt[nb0+2][kk] = f2us(w0[i].z); Bt[nb0+3][kk] = f2us(w0[i].w);
            Bt[nb0+4][kk] = f2us(w1[i].x); Bt[nb0+5][kk] = f2us(w1[i].y);
            Bt[nb0+6][kk] = f2us(w1[i].z); Bt[nb0+7][kk] = f2us(w1[i].w);
        }
        __syncthreads();
        #pragma unroll
        for (int ks = 0; ks < 2; ++ks) {
            short8 af[2], bfr[2];
            #pragma unroll
            for (int mi = 0; mi < 2; ++mi)
                af[mi] = *reinterpret_cast<const short8*>(
                             &As[wm*32 + mi*16 + c][ks*32 + quad*8]);
            #pragma unroll
            for (int ni = 0; ni < 2; ++ni)
                bfr[ni] = *reinterpret_cast<const short8*>(
                              &Bt[wn*32 + ni*16 + c][ks*32 + quad*8]);
            #pragma unroll
            for (int mi = 0; mi < 2; ++mi)
                #pragma unroll
                for (int ni = 0; ni < 2; ++ni)
                    acc[mi][ni] = __builtin_amdgcn_mfma_f32_16x16x32_bf16(
                                      af[mi], bfr[ni], acc[mi][ni], 0, 0, 0);
        }
    }
    float bcol[2];
    #pragma unroll
    for (int ni = 0; ni < 2; ++ni)
        bcol[ni] = ldv(bias, (size_t)boff + bn + wn*32 + ni*16 + c);
    #pragma unroll
    for (int mi = 0; mi < 2; ++mi)
        #pragma unroll
        for (int ni = 0; ni < 2; ++ni) {
            const int col = bn + wn*32 + ni*16 + c;
            #pragma unroll
            for (int r = 0; r < 4; ++r) {
                const int row = bm + wm*32 + mi*16 + quad*4 + r;
                if (row < M) {
                    float v = acc[mi][ni][r] + bcol[ni];
                    if (act) v = 0.5f * v * (1.0f + erff(v * 0.70710678118654752f));  // GELU
                    if (mode == 1) Cf[(size_t)row*N + col] += v;
                    else if (mode == 0) Cb[(size_t)row*N + col] = __float2bfloat16(v);
                    else if (mode == 3) Cb[(size_t)row*N + col] = __float2bfloat16(v * QSCALE);
                    else {
                        const int b   = row >= L_ ? 1 : 0;
                        const int key = row - b*L_;
                        const int hh  = col / 48, d = col - hh*48;
                        Cb[((size_t)(b*8 + hh)*48 + d)*VLP + key] = __float2bfloat16(v);
                    }
                }
            }
        }
}

__global__ __launch_bounds__(256) void k_gemm(
    const bf16* __restrict__ A, const void* W, long long woff, const void* bias, long long boff,
    bf16* Cb, float* Cf, int M, int N, int K, int act, int mode,
    const int* __restrict__ fl)
{
    if (*fl) gemm_body<float>(A, (const float*)W, woff, (const float*)bias, boff,
                              Cb, Cf, M, N, K, act, mode);
    else     gemm_body<bf16>(A, (const bf16*)W, woff, (const bf16*)bias, boff,
                             Cb, Cf, M, N, K, act, mode);
}

// QKV batched: z=0 Q (mode 3: pre-scaled), z=1 K, z=2 V (mode 2: transposed store)
__global__ __launch_bounds__(256) void k_gemm_qkv(
    const bf16* __restrict__ A,
    const void* qw, const void* kw, const void* vw,
    const void* qb, const void* kb, const void* vb,
    long long woff, long long boff,
    bf16* Cq, bf16* Ck, bf16* Cv, const int* __restrict__ fl)
{
    const int z = blockIdx.z;
    const void* W  = (z == 0) ? qw : (z == 1) ? kw : vw;
    const void* Bi = (z == 0) ? qb : (z == 1) ? kb : vb;
    bf16* C        = (z == 0) ? Cq : (z == 1) ? Ck : Cv;
    const int mode = (z == 0) ? 3 : (z == 2) ? 2 : 0;
    if (*fl) gemm_body<float>(A, (const float*)W, woff, (const float*)Bi, boff,
                              C, nullptr, M_, HID, HID, 0, mode);
    else     gemm_body<bf16>(A, (const bf16*)W, woff, (const bf16*)Bi, boff,
                             C, nullptr, M_, HID, HID, 0, mode);
}

// ---------------------------------------------------------------- MFMA flash attention
// 64-key tiles, pre-transposed V, in-block split-K x2. Q pre-scaled by QSCALE
// (log2 domain -> exp2f). PV via mfma 16x16x16: P's C-layout (row=quad*4+r)
// IS the 16x16x16 B-fragment layout (k=quad*4+j) -> P stays in registers.
__global__ __launch_bounds__(256) void k_attn(
    const bf16* __restrict__ q, const bf16* __restrict__ k,
    const bf16* __restrict__ vt, bf16* __restrict__ ao)
{
    __shared__ __align__(16) unsigned short Ks[2][64][80];   // [split][key][d 0..63 +pad]
    __shared__ __align__(16) unsigned short Vt[2][48][72];   // [split][d][key 0..63 +pad]
#ifndef HAVE_MFMA16K
    __shared__ __align__(16) unsigned short Pq[4][16][80];   // fallback P staging
#endif
    const int tid  = threadIdx.x;
    const int w    = tid >> 6, lane = tid & 63;
    const int quad = lane >> 4, c = lane & 15;
    const int qt = w & 1, sp = w >> 1;
    const int bh = blockIdx.y;                       // b*8+hh
    const size_t base  = (size_t)(bh >> 3)*L_*HID + (size_t)(bh & 7)*HD;
    const size_t vbase = (size_t)bh*48*VLP;
    const int q0 = blockIdx.x*32 + qt*16;
    const bool qvalid = q0 < L_;                     // wave-uniform
    const int qrow = qvalid ? (q0 + c) : c;

    short8 qf0, qf1;
    {
        const unsigned short* qp = (const unsigned short*)(q + base + (size_t)qrow*HID);
        qf0 = *reinterpret_cast<const short8*>(qp + quad*8);                 // d 0..31
        if (quad < 2) qf1 = *reinterpret_cast<const short8*>(qp + 32 + quad*8);  // d 32..47
        else          qf1 = short8{0,0,0,0,0,0,0,0};                         // d 48..63 pad
    }
    f32x4 o0 = {0.f,0.f,0.f,0.f}, o1 = {0.f,0.f,0.f,0.f}, o2 = {0.f,0.f,0.f,0.f};
    float m = -3.0e38f, lsum = 0.f;
    const int t128 = tid & 127, grp = tid >> 7;      // staging group == its waves' split

    for (int tt = 0; tt < 19; ++tt) {
        const int kb0 = grp*1216 + tt*64;            // staging key base
        __syncthreads();
        // ---- K staging: 512 short8 slots (row 0..63, ch 0..7 => d 0..63; ch>=6 zero)
        #pragma unroll
        for (int ii = 0; ii < 4; ++ii) {
            const int idx = t128 + ii*128;
            const int row = idx >> 3, ch = idx & 7;
            short8 val = short8{0,0,0,0,0,0,0,0};
            if (ch < 6) {
                const int key = min(kb0 + row, L_ - 1);   // clamp; masked on S side
                val = *reinterpret_cast<const short8*>(
                        (const unsigned short*)(k + base + (size_t)key*HID) + ch*8);
            }
            *reinterpret_cast<short8*>(&Ks[grp][row][ch*8]) = val;
        }
        // ---- V staging (pre-transposed in global): 384 short8 slots
        #pragma unroll
        for (int ii = 0; ii < 3; ++ii) {
            const int idx = t128 + ii*128;
            const int d = idx >> 3, ch = idx & 7;
            short8 val = *reinterpret_cast<const short8*>(
                    (const unsigned short*)(vt + vbase + (size_t)d*VLP + kb0) + ch*8);
            *reinterpret_cast<short8*>(&Vt[grp][d][ch*8]) = val;
        }
        __syncthreads();

        const int kt = sp*1216 + tt*64;              // compute key base for this wave
        float sv[16];
        #pragma unroll
        for (int t = 0; t < 4; ++t) {
            f32x4 acc = {0.f,0.f,0.f,0.f};
            short8 a0 = *reinterpret_cast<const short8*>(&Ks[sp][t*16 + c][quad*8]);
            short8 a1 = *reinterpret_cast<const short8*>(&Ks[sp][t*16 + c][32 + quad*8]);
            acc = __builtin_amdgcn_mfma_f32_16x16x32_bf16(a0, qf0, acc, 0, 0, 0);
            acc = __builtin_amdgcn_mfma_f32_16x16x32_bf16(a1, qf1, acc, 0, 0, 0);
            #pragma unroll
            for (int r = 0; r < 4; ++r) sv[t*4 + r] = acc[r];   // already log2-scaled
        }
        if (sp == 1 && tt == 18) {                   // only tile with keys >= L_
            #pragma unroll
            for (int t = 0; t < 4; ++t)
                #pragma unroll
                for (int r = 0; r < 4; ++r)
                    if (kt + t*16 + quad*4 + r >= L_) sv[t*4 + r] = -3.0e38f;
        }
        float tmax = sv[0];
        #pragma unroll
        for (int i = 1; i < 16; ++i) tmax = fmaxf(tmax, sv[i]);
        tmax = fmaxf(tmax, __shfl_xor(tmax, 16));
        tmax = fmaxf(tmax, __shfl_xor(tmax, 32));
        const float mn = fmaxf(m, tmax);
        const float alpha = exp2f(m - mn);
        m = mn;
        float psum = 0.f;
        unsigned short pv[16];
        #pragma unroll
        for (int i = 0; i < 16; ++i) {
            const float p = exp2f(sv[i] - m);
            psum += p;
            pv[i] = f2us(p);
        }
        lsum = lsum * alpha + psum;
        o0 *= alpha; o1 *= alpha; o2 *= alpha;
#ifdef HAVE_MFMA16K
        // P in registers: C-layout row=quad*4+r == 16x16x16 B-fragment k=quad*4+j
        #pragma unroll
        for (int t = 0; t < 4; ++t) {
            short4b pb;
            pb[0] = (short)pv[4*t+0]; pb[1] = (short)pv[4*t+1];
            pb[2] = (short)pv[4*t+2]; pb[3] = (short)pv[4*t+3];
            const int ko = t*16 + quad*4;
            short4b vf0 = *reinterpret_cast<const short4b*>(&Vt[sp][c][ko]);
            short4b vf1 = *reinterpret_cast<const short4b*>(&Vt[sp][16 + c][ko]);
            short4b vf2 = *reinterpret_cast<const short4b*>(&Vt[sp][32 + c][ko]);
            o0 = __builtin_amdgcn_mfma_f32_16x16x16bf16_1k(vf0, pb, o0, 0, 0, 0);
            o1 = __builtin_amdgcn_mfma_f32_16x16x16bf16_1k(vf1, pb, o1, 0, 0, 0);
            o2 = __builtin_amdgcn_mfma_f32_16x16x16bf16_1k(vf2, pb, o2, 0, 0, 0);
        }
#else
        // fallback: P via LDS round-trip (round-10 path)
        #pragma unroll
        for (int t = 0; t < 4; ++t)
            *reinterpret_cast<ushort4*>(&Pq[w][c][t*16 + quad*4]) =
                make_ushort4(pv[t*4+0], pv[t*4+1], pv[t*4+2], pv[t*4+3]);
        #pragma unroll
        for (int s = 0; s < 2; ++s) {
            short8 pf  = *reinterpret_cast<const short8*>(&Pq[w][c][s*32 + quad*8]);
            short8 vf0 = *reinterpret_cast<const short8*>(&Vt[sp][c][s*32 + quad*8]);
            short8 vf1 = *reinterpret_cast<const short8*>(&Vt[sp][16 + c][s*32 + quad*8]);
            short8 vf2 = *reinterpret_cast<const short8*>(&Vt[sp][32 + c][s*32 + quad*8]);
            o0 = __builtin_amdgcn_mfma_f32_16x16x32_bf16(vf0, pf, o0, 0, 0, 0);
            o1 = __builtin_amdgcn_mfma_f32_16x16x32_bf16(vf1, pf, o1, 0, 0, 0);
            o2 = __builtin_amdgcn_mfma_f32_16x16x32_bf16(vf2, pf, o2, 0, 0, 0);
        }
#endif
    }
    // ---- reduce l across quads within wave
    float lw = lsum;
    lw += __shfl_xor(lw, 16);
    lw += __shfl_xor(lw, 32);
    // ---- split merge through LDS (reuse Ks[0] area: 9216 B >= 7168 B; Ks dead here)
    float* Mg = (float*)&Ks[0][0][0];
    __syncthreads();
    if (sp == 1) {
        float* dst = Mg + (size_t)(qt*64 + lane)*14;
        dst[0] = o0[0]; dst[1] = o0[1]; dst[2]  = o0[2]; dst[3]  = o0[3];
        dst[4] = o1[0]; dst[5] = o1[1]; dst[6]  = o1[2]; dst[7]  = o1[3];
        dst[8] = o2[0]; dst[9] = o2[1]; dst[10] = o2[2]; dst[11] = o2[3];
        dst[12] = m; dst[13] = lw;
    }
    __syncthreads();
    if (sp == 0 && qvalid) {
        const float* src = Mg + (size_t)(qt*64 + lane)*14;
        const float m2 = src[12], l2 = src[13];
        const float mm = fmaxf(m, m2);
        const float a1 = exp2f(m - mm), a2 = exp2f(m2 - mm);
        const float inv = 1.0f / (lw*a1 + l2*a2);
        unsigned short* orow = (unsigned short*)(ao + base + (size_t)(q0 + c)*HID);
        const f32x4 ot[3] = {o0, o1, o2};
        #pragma unroll
        for (int dt = 0; dt < 3; ++dt) {
            ushort4 w4;
            w4.x = f2us((ot[dt][0]*a1 + src[dt*4+0]*a2) * inv);
            w4.y = f2us((ot[dt][1]*a1 + src[dt*4+1]*a2) * inv);
            w4.z = f2us((ot[dt][2]*a1 + src[dt*4+2]*a2) * inv);
            w4.w = f2us((ot[dt][3]*a1 + src[dt*4+3]*a2) * inv);
            *reinterpret_cast<ushort4*>(orow + dt*16 + quad*4) = w4;
        }
    }
}

// ------------------------------------------------------- final LN + heads
template <typename T, typename TO>
static __device__ void final_body(
    const float* h, const T* fn_g, const T* fn_b,
    const T* on_w, const T* on_b, const T* oe_w, const T* oe_b, TO* out)
{
    __shared__ float hf[HID];
    const int row = blockIdx.x;
    const int b = row / L_, l = row % L_;
    const int lane = threadIdx.x;
    const float* hr = h + (size_t)row*HID;
    float v[6]; float s = 0.f, ss = 0.f;
    #pragma unroll
    for (int j = 0; j < 6; ++j) { float t = hr[lane + j*64]; v[j] = t; s += t; ss += t*t; }
    #pragma unroll
    for (int off = 32; off; off >>= 1) { s += __shfl_xor(s, off); ss += __shfl_xor(ss, off); }
    const float mu = s * (1.0f/HID);
    const float rs = rsqrtf(fmaxf(ss * (1.0f/HID) - mu*mu, 0.0f) + 1e-5f);
    #pragma unroll
    for (int j = 0; j < 6; ++j) {
        int c = lane + j*64;
        hf[c] = (v[j] - mu) * rs * ldv(fn_g, c) + ldv(fn_b, c);
    }
    __syncthreads();
    if (l < N_) {
        if (lane < A_) {
            float acc = ldv(on_b, lane);
            for (int c = 0; c < HID; ++c) acc += hf[c] * ldv(on_w, (size_t)c*A_ + lane);
            stv(out, (size_t)(b*N_ + l)*A_ + lane, acc);
        }
    } else {
        const int e = l - N_;
        if (lane < E_) {
            float acc = ldv(oe_b, lane);
            for (int c = 0; c < HID; ++c) acc += hf[c] * ldv(oe_w, (size_t)c*E_ + lane);
            stv(out, (size_t)B_*N_*A_ + ((size_t)b*N_*N_ + e)*E_ + lane, acc);
        }
    }
}

__global__ __launch_bounds__(64) void k_final(
    const float* __restrict__ h, const void* fn_g, const void* fn_b,
    const void* on_w, const void* on_b, const void* oe_w, const void* oe_b,
    const int* __restrict__ fl, void* out)
{
    if (*fl) final_body<float, float>(h, (const float*)fn_g, (const float*)fn_b,
                                      (const float*)on_w, (const float*)on_b,
                                      (const float*)oe_w, (const float*)oe_b, (float*)out);
    else     final_body<bf16, bf16>(h, (const bf16*)fn_g, (const bf16*)fn_b,
                                    (const bf16*)on_w, (const bf16*)on_b,
                                    (const bf16*)oe_w, (const bf16*)oe_b, (bf16*)out);
}

// ---------------------------------------------------------------- launch
extern "C" void kernel_launch(void* const* d_in, const int* in_sizes, int n_in,
                              void* d_out, int out_size, void* d_ws, size_t ws_size,
                              hipStream_t stream) {
    const void* x      = d_in[0];
    const void* adj    = d_in[1];
    const void* t      = d_in[2];
    const void* node_w = d_in[3];
    const void* node_b = d_in[4];
    const void* edge_w = d_in[5];
    const void* edge_b = d_in[6];
    const void* pos    = d_in[7];
    const void* t_w1   = d_in[8];
    const void* t_b1   = d_in[9];
    const void* t_w2   = d_in[10];
    const void* t_b2   = d_in[11];
    const void* ada1_w = d_in[12];
    const void* ada1_b = d_in[13];
    const void* ada2_w = d_in[14];
    const void* ada2_b = d_in[15];
    const void* q_w    = d_in[16];
    const void* q_b    = d_in[17];
    const void* k_w    = d_in[18];
    const void* k_b    = d_in[19];
    const void* v_w    = d_in[20];
    const void* v_b    = d_in[21];
    const void* o_w    = d_in[22];
    const void* o_b    = d_in[23];
    const void* m1_w   = d_in[24];
    const void* m1_b   = d_in[25];
    const void* m2_w   = d_in[26];
    const void* m2_b   = d_in[27];
    const void* fn_g   = d_in[28];
    const void* fn_b   = d_in[29];
    const void* on_w   = d_in[30];
    const void* on_b   = d_in[31];
    const void* oe_w   = d_in[32];
    const void* oe_b   = d_in[33];

    const size_t SZ  = (size_t)M_ * HID;          // 1,806,336 elements
    const size_t VTZ = (size_t)B_*NHD*HD*VLP;     // 1,867,776 elements (padded V^T)
    const size_t NEED = 256
        + sizeof(float)*(SZ + 12288 + (size_t)B_*4*HID + (size_t)B_*12*HID)
        + sizeof(bf16)*(3*SZ + VTZ);              // ~21.9 MB
    // full-width MLP m1 spans qb..vtb + tail
    const size_t M1FULL = (size_t)M_ * MLPD;      // 7,225,344 elements
    const size_t EXTRA  = M1FULL - (2*SZ + VTZ);  // 1,744,896 elements
    const size_t NEED_BIG = NEED + sizeof(bf16)*EXTRA;   // ~25.4 MB
    if (ws_size < NEED) {
        hipMemsetAsync(d_out, 0, (size_t)out_size*sizeof(bf16), stream);  // 1.14 signature
        return;
    }
    const bool big = (ws_size >= NEED_BIG);
    int*   fl   = (int*)d_ws;
    float* h    = (float*)((char*)d_ws + 256);
    float* ada  = h + SZ;                  // [8][B_][768]
    float* hid  = ada + 12288;             // [B_][1536]
    float* part = hid + (size_t)B_*4*HID;  // [B_][12][384] cond partials
    bf16* nb  = (bf16*)(part + (size_t)B_*12*HID);
    bf16* qb  = nb + SZ;
    bf16* kb  = qb + SZ;
    bf16* vtb = kb + SZ;                   // transposed V, [bh*48+d][VLP]
    bf16* m1c = kb;                        // chunked m1: [2352,1536] spans kb+vtb
    bf16* m1f = qb;                        // full m1: [M_,1536] spans qb..vtb+tail

    k_detect<<<1, 64, 0, stream>>>(node_w, fl);
    k_embed<<<M_, HID, 0, stream>>>(x, adj, node_w, node_b, edge_w, edge_b, pos, fl, h);
    k_cond1<<<dim3(B_, 24), 256, 0, stream>>>(t, t_w1, t_b1, fl, hid);
    k_cond2<<<dim3(B_, 12), 384, 0, stream>>>(t_w2, t_b2, fl, hid, part);
    k_cond3<<<dim3(24, B_), 256, 0, stream>>>(ada1_w, ada1_b, ada2_w, ada2_b, fl, part, ada);
    for (int i = 0; i < LYR; ++i) {
        const long long woff   = (long long)i * HID * HID;
        const long long boff   = (long long)i * HID;
        const long long m1woff = (long long)i * HID * MLPD;
        const long long m1boff = (long long)i * MLPD;
        const long long m2woff = (long long)i * MLPD * HID;

        k_adaln<<<M_/4, 256, 0, stream>>>(h, ada, nb, 2*i);
        k_gemm_qkv<<<dim3(74, 6, 3), 256, 0, stream>>>(nb, q_w, k_w, v_w, q_b, k_b, v_b,
                                                       woff, boff, qb, kb, vtb, fl);
        k_attn<<<dim3(74, B_*NHD), 256, 0, stream>>>(qb, kb, vtb, nb);     // ao -> nb
        k_gemm<<<dim3(74, 6), 256, 0, stream>>>(nb, o_w, woff, o_b, boff,
                                                nullptr, h, M_, HID, HID, 0, 1, fl);
        k_adaln<<<M_/4, 256, 0, stream>>>(h, ada, nb, 2*i + 1);            // n2 -> nb
        if (big) {
            k_gemm<<<dim3(74, 24), 256, 0, stream>>>(nb, m1_w, m1woff, m1_b, m1boff,
                                                     m1f, nullptr, M_, MLPD, HID, 1, 0, fl);
            k_gemm<<<dim3(74, 6), 256, 0, stream>>>(m1f, m2_w, m2woff, m2_b, boff,
                                                    nullptr, h, M_, HID, MLPD, 0, 1, fl);
        } else {
            for (int c = 0; c < 2; ++c) {
                k_gemm<<<dim3(37, 24), 256, 0, stream>>>(nb + (size_t)c*2352*HID,
                                                         m1_w, m1woff, m1_b, m1boff,
                                                         m1c, nullptr, 2352, MLPD, HID, 1, 0, fl);
                k_gemm<<<dim3(37, 6), 256, 0, stream>>>(m1c, m2_w, m2woff, m2_b, boff,
                                                        nullptr, h + (size_t)c*2352*HID,
                                                        2352, HID, MLPD, 0, 1, fl);
            }
        }
    }
    k_final<<<M_, 64, 0, stream>>>(h, fn_g, fn_b, on_w, on_b, oe_w, oe_b, fl, (void*)d_out);
}

// Round 12
// 915.952 us; speedup vs baseline: 11.0555x; 1.2102x over previous
//
#include <hip/hip_runtime.h>
#include <hip/hip_bf16.h>
#include <math.h>

typedef __hip_bfloat16 bf16;
typedef __attribute__((ext_vector_type(8))) short short8;   // 8 bf16 in 4 VGPRs
typedef __attribute__((ext_vector_type(4))) float f32x4;

#define B_ 2
#define N_ 48
#define A_ 16
#define E_ 5
#define HID 384
#define NHD 8
#define HD 48
#define LYR 4
#define MLPD 1536
#define L_ 2352      // N_ + N_*N_
#define M_ 4704      // B_*L_
#define VLP 2432     // padded key stride of transposed-V buffer
// 1/sqrt(48) * log2(e): Q pre-scale so softmax runs in log2 domain (exp2f)
#define QSCALE 0.20823513f

// prepped-weight element offsets (bf16, transposed [n][k] per matrix)
#define WQ_  0LL
#define WK_  589824LL
#define WV_  1179648LL
#define WO_  1769472LL
#define WM1_ 2359296LL
#define WM2_ 4718592LL
#define WTOT 7077888
// prepped-bias offsets
#define BQ_  0
#define BK_  1536
#define BV_  3072
#define BO_  4608
#define BM1_ 6144
#define BM2_ 12288
#define BTOT 13824

static __device__ __forceinline__ float b2f(bf16 v) { return __bfloat162float(v); }
static __device__ __forceinline__ float us2f(unsigned short u) {
    return __uint_as_float(((unsigned)u) << 16);
}
static __device__ __forceinline__ unsigned short f2us(float f) {
    bf16 h = __float2bfloat16(f);
    return *reinterpret_cast<unsigned short*>(&h);
}
static __device__ __forceinline__ float ldv(const float* p, size_t i) { return p[i]; }
static __device__ __forceinline__ float ldv(const bf16*  p, size_t i) { return b2f(p[i]); }
static __device__ __forceinline__ void  stv(float* p, size_t i, float v) { p[i] = v; }
static __device__ __forceinline__ void  stv(bf16*  p, size_t i, float v) { p[i] = __float2bfloat16(v); }
static __device__ __forceinline__ float4 ld4(const float* p, size_t i) {
    return *reinterpret_cast<const float4*>(p + i);
}
static __device__ __forceinline__ float4 ld4(const bf16* p, size_t i) {
    ushort4 u = *reinterpret_cast<const ushort4*>(p + i);
    return make_float4(us2f(u.x), us2f(u.y), us2f(u.z), us2f(u.w));
}

// ------------------------------------------------ dtype detect (flag: 1=fp32, 0=bf16)
__global__ void k_detect(const void* w, int* flag) {
    if (threadIdx.x == 0 && blockIdx.x == 0) {
        const bf16* p = (const bf16*)w;   // node_w: 6144 elems of 0.02*normal
        int isf = 0;
        for (int i = 0; i < 256; ++i) {
            float v = fabsf(b2f(p[i]));
            if (!(v <= 1000.0f)) { isf = 1; break; }
        }
        *flag = isf;
    }
}

// ------------------------------------- weight prep: convert + transpose to [n][k] bf16
template <typename T>
static __device__ void prepw_body(
    const T* q_w, const T* k_w, const T* v_w, const T* o_w,
    const T* m1_w, const T* m2_w, bf16* wbt)
{
    __shared__ unsigned short Ts[64][72];
    const int z = blockIdx.y;
    const int kind = z >> 2, l = z & 3;
    const T* src; int K, N; long long dbase;
    switch (kind) {
        case 0: src = q_w;  K = 384;  N = 384;  dbase = WQ_;  break;
        case 1: src = k_w;  K = 384;  N = 384;  dbase = WK_;  break;
        case 2: src = v_w;  K = 384;  N = 384;  dbase = WV_;  break;
        case 3: src = o_w;  K = 384;  N = 384;  dbase = WO_;  break;
        case 4: src = m1_w; K = 384;  N = 1536; dbase = WM1_; break;
        default: src = m2_w; K = 1536; N = 384; dbase = WM2_; break;
    }
    const int Nt = N >> 6;
    const int tiles = (K >> 6) * Nt;
    if (blockIdx.x >= tiles) return;
    const int tk = blockIdx.x / Nt, tn = blockIdx.x % Nt;
    const int k0 = tk*64, n0 = tn*64;
    const size_t soff = (size_t)l * K * N;
    const size_t doff = (size_t)dbase + (size_t)l * K * N;
    const int tid = threadIdx.x;
    {   // load 64x64 fp tile -> bf16 LDS
        const int kk = tid >> 2, nc = (tid & 3) * 16;
        #pragma unroll
        for (int j = 0; j < 16; ++j)
            Ts[kk][nc + j] = f2us(ldv(src, soff + (size_t)(k0 + kk)*N + n0 + nc + j));
    }
    __syncthreads();
    {   // store transposed [n][k] with b128 writes
        const int nn = tid >> 2, kc = (tid & 3) * 16;
        unsigned short tmp[16];
        #pragma unroll
        for (int j = 0; j < 16; ++j) tmp[j] = Ts[kc + j][nn];
        unsigned short* dst = (unsigned short*)wbt + doff + (size_t)(n0 + nn)*K + k0 + kc;
        *reinterpret_cast<short8*>(dst)     = *reinterpret_cast<short8*>(&tmp[0]);
        *reinterpret_cast<short8*>(dst + 8) = *reinterpret_cast<short8*>(&tmp[8]);
    }
}

__global__ __launch_bounds__(256) void k_prepw(
    const void* q_w, const void* k_w, const void* v_w, const void* o_w,
    const void* m1_w, const void* m2_w, const int* __restrict__ fl, bf16* __restrict__ wbt)
{
    if (*fl) prepw_body<float>((const float*)q_w, (const float*)k_w, (const float*)v_w,
                               (const float*)o_w, (const float*)m1_w, (const float*)m2_w, wbt);
    else     prepw_body<bf16>((const bf16*)q_w, (const bf16*)k_w, (const bf16*)v_w,
                              (const bf16*)o_w, (const bf16*)m1_w, (const bf16*)m2_w, wbt);
}

template <typename T>
static __device__ void prepb_body(
    const T* q_b, const T* k_b, const T* v_b, const T* o_b,
    const T* m1_b, const T* m2_b, bf16* bb)
{
    for (int i = threadIdx.x; i < BTOT; i += 256) {
        float v;
        if      (i < BK_)  v = ldv(q_b,  i);
        else if (i < BV_)  v = ldv(k_b,  i - BK_);
        else if (i < BO_)  v = ldv(v_b,  i - BV_);
        else if (i < BM1_) v = ldv(o_b,  i - BO_);
        else if (i < BM2_) v = ldv(m1_b, i - BM1_);
        else               v = ldv(m2_b, i - BM2_);
        bb[i] = __float2bfloat16(v);
    }
}

__global__ __launch_bounds__(256) void k_prepb(
    const void* q_b, const void* k_b, const void* v_b, const void* o_b,
    const void* m1_b, const void* m2_b, const int* __restrict__ fl, bf16* __restrict__ bb)
{
    if (*fl) prepb_body<float>((const float*)q_b, (const float*)k_b, (const float*)v_b,
                               (const float*)o_b, (const float*)m1_b, (const float*)m2_b, bb);
    else     prepb_body<bf16>((const bf16*)q_b, (const bf16*)k_b, (const bf16*)v_b,
                              (const bf16*)o_b, (const bf16*)m1_b, (const bf16*)m2_b, bb);
}

// ---------------------------------------------------------------- embed (-> f32 h)
template <typename T>
static __device__ void embed_body(
    const T* x, const T* adj, const T* node_w, const T* node_b,
    const T* edge_w, const T* edge_b, const T* pos, float* h)
{
    const int bl = blockIdx.x;
    const int b = bl / L_, l = bl % L_;
    const int c = threadIdx.x;          // 0..383
    float acc;
    if (l < N_) {
        acc = ldv(node_b, c);
        const size_t xr = (size_t)(b*N_ + l)*A_;
        #pragma unroll
        for (int a = 0; a < A_; ++a) acc += ldv(x, xr + a) * ldv(node_w, (size_t)a*HID + c);
    } else {
        const int e = l - N_;
        acc = ldv(edge_b, c);
        const size_t ar = ((size_t)b*N_*N_ + e)*E_;
        #pragma unroll
        for (int j = 0; j < E_; ++j) acc += ldv(adj, ar + j) * ldv(edge_w, (size_t)j*HID + c);
    }
    h[(size_t)bl*HID + c] = acc + ldv(pos, (size_t)l*HID + c);
}

__global__ __launch_bounds__(384) void k_embed(
    const void* x, const void* adj, const void* node_w, const void* node_b,
    const void* edge_w, const void* edge_b, const void* pos,
    const int* __restrict__ fl, float* __restrict__ h)
{
    if (*fl) embed_body<float>((const float*)x, (const float*)adj, (const float*)node_w,
                               (const float*)node_b, (const float*)edge_w, (const float*)edge_b,
                               (const float*)pos, h);
    else     embed_body<bf16>((const bf16*)x, (const bf16*)adj, (const bf16*)node_w,
                              (const bf16*)node_b, (const bf16*)edge_w, (const bf16*)edge_b,
                              (const bf16*)pos, h);
}

// ---------------------------------------- cond stage 1: temb -> hidden (SiLU)
template <typename T>
static __device__ void cond1_body(const T* t, const T* t_w1, const T* t_b1, float* hid)
{
    __shared__ float temb[HID];
    __shared__ float red[4][64];
    const int b = blockIdx.x, jb = blockIdx.y, tid = threadIdx.x;
    const float tv = ldv(t, b);
    for (int c = tid; c < HID; c += 256) {
        int i = (c < 192) ? c : c - 192;
        float f = expf(-9.2103403719761836f * (float)i / 192.0f);
        float ang = tv * f;
        temb[c] = (c < 192) ? sinf(ang) : cosf(ang);
    }
    __syncthreads();
    const int ko = tid >> 6, jo = tid & 63;
    const int j = jb*64 + jo;
    float acc = 0.f;
    for (int i = ko*96; i < (ko + 1)*96; ++i)
        acc += temb[i] * ldv(t_w1, (size_t)i*4*HID + j);
    red[ko][jo] = acc;
    __syncthreads();
    if (ko == 0) {
        float a = red[0][jo] + red[1][jo] + red[2][jo] + red[3][jo] + ldv(t_b1, j);
        hid[(size_t)b*4*HID + j] = a / (1.0f + expf(-a));   // SiLU
    }
}

__global__ __launch_bounds__(256) void k_cond1(
    const void* t, const void* t_w1, const void* t_b1,
    const int* __restrict__ fl, float* __restrict__ hid)
{
    if (*fl) cond1_body<float>((const float*)t, (const float*)t_w1, (const float*)t_b1, hid);
    else     cond1_body<bf16>((const bf16*)t, (const bf16*)t_w1, (const bf16*)t_b1, hid);
}

// ---------------------------------------- cond stage 2: hidden -> partial cond sums
template <typename T>
static __device__ void cond2_body(const T* t_w2, const T* t_b2, const float* hid, float* part)
{
    __shared__ float hs[128];
    const int b = blockIdx.x, ch = blockIdx.y, c = threadIdx.x;
    const int j0 = ch*128;
    if (c < 128) hs[c] = hid[(size_t)b*4*HID + j0 + c];
    __syncthreads();
    float acc = (ch == 0) ? ldv(t_b2, c) : 0.f;
    for (int jj = 0; jj < 128; ++jj)
        acc += hs[jj] * ldv(t_w2, (size_t)(j0 + jj)*HID + c);
    part[((size_t)b*12 + ch)*HID + c] = acc;
}

__global__ __launch_bounds__(384) void k_cond2(
    const void* t_w2, const void* t_b2, const int* __restrict__ fl,
    const float* __restrict__ hid, float* __restrict__ part)
{
    if (*fl) cond2_body<float>((const float*)t_w2, (const float*)t_b2, hid, part);
    else     cond2_body<bf16>((const bf16*)t_w2, (const bf16*)t_b2, hid, part);
}

// ---------------------------------------- cond stage 3: ada projections
template <typename T>
static __device__ void cond3_body(
    const T* ada1_w, const T* ada1_b, const T* ada2_w, const T* ada2_b,
    const float* part, float* ada_out)
{
    __shared__ float cs[HID];
    const int slot = blockIdx.x / 3, ob = blockIdx.x % 3, b = blockIdx.y;
    const int tid = threadIdx.x;
    for (int c = tid; c < HID; c += 256) {
        float s = 0.f;
        #pragma unroll
        for (int ch = 0; ch < 12; ++ch) s += part[((size_t)b*12 + ch)*HID + c];
        cs[c] = s;
    }
    __syncthreads();
    const int layer = slot >> 1, which = slot & 1;
    const int o = ob*256 + tid;
    const T* W  = which ? ada2_w : ada1_w;
    const T* Bi = which ? ada2_b : ada1_b;
    float acc = ldv(Bi, (size_t)layer*768 + o);
    const size_t wb = (size_t)layer*HID*768 + o;
    for (int c = 0; c < HID; ++c) acc += cs[c] * ldv(W, wb + (size_t)c*768);
    ada_out[((size_t)slot*B_ + b)*768 + o] = acc;
}

__global__ __launch_bounds__(256) void k_cond3(
    const void* ada1_w, const void* ada1_b, const void* ada2_w, const void* ada2_b,
    const int* __restrict__ fl, const float* __restrict__ part, float* __restrict__ ada_out)
{
    if (*fl) cond3_body<float>((const float*)ada1_w, (const float*)ada1_b,
                               (const float*)ada2_w, (const float*)ada2_b, part, ada_out);
    else     cond3_body<bf16>((const bf16*)ada1_w, (const bf16*)ada1_b,
                              (const bf16*)ada2_w, (const bf16*)ada2_b, part, ada_out);
}

// ---------------------------------------------------------------- adaLN (f32 h -> bf16 n)
__global__ __launch_bounds__(256) void k_adaln(
    const float* __restrict__ h, const float* __restrict__ ada,
    bf16* __restrict__ n, int slot)
{
    const int row  = blockIdx.x * 4 + (threadIdx.x >> 6);
    const int lane = threadIdx.x & 63;
    const int b = row / L_;
    const float* hr = h + (size_t)row*HID;
    float v[6]; float s = 0.f, ss = 0.f;
    #pragma unroll
    for (int j = 0; j < 6; ++j) { float t = hr[lane + j*64]; v[j] = t; s += t; ss += t*t; }
    #pragma unroll
    for (int off = 32; off; off >>= 1) { s += __shfl_xor(s, off); ss += __shfl_xor(ss, off); }
    const float mu = s * (1.0f/HID);
    const float rs = rsqrtf(fmaxf(ss * (1.0f/HID) - mu*mu, 0.0f) + 1e-5f);
    const float* ap = ada + ((size_t)slot*B_ + b)*768;
    bf16* nr = n + (size_t)row*HID;
    #pragma unroll
    for (int j = 0; j < 6; ++j) {
        int c = lane + j*64;
        nr[c] = __float2bfloat16((v[j] - mu)*rs*(1.0f + ap[c]) + ap[384 + c]);
    }
}

// ------------------------------------------------- MFMA GEMM epilogue (shared)
static __device__ __forceinline__ void gemm_epilogue(
    f32x4 (&acc)[2][2], float bcol0, float bcol1,
    bf16* Cb, float* Cf, int M, int N, int act, int mode,
    int bm, int bn, int wm, int wn, int quad, int c)
{
    const float bcol[2] = {bcol0, bcol1};
    #pragma unroll
    for (int mi = 0; mi < 2; ++mi)
        #pragma unroll
        for (int ni = 0; ni < 2; ++ni) {
            const int col = bn + wn*32 + ni*16 + c;
            #pragma unroll
            for (int r = 0; r < 4; ++r) {
                const int row = bm + wm*32 + mi*16 + quad*4 + r;
                if (row < M) {
                    float v = acc[mi][ni][r] + bcol[ni];
                    if (act) v = 0.5f * v * (1.0f + erff(v * 0.70710678118654752f));  // GELU
                    if (mode == 1) Cf[(size_t)row*N + col] += v;
                    else if (mode == 0) Cb[(size_t)row*N + col] = __float2bfloat16(v);
                    else if (mode == 3) Cb[(size_t)row*N + col] = __float2bfloat16(v * QSCALE);
                    else {
                        const int b   = row >= L_ ? 1 : 0;
                        const int key = row - b*L_;
                        const int hh  = col / 48, d = col - hh*48;
                        Cb[((size_t)(b*8 + hh)*48 + d)*VLP + key] = __float2bfloat16(v);
                    }
                }
            }
        }
}

// -------- legacy GEMM: W fp32/bf16 [k][n], converted+transposed during staging
template <typename T>
static __device__ void gemm_body(
    const bf16* A, const T* W, long long woff, const T* bias, long long boff,
    bf16* Cb, float* Cf, int M, int N, int K, int act, int mode)
{
    __shared__ __align__(16) unsigned short As[64][72];
    __shared__ __align__(16) unsigned short Bt[64][72];
    const int tid  = threadIdx.x;
    const int wv   = tid >> 6, lane = tid & 63;
    const int quad = lane >> 4, c = lane & 15;
    const int wm = wv & 1, wn = wv >> 1;
    const int bm = blockIdx.x * 64, bn = blockIdx.y * 64;
    const int arow = tid >> 3, ach = tid & 7;
    f32x4 acc[2][2] = {{{0.f,0.f,0.f,0.f},{0.f,0.f,0.f,0.f}},
                       {{0.f,0.f,0.f,0.f},{0.f,0.f,0.f,0.f}}};
    for (int k0 = 0; k0 < K; k0 += 64) {
        short8 av[2]; float4 w0[2], w1[2];
        #pragma unroll
        for (int i = 0; i < 2; ++i) {
            const int row = i*32 + arow;
            av[i] = short8{0,0,0,0,0,0,0,0};
            if (bm + row < M)
                av[i] = *reinterpret_cast<const short8*>(
                            A + (size_t)(bm + row)*K + k0 + ach*8);
            const size_t wrow = (size_t)woff + (size_t)(k0 + i*32 + arow)*N + bn + ach*8;
            w0[i] = ld4(W, wrow);
            w1[i] = ld4(W, wrow + 4);
        }
        __syncthreads();
        #pragma unroll
        for (int i = 0; i < 2; ++i) {
            *reinterpret_cast<short8*>(&As[i*32 + arow][ach*8]) = av[i];
            const int kk = i*32 + arow, nb0 = ach*8;
            Bt[nb0+0][kk] = f2us(w0[i].x); Bt[nb0+1][kk] = f2us(w0[i].y);
            Bt[nb0+2][kk] = f2us(w0[i].z); Bt[nb0+3][kk] = f2us(w0[i].w);
            Bt[nb0+4][kk] = f2us(w1[i].x); Bt[nb0+5][kk] = f2us(w1[i].y);
            Bt[nb0+6][kk] = f2us(w1[i].z); Bt[nb0+7][kk] = f2us(w1[i].w);
        }
        __syncthreads();
        #pragma unroll
        for (int ks = 0; ks < 2; ++ks) {
            short8 af[2], bfr[2];
            #pragma unroll
            for (int mi = 0; mi < 2; ++mi)
                af[mi] = *reinterpret_cast<const short8*>(
                             &As[wm*32 + mi*16 + c][ks*32 + quad*8]);
            #pragma unroll
            for (int ni = 0; ni < 2; ++ni)
                bfr[ni] = *reinterpret_cast<const short8*>(
                              &Bt[wn*32 + ni*16 + c][ks*32 + quad*8]);
            #pragma unroll
            for (int mi = 0; mi < 2; ++mi)
                #pragma unroll
                for (int ni = 0; ni < 2; ++ni)
                    acc[mi][ni] = __builtin_amdgcn_mfma_f32_16x16x32_bf16(
                                      af[mi], bfr[ni], acc[mi][ni], 0, 0, 0);
        }
    }
    gemm_epilogue(acc, ldv(bias, (size_t)boff + bn + wn*32 + c),
                  ldv(bias, (size_t)boff + bn + wn*32 + 16 + c),
                  Cb, Cf, M, N, act, mode, bm, bn, wm, wn, quad, c);
}

__global__ __launch_bounds__(256) void k_gemm(
    const bf16* __restrict__ A, const void* W, long long woff, const void* bias, long long boff,
    bf16* Cb, float* Cf, int M, int N, int K, int act, int mode,
    const int* __restrict__ fl)
{
    if (*fl) gemm_body<float>(A, (const float*)W, woff, (const float*)bias, boff,
                              Cb, Cf, M, N, K, act, mode);
    else     gemm_body<bf16>(A, (const bf16*)W, woff, (const bf16*)bias, boff,
                             Cb, Cf, M, N, K, act, mode);
}

__global__ __launch_bounds__(256) void k_gemm_qkv(
    const bf16* __restrict__ A,
    const void* qw, const void* kw, const void* vw,
    const void* qb, const void* kb, const void* vb,
    long long woff, long long boff,
    bf16* Cq, bf16* Ck, bf16* Cv, const int* __restrict__ fl)
{
    const int z = blockIdx.z;
    const void* W  = (z == 0) ? qw : (z == 1) ? kw : vw;
    const void* Bi = (z == 0) ? qb : (z == 1) ? kb : vb;
    bf16* C        = (z == 0) ? Cq : (z == 1) ? Ck : Cv;
    const int mode = (z == 0) ? 3 : (z == 2) ? 2 : 0;
    if (*fl) gemm_body<float>(A, (const float*)W, woff, (const float*)Bi, boff,
                              C, nullptr, M_, HID, HID, 0, mode);
    else     gemm_body<bf16>(A, (const bf16*)W, woff, (const bf16*)Bi, boff,
                             C, nullptr, M_, HID, HID, 0, mode);
}

// -------- prepped GEMM: W bf16 pre-transposed [n][k] -> pure b128 staging
static __device__ void gemm_t_body(
    const bf16* A, const bf16* Wt, long long woff, const bf16* bias, long long boff,
    bf16* Cb, float* Cf, int M, int N, int K, int act, int mode)
{
    __shared__ __align__(16) unsigned short As[64][72];
    __shared__ __align__(16) unsigned short Bt[64][72];
    const int tid  = threadIdx.x;
    const int wv   = tid >> 6, lane = tid & 63;
    const int quad = lane >> 4, c = lane & 15;
    const int wm = wv & 1, wn = wv >> 1;
    const int bm = blockIdx.x * 64, bn = blockIdx.y * 64;
    const int arow = tid >> 3, ach = tid & 7;
    f32x4 acc[2][2] = {{{0.f,0.f,0.f,0.f},{0.f,0.f,0.f,0.f}},
                       {{0.f,0.f,0.f,0.f},{0.f,0.f,0.f,0.f}}};
    for (int k0 = 0; k0 < K; k0 += 64) {
        short8 av[2], wv8[2];
        #pragma unroll
        for (int i = 0; i < 2; ++i) {
            const int row = i*32 + arow;
            av[i] = short8{0,0,0,0,0,0,0,0};
            if (bm + row < M)
                av[i] = *reinterpret_cast<const short8*>(
                            A + (size_t)(bm + row)*K + k0 + ach*8);
            wv8[i] = *reinterpret_cast<const short8*>(
                         Wt + (size_t)woff + (size_t)(bn + row)*K + k0 + ach*8);
        }
        __syncthreads();
        #pragma unroll
        for (int i = 0; i < 2; ++i) {
            *reinterpret_cast<short8*>(&As[i*32 + arow][ach*8]) = av[i];
            *reinterpret_cast<short8*>(&Bt[i*32 + arow][ach*8]) = wv8[i];
        }
        __syncthreads();
        #pragma unroll
        for (int ks = 0; ks < 2; ++ks) {
            short8 af[2], bfr[2];
            #pragma unroll
            for (int mi = 0; mi < 2; ++mi)
                af[mi] = *reinterpret_cast<const short8*>(
                             &As[wm*32 + mi*16 + c][ks*32 + quad*8]);
            #pragma unroll
            for (int ni = 0; ni < 2; ++ni)
                bfr[ni] = *reinterpret_cast<const short8*>(
                              &Bt[wn*32 + ni*16 + c][ks*32 + quad*8]);
            #pragma unroll
            for (int mi = 0; mi < 2; ++mi)
                #pragma unroll
                for (int ni = 0; ni < 2; ++ni)
                    acc[mi][ni] = __builtin_amdgcn_mfma_f32_16x16x32_bf16(
                                      af[mi], bfr[ni], acc[mi][ni], 0, 0, 0);
        }
    }
    gemm_epilogue(acc, b2f(bias[boff + bn + wn*32 + c]),
                  b2f(bias[boff + bn + wn*32 + 16 + c]),
                  Cb, Cf, M, N, act, mode, bm, bn, wm, wn, quad, c);
}

__global__ __launch_bounds__(256) void k_gemm_t(
    const bf16* __restrict__ A, const bf16* __restrict__ Wt, long long woff,
    const bf16* __restrict__ bias, long long boff,
    bf16* Cb, float* Cf, int M, int N, int K, int act, int mode)
{
    gemm_t_body(A, Wt, woff, bias, boff, Cb, Cf, M, N, K, act, mode);
}

__global__ __launch_bounds__(256) void k_gemm_qkv_t(
    const bf16* __restrict__ A, const bf16* __restrict__ wbt, const bf16* __restrict__ bb,
    int lyr, bf16* Cq, bf16* Ck, bf16* Cv)
{
    const int z = blockIdx.z;
    long long woff; long long boff; bf16* C; int mode;
    if (z == 0)      { woff = WQ_ + (long long)lyr*147456; boff = BQ_ + lyr*384; C = Cq; mode = 3; }
    else if (z == 1) { woff = WK_ + (long long)lyr*147456; boff = BK_ + lyr*384; C = Ck; mode = 0; }
    else             { woff = WV_ + (long long)lyr*147456; boff = BV_ + lyr*384; C = Cv; mode = 2; }
    gemm_t_body(A, wbt, woff, bb, boff, C, nullptr, M_, HID, HID, 0, mode);
}

// ---------------------------------------------------------------- MFMA flash attention
// 64-key tiles, pre-transposed V, in-block split-K x2, Q pre-scaled (exp2 domain).
// PV via b128 LDS round-trip (measured faster than 16x16x16 register path — r11).
__global__ __launch_bounds__(256) void k_attn(
    const bf16* __restrict__ q, const bf16* __restrict__ k,
    const bf16* __restrict__ vt, bf16* __restrict__ ao)
{
    __shared__ __align__(16) unsigned short Ks[2][64][80];   // [split][key][d 0..63 +pad]
    __shared__ __align__(16) unsigned short Vt[2][48][72];   // [split][d][key 0..63 +pad]
    __shared__ __align__(16) unsigned short Pq[4][16][72];   // [wave][query][key 0..63 +pad]
    const int tid  = threadIdx.x;
    const int w    = tid >> 6, lane = tid & 63;
    const int quad = lane >> 4, c = lane & 15;
    const int qt = w & 1, sp = w >> 1;
    const int bh = blockIdx.y;                       // b*8+hh
    const size_t base  = (size_t)(bh >> 3)*L_*HID + (size_t)(bh & 7)*HD;
    const size_t vbase = (size_t)bh*48*VLP;
    const int q0 = blockIdx.x*32 + qt*16;
    const bool qvalid = q0 < L_;                     // wave-uniform
    const int qrow = qvalid ? (q0 + c) : c;

    short8 qf0, qf1;
    {
        const unsigned short* qp = (const unsigned short*)(q + base + (size_t)qrow*HID);
        qf0 = *reinterpret_cast<const short8*>(qp + quad*8);                 // d 0..31
        if (quad < 2) qf1 = *reinterpret_cast<const short8*>(qp + 32 + quad*8);  // d 32..47
        else          qf1 = short8{0,0,0,0,0,0,0,0};                         // d 48..63 pad
    }
    f32x4 o0 = {0.f,0.f,0.f,0.f}, o1 = {0.f,0.f,0.f,0.f}, o2 = {0.f,0.f,0.f,0.f};
    float m = -3.0e38f, lsum = 0.f;
    const int t128 = tid & 127, grp = tid >> 7;      // staging group == its waves' split

    for (int tt = 0; tt < 19; ++tt) {
        const int kb0 = grp*1216 + tt*64;            // staging key base
        __syncthreads();
        // ---- K staging: 512 short8 slots (row 0..63, ch 0..7 => d 0..63; ch>=6 zero)
        #pragma unroll
        for (int ii = 0; ii < 4; ++ii) {
            const int idx = t128 + ii*128;
            const int row = idx >> 3, ch = idx & 7;
            short8 val = short8{0,0,0,0,0,0,0,0};
            if (ch < 6) {
                const int key = min(kb0 + row, L_ - 1);   // clamp; masked on S side
                val = *reinterpret_cast<const short8*>(
                        (const unsigned short*)(k + base + (size_t)key*HID) + ch*8);
            }
            *reinterpret_cast<short8*>(&Ks[grp][row][ch*8]) = val;
        }
        // ---- V staging (pre-transposed in global): 384 short8 slots
        #pragma unroll
        for (int ii = 0; ii < 3; ++ii) {
            const int idx = t128 + ii*128;
            const int d = idx >> 3, ch = idx & 7;
            short8 val = *reinterpret_cast<const short8*>(
                    (const unsigned short*)(vt + vbase + (size_t)d*VLP + kb0) + ch*8);
            *reinterpret_cast<short8*>(&Vt[grp][d][ch*8]) = val;
        }
        __syncthreads();

        const int kt = sp*1216 + tt*64;              // compute key base for this wave
        float sv[16];
        #pragma unroll
        for (int t = 0; t < 4; ++t) {
            f32x4 acc = {0.f,0.f,0.f,0.f};
            short8 a0 = *reinterpret_cast<const short8*>(&Ks[sp][t*16 + c][quad*8]);
            short8 a1 = *reinterpret_cast<const short8*>(&Ks[sp][t*16 + c][32 + quad*8]);
            acc = __builtin_amdgcn_mfma_f32_16x16x32_bf16(a0, qf0, acc, 0, 0, 0);
            acc = __builtin_amdgcn_mfma_f32_16x16x32_bf16(a1, qf1, acc, 0, 0, 0);
            #pragma unroll
            for (int r = 0; r < 4; ++r) sv[t*4 + r] = acc[r];   // already log2-scaled
        }
        if (sp == 1 && tt == 18) {                   // only tile with keys >= L_
            #pragma unroll
            for (int t = 0; t < 4; ++t)
                #pragma unroll
                for (int r = 0; r < 4; ++r)
                    if (kt + t*16 + quad*4 + r >= L_) sv[t*4 + r] = -3.0e38f;
        }
        float tmax = sv[0];
        #pragma unroll
        for (int i = 1; i < 16; ++i) tmax = fmaxf(tmax, sv[i]);
        tmax = fmaxf(tmax, __shfl_xor(tmax, 16));
        tmax = fmaxf(tmax, __shfl_xor(tmax, 32));
        const float mn = fmaxf(m, tmax);
        const float alpha = exp2f(m - mn);
        m = mn;
        float psum = 0.f;
        unsigned short pv[16];
        #pragma unroll
        for (int i = 0; i < 16; ++i) {
            const float p = exp2f(sv[i] - m);
            psum += p;
            pv[i] = f2us(p);
        }
        lsum = lsum * alpha + psum;
        o0 *= alpha; o1 *= alpha; o2 *= alpha;
        // P row (query c) -> LDS; same-wave rw, no barrier needed
        #pragma unroll
        for (int t = 0; t < 4; ++t)
            *reinterpret_cast<ushort4*>(&Pq[w][c][t*16 + quad*4]) =
                make_ushort4(pv[t*4+0], pv[t*4+1], pv[t*4+2], pv[t*4+3]);
        // PV in 2 steps of 32 keys (b128 fragments)
        #pragma unroll
        for (int s = 0; s < 2; ++s) {
            short8 pf  = *reinterpret_cast<const short8*>(&Pq[w][c][s*32 + quad*8]);
            short8 vf0 = *reinterpret_cast<const short8*>(&Vt[sp][c][s*32 + quad*8]);
            short8 vf1 = *reinterpret_cast<const short8*>(&Vt[sp][16 + c][s*32 + quad*8]);
            short8 vf2 = *reinterpret_cast<const short8*>(&Vt[sp][32 + c][s*32 + quad*8]);
            o0 = __builtin_amdgcn_mfma_f32_16x16x32_bf16(vf0, pf, o0, 0, 0, 0);
            o1 = __builtin_amdgcn_mfma_f32_16x16x32_bf16(vf1, pf, o1, 0, 0, 0);
            o2 = __builtin_amdgcn_mfma_f32_16x16x32_bf16(vf2, pf, o2, 0, 0, 0);
        }
    }
    // ---- reduce l across quads within wave
    float lw = lsum;
    lw += __shfl_xor(lw, 16);
    lw += __shfl_xor(lw, 32);
    // ---- split merge through LDS (reuse Ks[0]: 10240 B >= 7168 B; Ks dead here)
    float* Mg = (float*)&Ks[0][0][0];
    __syncthreads();
    if (sp == 1) {
        float* dst = Mg + (size_t)(qt*64 + lane)*14;
        dst[0] = o0[0]; dst[1] = o0[1]; dst[2]  = o0[2]; dst[3]  = o0[3];
        dst[4] = o1[0]; dst[5] = o1[1]; dst[6]  = o1[2]; dst[7]  = o1[3];
        dst[8] = o2[0]; dst[9] = o2[1]; dst[10] = o2[2]; dst[11] = o2[3];
        dst[12] = m; dst[13] = lw;
    }
    __syncthreads();
    if (sp == 0 && qvalid) {
        const float* src = Mg + (size_t)(qt*64 + lane)*14;
        const float m2 = src[12], l2 = src[13];
        const float mm = fmaxf(m, m2);
        const float a1 = exp2f(m - mm), a2 = exp2f(m2 - mm);
        const float inv = 1.0f / (lw*a1 + l2*a2);
        unsigned short* orow = (unsigned short*)(ao + base + (size_t)(q0 + c)*HID);
        const f32x4 ot[3] = {o0, o1, o2};
        #pragma unroll
        for (int dt = 0; dt < 3; ++dt) {
            ushort4 w4;
            w4.x = f2us((ot[dt][0]*a1 + src[dt*4+0]*a2) * inv);
            w4.y = f2us((ot[dt][1]*a1 + src[dt*4+1]*a2) * inv);
            w4.z = f2us((ot[dt][2]*a1 + src[dt*4+2]*a2) * inv);
            w4.w = f2us((ot[dt][3]*a1 + src[dt*4+3]*a2) * inv);
            *reinterpret_cast<ushort4*>(orow + dt*16 + quad*4) = w4;
        }
    }
}

// ------------------------------------------------------- final LN + heads
template <typename T, typename TO>
static __device__ void final_body(
    const float* h, const T* fn_g, const T* fn_b,
    const T* on_w, const T* on_b, const T* oe_w, const T* oe_b, TO* out)
{
    __shared__ float hf[HID];
    const int row = blockIdx.x;
    const int b = row / L_, l = row % L_;
    const int lane = threadIdx.x;
    const float* hr = h + (size_t)row*HID;
    float v[6]; float s = 0.f, ss = 0.f;
    #pragma unroll
    for (int j = 0; j < 6; ++j) { float t = hr[lane + j*64]; v[j] = t; s += t; ss += t*t; }
    #pragma unroll
    for (int off = 32; off; off >>= 1) { s += __shfl_xor(s, off); ss += __shfl_xor(ss, off); }
    const float mu = s * (1.0f/HID);
    const float rs = rsqrtf(fmaxf(ss * (1.0f/HID) - mu*mu, 0.0f) + 1e-5f);
    #pragma unroll
    for (int j = 0; j < 6; ++j) {
        int c = lane + j*64;
        hf[c] = (v[j] - mu) * rs * ldv(fn_g, c) + ldv(fn_b, c);
    }
    __syncthreads();
    if (l < N_) {
        if (lane < A_) {
            float acc = ldv(on_b, lane);
            for (int c = 0; c < HID; ++c) acc += hf[c] * ldv(on_w, (size_t)c*A_ + lane);
            stv(out, (size_t)(b*N_ + l)*A_ + lane, acc);
        }
    } else {
        const int e = l - N_;
        if (lane < E_) {
            float acc = ldv(oe_b, lane);
            for (int c = 0; c < HID; ++c) acc += hf[c] * ldv(oe_w, (size_t)c*E_ + lane);
            stv(out, (size_t)B_*N_*A_ + ((size_t)b*N_*N_ + e)*E_ + lane, acc);
        }
    }
}

__global__ __launch_bounds__(64) void k_final(
    const float* __restrict__ h, const void* fn_g, const void* fn_b,
    const void* on_w, const void* on_b, const void* oe_w, const void* oe_b,
    const int* __restrict__ fl, void* out)
{
    if (*fl) final_body<float, float>(h, (const float*)fn_g, (const float*)fn_b,
                                      (const float*)on_w, (const float*)on_b,
                                      (const float*)oe_w, (const float*)oe_b, (float*)out);
    else     final_body<bf16, bf16>(h, (const bf16*)fn_g, (const bf16*)fn_b,
                                    (const bf16*)on_w, (const bf16*)on_b,
                                    (const bf16*)oe_w, (const bf16*)oe_b, (bf16*)out);
}

// ---------------------------------------------------------------- launch
extern "C" void kernel_launch(void* const* d_in, const int* in_sizes, int n_in,
                              void* d_out, int out_size, void* d_ws, size_t ws_size,
                              hipStream_t stream) {
    const void* x      = d_in[0];
    const void* adj    = d_in[1];
    const void* t      = d_in[2];
    const void* node_w = d_in[3];
    const void* node_b = d_in[4];
    const void* edge_w = d_in[5];
    const void* edge_b = d_in[6];
    const void* pos    = d_in[7];
    const void* t_w1   = d_in[8];
    const void* t_b1   = d_in[9];
    const void* t_w2   = d_in[10];
    const void* t_b2   = d_in[11];
    const void* ada1_w = d_in[12];
    const void* ada1_b = d_in[13];
    const void* ada2_w = d_in[14];
    const void* ada2_b = d_in[15];
    const void* q_w    = d_in[16];
    const void* q_b    = d_in[17];
    const void* k_w    = d_in[18];
    const void* k_b    = d_in[19];
    const void* v_w    = d_in[20];
    const void* v_b    = d_in[21];
    const void* o_w    = d_in[22];
    const void* o_b    = d_in[23];
    const void* m1_w   = d_in[24];
    const void* m1_b   = d_in[25];
    const void* m2_w   = d_in[26];
    const void* m2_b   = d_in[27];
    const void* fn_g   = d_in[28];
    const void* fn_b   = d_in[29];
    const void* on_w   = d_in[30];
    const void* on_b   = d_in[31];
    const void* oe_w   = d_in[32];
    const void* oe_b   = d_in[33];

    const size_t SZ  = (size_t)M_ * HID;          // 1,806,336 elements
    const size_t VTZ = (size_t)B_*NHD*HD*VLP;     // 1,867,776 elements (padded V^T)
    const size_t FLT = SZ + 12288 + (size_t)B_*4*HID + (size_t)B_*12*HID;  // 1,830,912
    const size_t M1FULL = (size_t)M_ * MLPD;      // 7,225,344
    const size_t BF_BASE = 3*SZ + VTZ;            // nb..vtb end = 7,286,784
    const size_t BF_BIG  = SZ + M1FULL;           // nb + m1f(from qb) end = 9,031,680
    const size_t NEED      = 256 + sizeof(float)*FLT + sizeof(bf16)*BF_BASE;   // ~21.9 MB
    const size_t NEED_BIG  = 256 + sizeof(float)*FLT + sizeof(bf16)*BF_BIG;    // ~25.4 MB
    const size_t NEED_PREP = 256 + sizeof(float)*FLT
                           + sizeof(bf16)*(BF_BIG + WTOT + BTOT);              // ~39.6 MB
    if (ws_size < NEED) {
        hipMemsetAsync(d_out, 0, (size_t)out_size*sizeof(bf16), stream);  // 1.14 signature
        return;
    }
    const bool big  = (ws_size >= NEED_BIG);
    const bool prep = (ws_size >= NEED_PREP);
    int*   fl   = (int*)d_ws;
    float* h    = (float*)((char*)d_ws + 256);
    float* ada  = h + SZ;                  // [8][B_][768]
    float* hid  = ada + 12288;             // [B_][1536]
    float* part = hid + (size_t)B_*4*HID;  // [B_][12][384] cond partials
    bf16* nb  = (bf16*)(part + (size_t)B_*12*HID);
    bf16* qb  = nb + SZ;
    bf16* kb  = qb + SZ;
    bf16* vtb = kb + SZ;                   // transposed V, [bh*48+d][VLP]
    bf16* m1c = kb;                        // chunked m1: [2352,1536] spans kb+vtb
    bf16* m1f = qb;                        // full m1: [M_,1536] spans qb..vtb+tail
    bf16* wbt = nb + BF_BIG;               // prepped weights (bf16, [n][k])
    bf16* bb  = wbt + WTOT;                // prepped biases

    k_detect<<<1, 64, 0, stream>>>(node_w, fl);
    if (prep) {
        k_prepw<<<dim3(144, 24), 256, 0, stream>>>(q_w, k_w, v_w, o_w, m1_w, m2_w, fl, wbt);
        k_prepb<<<1, 256, 0, stream>>>(q_b, k_b, v_b, o_b, m1_b, m2_b, fl, bb);
    }
    k_embed<<<M_, HID, 0, stream>>>(x, adj, node_w, node_b, edge_w, edge_b, pos, fl, h);
    k_cond1<<<dim3(B_, 24), 256, 0, stream>>>(t, t_w1, t_b1, fl, hid);
    k_cond2<<<dim3(B_, 12), 384, 0, stream>>>(t_w2, t_b2, fl, hid, part);
    k_cond3<<<dim3(24, B_), 256, 0, stream>>>(ada1_w, ada1_b, ada2_w, ada2_b, fl, part, ada);
    for (int i = 0; i < LYR; ++i) {
        const long long woff   = (long long)i * HID * HID;
        const long long boff   = (long long)i * HID;
        const long long m1woff = (long long)i * HID * MLPD;
        const long long m1boff = (long long)i * MLPD;
        const long long m2woff = (long long)i * MLPD * HID;

        k_adaln<<<M_/4, 256, 0, stream>>>(h, ada, nb, 2*i);
        if (prep) {
            k_gemm_qkv_t<<<dim3(74, 6, 3), 256, 0, stream>>>(nb, wbt, bb, i, qb, kb, vtb);
            k_attn<<<dim3(74, B_*NHD), 256, 0, stream>>>(qb, kb, vtb, nb);   // ao -> nb
            k_gemm_t<<<dim3(74, 6), 256, 0, stream>>>(nb, wbt, WO_ + (long long)i*147456,
                                                      bb, BO_ + i*384,
                                                      nullptr, h, M_, HID, HID, 0, 1);
            k_adaln<<<M_/4, 256, 0, stream>>>(h, ada, nb, 2*i + 1);          // n2 -> nb
            k_gemm_t<<<dim3(74, 24), 256, 0, stream>>>(nb, wbt, WM1_ + (long long)i*589824,
                                                       bb, BM1_ + i*MLPD,
                                                       m1f, nullptr, M_, MLPD, HID, 1, 0);
            k_gemm_t<<<dim3(74, 6), 256, 0, stream>>>(m1f, wbt, WM2_ + (long long)i*589824,
                                                      bb, BM2_ + i*384,
                                                      nullptr, h, M_, HID, MLPD, 0, 1);
        } else {
            k_gemm_qkv<<<dim3(74, 6, 3), 256, 0, stream>>>(nb, q_w, k_w, v_w, q_b, k_b, v_b,
                                                           woff, boff, qb, kb, vtb, fl);
            k_attn<<<dim3(74, B_*NHD), 256, 0, stream>>>(qb, kb, vtb, nb);   // ao -> nb
            k_gemm<<<dim3(74, 6), 256, 0, stream>>>(nb, o_w, woff, o_b, boff,
                                                    nullptr, h, M_, HID, HID, 0, 1, fl);
            k_adaln<<<M_/4, 256, 0, stream>>>(h, ada, nb, 2*i + 1);          // n2 -> nb
            if (big) {
                k_gemm<<<dim3(74, 24), 256, 0, stream>>>(nb, m1_w, m1woff, m1_b, m1boff,
                                                         m1f, nullptr, M_, MLPD, HID, 1, 0, fl);
                k_gemm<<<dim3(74, 6), 256, 0, stream>>>(m1f, m2_w, m2woff, m2_b, boff,
                                                        nullptr, h, M_, HID, MLPD, 0, 1, fl);
            } else {
                for (int c = 0; c < 2; ++c) {
                    k_gemm<<<dim3(37, 24), 256, 0, stream>>>(nb + (size_t)c*2352*HID,
                                                             m1_w, m1woff, m1_b, m1boff,
                                                             m1c, nullptr, 2352, MLPD, HID, 1, 0, fl);
                    k_gemm<<<dim3(37, 6), 256, 0, stream>>>(m1c, m2_w, m2woff, m2_b, boff,
                                                            nullptr, h + (size_t)c*2352*HID,
                                                            2352, HID, MLPD, 0, 1, fl);
                }
            }
        }
    }
    k_final<<<M_, 64, 0, stream>>>(h, fn_g, fn_b, on_w, on_b, oe_w, oe_b, fl, (void*)d_out);
}